// Round 1
// baseline (1611.989 us; speedup 1.0000x reference)
//
#include <hip/hip_runtime.h>

#define NN 6000
#define NE 150000

__device__ __forceinline__ float siluf(float x) { return x / (1.f + __expf(-x)); }
__device__ __forceinline__ float sigmf(float x) { return 1.f / (1.f + __expf(-x)); }

// ---------------- atom embedding: x[n,c] = sum_f atom_emb[f, feat, c] ----------------
__global__ __launch_bounds__(128)
void k_atom_embed(const int* __restrict__ af, const float* __restrict__ aemb,
                  float* __restrict__ x)
{
    int n = blockIdx.x, c = threadIdx.x;
    float s = 0.f;
    #pragma unroll
    for (int f = 0; f < 4; ++f) {
        int idx = af[n * 4 + f];
        s += aemb[(f * 10 + idx) * 128 + c];
    }
    x[n * 128 + c] = s;
}

// ---------------- edge embedding MLP (windowed RBF) ----------------
// e = silu(rbf @ W1 + b1) @ W2 + b2 + bond_emb ;  16 edges per block, 256 thr
__global__ __launch_bounds__(256)
void k_edge_embed(const float* __restrict__ dist, const int* __restrict__ bf,
                  const float* __restrict__ W1, const float* __restrict__ b1,
                  const float* __restrict__ W2, const float* __restrict__ b2,
                  const float* __restrict__ bemb, float* __restrict__ ebuf)
{
    __shared__ float rbf_s[16][32];
    __shared__ int   bs_s[16];
    __shared__ float t_s[16][128];
    const int tid = threadIdx.x;
    const int e0 = blockIdx.x * 16;

    for (int idx = tid; idx < 16 * 32; idx += 256) {
        int ei = idx >> 5, j = idx & 31;
        float d = dist[e0 + ei];
        const float step = 5.0f / 511.0f;
        const float invw = 512.0f / 5.0f;
        int b0 = (int)(d * (511.0f / 5.0f) + 0.5f);
        int bs = min(max(b0 - 16, 0), 512 - 32);
        if (j == 0) bs_s[ei] = bs;
        float z = (d - (float)(bs + j) * step) * invw;
        rbf_s[ei][j] = __expf(-z * z);   // window: values outside are < e^-225 == 0 in f32
    }
    __syncthreads();

    // stage 1: t = silu(rbf @ W1 + b1), 16 edges x 128 cols, 8 outputs/thread
    #pragma unroll
    for (int pass = 0; pass < 8; ++pass) {
        int idx = pass * 256 + tid;
        int ei = idx >> 7, c = idx & 127;
        int bs = bs_s[ei];
        float t = b1[c];
        #pragma unroll
        for (int j = 0; j < 32; ++j)
            t += rbf_s[ei][j] * W1[(bs + j) * 128 + c];
        t_s[ei][c] = siluf(t);
    }
    __syncthreads();

    // stage 2: e = t @ W2 + b2 + bond embeddings
    const int c = tid & 127, eg = tid >> 7;
    float acc[8];
    #pragma unroll
    for (int i = 0; i < 8; ++i) acc[i] = 0.f;
    for (int j4 = 0; j4 < 128; j4 += 4) {
        float w0 = W2[(j4 + 0) * 128 + c];
        float w1 = W2[(j4 + 1) * 128 + c];
        float w2 = W2[(j4 + 2) * 128 + c];
        float w3 = W2[(j4 + 3) * 128 + c];
        #pragma unroll
        for (int i = 0; i < 8; ++i) {
            const float4 t4 = *reinterpret_cast<const float4*>(&t_s[eg * 8 + i][j4]);
            acc[i] += t4.x * w0 + t4.y * w1 + t4.z * w2 + t4.w * w3;
        }
    }
    #pragma unroll
    for (int i = 0; i < 8; ++i) {
        int eid = e0 + eg * 8 + i;
        float s = acc[i] + b2[c];
        #pragma unroll
        for (int f = 0; f < 3; ++f)
            s += bemb[(f * 8 + bf[eid * 3 + f]) * 128 + c];
        ebuf[(size_t)eid * 128 + c] = s;
    }
}

// ---------------- rms_sh norm over (K,C) with only k=0 nonzero ----------------
__global__ __launch_bounds__(128)
void k_rms(const float* __restrict__ x, float* __restrict__ xn)
{
    int n = blockIdx.x, c = threadIdx.x;
    float v = x[n * 128 + c];
    float ss = v * v;
    #pragma unroll
    for (int o = 32; o > 0; o >>= 1) ss += __shfl_down(ss, o, 64);
    __shared__ float red[2];
    if ((c & 63) == 0) red[c >> 6] = ss;
    __syncthreads();
    float tot = red[0] + red[1];
    xn[n * 128 + c] = v * rsqrtf(tot * (1.0f / 1152.0f) + 1e-6f);
}

// ---------------- attention: logits (exp'd) + per-dst sums + gate ----------------
// 16 edges/block, 128 thr; thread owns 4 contiguous cols x 4 edges in stage 1
__global__ __launch_bounds__(128)
void k_attn_logits(const float* __restrict__ xn, const float* __restrict__ ebuf,
                   const int* __restrict__ eidx,
                   const float* __restrict__ Wa1l, const float* __restrict__ Wa2l,
                   const float* __restrict__ Wgl,
                   float* __restrict__ exb, float* __restrict__ gateb,
                   float* __restrict__ sums)
{
    __shared__ float inv_s[16][384];
    __shared__ float t_s[16][128];
    __shared__ int dst_s[16];
    const int tid = threadIdx.x;
    const int e0 = blockIdx.x * 16;

    if (tid < 16) dst_s[tid] = eidx[NE + e0 + tid];
    for (int q = tid; q < 16 * 96; q += 128) {
        int ei = q / 96, j4 = (q % 96) * 4;
        int eid = e0 + ei;
        float4 v;
        if (j4 < 128)      v = *reinterpret_cast<const float4*>(&xn[(size_t)eidx[eid] * 128 + j4]);
        else if (j4 < 256) v = *reinterpret_cast<const float4*>(&xn[(size_t)eidx[NE + eid] * 128 + (j4 - 128)]);
        else               v = *reinterpret_cast<const float4*>(&ebuf[(size_t)eid * 128 + (j4 - 256)]);
        *reinterpret_cast<float4*>(&inv_s[ei][j4]) = v;
    }
    __syncthreads();

    const int ct = tid & 31, eg = tid >> 5;   // eg in [0,4): 4 edges each
    float acc[4][4];
    #pragma unroll
    for (int i = 0; i < 4; ++i)
        #pragma unroll
        for (int m = 0; m < 4; ++m) acc[i][m] = 0.f;

    for (int j4 = 0; j4 < 384; j4 += 4) {
        float4 w0 = *reinterpret_cast<const float4*>(&Wa1l[(j4 + 0) * 128 + 4 * ct]);
        float4 w1 = *reinterpret_cast<const float4*>(&Wa1l[(j4 + 1) * 128 + 4 * ct]);
        float4 w2 = *reinterpret_cast<const float4*>(&Wa1l[(j4 + 2) * 128 + 4 * ct]);
        float4 w3 = *reinterpret_cast<const float4*>(&Wa1l[(j4 + 3) * 128 + 4 * ct]);
        #pragma unroll
        for (int i = 0; i < 4; ++i) {
            const float4 xv = *reinterpret_cast<const float4*>(&inv_s[eg * 4 + i][j4]);
            acc[i][0] += xv.x * w0.x + xv.y * w1.x + xv.z * w2.x + xv.w * w3.x;
            acc[i][1] += xv.x * w0.y + xv.y * w1.y + xv.z * w2.y + xv.w * w3.y;
            acc[i][2] += xv.x * w0.z + xv.y * w1.z + xv.z * w2.z + xv.w * w3.z;
            acc[i][3] += xv.x * w0.w + xv.y * w1.w + xv.z * w2.w + xv.w * w3.w;
        }
    }
    #pragma unroll
    for (int i = 0; i < 4; ++i) {
        float4 r;
        r.x = siluf(acc[i][0]); r.y = siluf(acc[i][1]);
        r.z = siluf(acc[i][2]); r.w = siluf(acc[i][3]);
        *reinterpret_cast<float4*>(&t_s[eg * 4 + i][4 * ct]) = r;
    }
    __syncthreads();

    // stage 2: logits -> exp, atomic sums; gate
    {
        int ei = tid >> 3, h = tid & 7;
        float lg = 0.f;
        for (int j4 = 0; j4 < 128; j4 += 4) {
            const float4 tv = *reinterpret_cast<const float4*>(&t_s[ei][j4]);
            lg += tv.x * Wa2l[(j4 + 0) * 8 + h] + tv.y * Wa2l[(j4 + 1) * 8 + h]
                + tv.z * Wa2l[(j4 + 2) * 8 + h] + tv.w * Wa2l[(j4 + 3) * 8 + h];
        }
        float ex = __expf(lg);    // logits are O(0.3); no max-subtraction needed
        exb[(size_t)(e0 + ei) * 8 + h] = ex;
        atomicAdd(&sums[(size_t)dst_s[ei] * 8 + h], ex);

        float g = 0.f;
        for (int j4 = 0; j4 < 128; j4 += 4) {
            const float4 ev = *reinterpret_cast<const float4*>(&inv_s[ei][256 + j4]);
            g += ev.x * Wgl[(j4 + 0) * 8 + h] + ev.y * Wgl[(j4 + 1) * 8 + h]
               + ev.z * Wgl[(j4 + 2) * 8 + h] + ev.w * Wgl[(j4 + 3) * 8 + h];
        }
        gateb[(size_t)(e0 + ei) * 8 + h] = sigmf(g);
    }
}

// ---------------- messages: v = xn[src] @ Wv, scale by alpha*gate, scatter ----------------
__global__ __launch_bounds__(128)
void k_msg(const float* __restrict__ xn, const int* __restrict__ eidx,
           const float* __restrict__ exb, const float* __restrict__ gateb,
           const float* __restrict__ sums, const float* __restrict__ Wvl,
           float* __restrict__ agg)
{
    __shared__ float xs_s[16][128];
    __shared__ float coef_s[16][8];
    __shared__ int dst_s[16];
    const int tid = threadIdx.x;
    const int e0 = blockIdx.x * 16;

    if (tid < 16) dst_s[tid] = eidx[NE + e0 + tid];
    for (int q = tid; q < 16 * 32; q += 128) {
        int ei = q >> 5, j4 = (q & 31) * 4;
        *reinterpret_cast<float4*>(&xs_s[ei][j4]) =
            *reinterpret_cast<const float4*>(&xn[(size_t)eidx[e0 + ei] * 128 + j4]);
    }
    __syncthreads();
    {
        int ei = tid >> 3, h = tid & 7;
        int eid = e0 + ei;
        float al = exb[(size_t)eid * 8 + h] / (sums[(size_t)dst_s[ei] * 8 + h] + 1e-9f);
        coef_s[ei][h] = al * gateb[(size_t)eid * 8 + h];
    }
    __syncthreads();

    const int ct = tid & 31, eg = tid >> 5;
    float acc[4][4];
    #pragma unroll
    for (int i = 0; i < 4; ++i)
        #pragma unroll
        for (int m = 0; m < 4; ++m) acc[i][m] = 0.f;

    for (int j4 = 0; j4 < 128; j4 += 4) {
        float4 w0 = *reinterpret_cast<const float4*>(&Wvl[(j4 + 0) * 128 + 4 * ct]);
        float4 w1 = *reinterpret_cast<const float4*>(&Wvl[(j4 + 1) * 128 + 4 * ct]);
        float4 w2 = *reinterpret_cast<const float4*>(&Wvl[(j4 + 2) * 128 + 4 * ct]);
        float4 w3 = *reinterpret_cast<const float4*>(&Wvl[(j4 + 3) * 128 + 4 * ct]);
        #pragma unroll
        for (int i = 0; i < 4; ++i) {
            const float4 xv = *reinterpret_cast<const float4*>(&xs_s[eg * 4 + i][j4]);
            acc[i][0] += xv.x * w0.x + xv.y * w1.x + xv.z * w2.x + xv.w * w3.x;
            acc[i][1] += xv.x * w0.y + xv.y * w1.y + xv.z * w2.y + xv.w * w3.y;
            acc[i][2] += xv.x * w0.z + xv.y * w1.z + xv.z * w2.z + xv.w * w3.z;
            acc[i][3] += xv.x * w0.w + xv.y * w1.w + xv.z * w2.w + xv.w * w3.w;
        }
    }
    const int h = ct >> 2;     // (4*ct)/16
    #pragma unroll
    for (int i = 0; i < 4; ++i) {
        int ei = eg * 4 + i;
        float cf = coef_s[ei][h];
        float* dp = &agg[(size_t)dst_s[ei] * 128 + 4 * ct];
        atomicAdd(dp + 0, acc[i][0] * cf);
        atomicAdd(dp + 1, acc[i][1] * cf);
        atomicAdd(dp + 2, acc[i][2] * cf);
        atomicAdd(dp + 3, acc[i][3] * cf);
    }
}

// ---------------- x += agg @ Wo ----------------
__global__ __launch_bounds__(128)
void k_out_proj(float* __restrict__ x, const float* __restrict__ agg,
                const float* __restrict__ Wol)
{
    __shared__ float a_s[128];
    int n = blockIdx.x, c = threadIdx.x;
    a_s[c] = agg[n * 128 + c];
    __syncthreads();
    float s = 0.f;
    for (int j4 = 0; j4 < 128; j4 += 4) {
        const float4 a4 = *reinterpret_cast<const float4*>(&a_s[j4]);
        s += a4.x * Wol[(j4 + 0) * 128 + c] + a4.y * Wol[(j4 + 1) * 128 + c]
           + a4.z * Wol[(j4 + 2) * 128 + c] + a4.w * Wol[(j4 + 3) * 128 + c];
    }
    x[n * 128 + c] += s;
}

// ---------------- FFN: x += silu(xn @ Wf1) @ Wf2 ; 8 nodes/block ----------------
__global__ __launch_bounds__(256)
void k_ffn(float* __restrict__ x, const float* __restrict__ xn,
           const float* __restrict__ Wf1l, const float* __restrict__ Wf2l)
{
    __shared__ float xn_s[8][128];
    __shared__ float h_s[8][512];
    const int tid = threadIdx.x;
    const int n0 = blockIdx.x * 8;

    for (int q = tid; q < 8 * 32; q += 256) {
        int ni = q >> 5, j4 = (q & 31) * 4;
        *reinterpret_cast<float4*>(&xn_s[ni][j4]) =
            *reinterpret_cast<const float4*>(&xn[(size_t)(n0 + ni) * 128 + j4]);
    }
    __syncthreads();

    {
        const int hc0 = tid, hc1 = tid + 256;
        float a0[8], a1[8];
        #pragma unroll
        for (int i = 0; i < 8; ++i) { a0[i] = 0.f; a1[i] = 0.f; }
        for (int j4 = 0; j4 < 128; j4 += 4) {
            float w00 = Wf1l[(j4 + 0) * 512 + hc0], w10 = Wf1l[(j4 + 0) * 512 + hc1];
            float w01 = Wf1l[(j4 + 1) * 512 + hc0], w11 = Wf1l[(j4 + 1) * 512 + hc1];
            float w02 = Wf1l[(j4 + 2) * 512 + hc0], w12 = Wf1l[(j4 + 2) * 512 + hc1];
            float w03 = Wf1l[(j4 + 3) * 512 + hc0], w13 = Wf1l[(j4 + 3) * 512 + hc1];
            #pragma unroll
            for (int i = 0; i < 8; ++i) {
                const float4 xv = *reinterpret_cast<const float4*>(&xn_s[i][j4]);
                a0[i] += xv.x * w00 + xv.y * w01 + xv.z * w02 + xv.w * w03;
                a1[i] += xv.x * w10 + xv.y * w11 + xv.z * w12 + xv.w * w13;
            }
        }
        #pragma unroll
        for (int i = 0; i < 8; ++i) { h_s[i][hc0] = siluf(a0[i]); h_s[i][hc1] = siluf(a1[i]); }
    }
    __syncthreads();

    const int c = tid & 127, ng = tid >> 7;
    float acc[4] = {0.f, 0.f, 0.f, 0.f};
    for (int j4 = 0; j4 < 512; j4 += 4) {
        float w0 = Wf2l[(j4 + 0) * 128 + c];
        float w1 = Wf2l[(j4 + 1) * 128 + c];
        float w2 = Wf2l[(j4 + 2) * 128 + c];
        float w3 = Wf2l[(j4 + 3) * 128 + c];
        #pragma unroll
        for (int i = 0; i < 4; ++i) {
            const float4 hv = *reinterpret_cast<const float4*>(&h_s[ng * 4 + i][j4]);
            acc[i] += hv.x * w0 + hv.y * w1 + hv.z * w2 + hv.w * w3;
        }
    }
    #pragma unroll
    for (int i = 0; i < 4; ++i)
        x[(size_t)(n0 + ng * 4 + i) * 128 + c] += acc[i];
}

// ---------------- finalize: out[:,0,:] = rms_sh(x), out[:,1:,:] = 0 ----------------
__global__ __launch_bounds__(128)
void k_finalize(const float* __restrict__ x, float* __restrict__ out)
{
    int n = blockIdx.x, c = threadIdx.x;
    float v = x[n * 128 + c];
    float ss = v * v;
    #pragma unroll
    for (int o = 32; o > 0; o >>= 1) ss += __shfl_down(ss, o, 64);
    __shared__ float red[2];
    if ((c & 63) == 0) red[c >> 6] = ss;
    __syncthreads();
    float r = rsqrtf((red[0] + red[1]) * (1.0f / 1152.0f) + 1e-6f);
    size_t base = (size_t)n * 1152;
    out[base + c] = v * r;
    #pragma unroll
    for (int k = 1; k < 9; ++k) out[base + k * 128 + c] = 0.f;
}

extern "C" void kernel_launch(void* const* d_in, const int* in_sizes, int n_in,
                              void* d_out, int out_size, void* d_ws, size_t ws_size,
                              hipStream_t stream)
{
    const int*   atom_feats = (const int*)d_in[0];
    const int*   bond_feats = (const int*)d_in[1];
    const int*   edge_index = (const int*)d_in[2];
    const float* edge_dist  = (const float*)d_in[3];
    const float* atom_emb   = (const float*)d_in[4];
    const float* bond_emb   = (const float*)d_in[5];
    const float* W_rbf1     = (const float*)d_in[6];
    const float* b_rbf1     = (const float*)d_in[7];
    const float* W_rbf2     = (const float*)d_in[8];
    const float* b_rbf2     = (const float*)d_in[9];
    const float* Wa1        = (const float*)d_in[10];
    const float* Wa2        = (const float*)d_in[11];
    const float* Wv         = (const float*)d_in[12];
    const float* Wg         = (const float*)d_in[13];
    const float* Wo         = (const float*)d_in[14];
    const float* Wf1        = (const float*)d_in[15];
    const float* Wf2        = (const float*)d_in[16];
    float* out = (float*)d_out;

    float* ws    = (float*)d_ws;
    float* x     = ws;                           // N*C
    float* xn    = x     + NN * 128;             // N*C
    float* ebuf  = xn    + NN * 128;             // E*C
    float* exb   = ebuf  + (size_t)NE * 128;     // E*H
    float* gateb = exb   + (size_t)NE * 8;       // E*H
    float* agg   = gateb + (size_t)NE * 8;       // N*C
    float* sums  = agg   + NN * 128;             // N*H   (adjacent to agg: one memset)

    k_atom_embed<<<NN, 128, 0, stream>>>(atom_feats, atom_emb, x);
    k_edge_embed<<<NE / 16, 256, 0, stream>>>(edge_dist, bond_feats, W_rbf1, b_rbf1,
                                              W_rbf2, b_rbf2, bond_emb, ebuf);
    for (int l = 0; l < 2; ++l) {
        k_rms<<<NN, 128, 0, stream>>>(x, xn);
        hipMemsetAsync(agg, 0, (size_t)(NN * 128 + NN * 8) * sizeof(float), stream);
        k_attn_logits<<<NE / 16, 128, 0, stream>>>(xn, ebuf, edge_index,
            Wa1 + (size_t)l * 384 * 128, Wa2 + (size_t)l * 128 * 8, Wg + (size_t)l * 128 * 8,
            exb, gateb, sums);
        k_msg<<<NE / 16, 128, 0, stream>>>(xn, edge_index, exb, gateb, sums,
            Wv + (size_t)l * 128 * 128, agg);
        k_out_proj<<<NN, 128, 0, stream>>>(x, agg, Wo + (size_t)l * 128 * 128);
        k_rms<<<NN, 128, 0, stream>>>(x, xn);
        k_ffn<<<NN / 8, 256, 0, stream>>>(x, xn,
            Wf1 + (size_t)l * 128 * 512, Wf2 + (size_t)l * 512 * 128);
    }
    k_finalize<<<NN, 128, 0, stream>>>(x, out);
}

// Round 2
// 753.492 us; speedup vs baseline: 2.1394x; 2.1394x over previous
//
#include <hip/hip_runtime.h>

#define NN 6000
#define NE 150000

typedef unsigned int uint;
typedef unsigned short ushort;

__device__ __forceinline__ float siluf(float x) { return x / (1.f + __expf(-x)); }
__device__ __forceinline__ float sigmf(float x) { return 1.f / (1.f + __expf(-x)); }
__device__ __forceinline__ ushort f2bf(float f) {
    uint u = __float_as_uint(f);
    uint r = (u + 0x7fffu + ((u >> 16) & 1u)) >> 16;
    return (ushort)r;
}
__device__ __forceinline__ float bf2f(ushort h) { return __uint_as_float(((uint)h) << 16); }

// ---------------- atom embedding ----------------
__global__ __launch_bounds__(128)
void k_atom_embed(const int* __restrict__ af, const float* __restrict__ aemb,
                  float* __restrict__ x)
{
    int n = blockIdx.x, c = threadIdx.x;
    float s = 0.f;
    #pragma unroll
    for (int f = 0; f < 4; ++f) {
        int idx = af[n * 4 + f];
        s += aemb[(f * 10 + idx) * 128 + c];
    }
    x[n * 128 + c] = s;
}

// ---------------- edge embedding MLP (windowed RBF), bf16 output ----------------
__global__ __launch_bounds__(256)
void k_edge_embed(const float* __restrict__ dist, const int* __restrict__ bf,
                  const float* __restrict__ W1, const float* __restrict__ b1,
                  const float* __restrict__ W2, const float* __restrict__ b2,
                  const float* __restrict__ bemb, ushort* __restrict__ eb16)
{
    __shared__ float rbf_s[16][32];
    __shared__ int   bs_s[16];
    __shared__ float t_s[16][132];
    const int tid = threadIdx.x;
    const int e0 = blockIdx.x * 16;

    for (int idx = tid; idx < 16 * 32; idx += 256) {
        int ei = idx >> 5, j = idx & 31;
        float d = dist[e0 + ei];
        const float step = 5.0f / 511.0f;
        const float invw = 512.0f / 5.0f;
        int b0 = (int)(d * (511.0f / 5.0f) + 0.5f);
        int bs = min(max(b0 - 16, 0), 512 - 32);
        if (j == 0) bs_s[ei] = bs;
        float z = (d - (float)(bs + j) * step) * invw;
        rbf_s[ei][j] = __expf(-z * z);
    }
    __syncthreads();

    #pragma unroll
    for (int pass = 0; pass < 8; ++pass) {
        int idx = pass * 256 + tid;
        int ei = idx >> 7, c = idx & 127;
        int bs = bs_s[ei];
        float t = b1[c];
        #pragma unroll
        for (int j = 0; j < 32; ++j)
            t += rbf_s[ei][j] * W1[(bs + j) * 128 + c];
        t_s[ei][c] = siluf(t);
    }
    __syncthreads();

    const int c = tid & 127, eg = tid >> 7;
    float acc[8];
    #pragma unroll
    for (int i = 0; i < 8; ++i) acc[i] = 0.f;
    for (int j4 = 0; j4 < 128; j4 += 4) {
        float w0 = W2[(j4 + 0) * 128 + c];
        float w1 = W2[(j4 + 1) * 128 + c];
        float w2 = W2[(j4 + 2) * 128 + c];
        float w3 = W2[(j4 + 3) * 128 + c];
        #pragma unroll
        for (int i = 0; i < 8; ++i) {
            const float4 t4 = *reinterpret_cast<const float4*>(&t_s[eg * 8 + i][j4]);
            acc[i] += t4.x * w0 + t4.y * w1 + t4.z * w2 + t4.w * w3;
        }
    }
    #pragma unroll
    for (int i = 0; i < 8; ++i) {
        int eid = e0 + eg * 8 + i;
        float s = acc[i] + b2[c];
        #pragma unroll
        for (int f = 0; f < 3; ++f)
            s += bemb[(f * 8 + bf[eid * 3 + f]) * 128 + c];
        eb16[(size_t)eid * 128 + c] = f2bf(s);
    }
}

// ---------------- rms_sh norm (only k=0 nonzero; mean over 9*128) ----------------
__global__ __launch_bounds__(128)
void k_rms(const float* __restrict__ x, float* __restrict__ xn)
{
    int n = blockIdx.x, c = threadIdx.x;
    float v = x[n * 128 + c];
    float ss = v * v;
    #pragma unroll
    for (int o = 32; o > 0; o >>= 1) ss += __shfl_down(ss, o, 64);
    __shared__ float red[2];
    if ((c & 63) == 0) red[c >> 6] = ss;
    __syncthreads();
    float tot = red[0] + red[1];
    xn[n * 128 + c] = v * rsqrtf(tot * (1.0f / 1152.0f) + 1e-6f);
}

// ---------------- node GEMMs: V = xn@Wv, Ps = xn@Wa1[0:128], Pd = xn@Wa1[128:256] ----------------
__global__ __launch_bounds__(256)
void k_nodegemm(const float* __restrict__ xn, const float* __restrict__ Wvl,
                const float* __restrict__ Wa1l, float* __restrict__ V,
                float* __restrict__ Ps, float* __restrict__ Pd)
{
    const float* W; float* O;
    if (blockIdx.y == 0)      { W = Wvl;              O = V;  }
    else if (blockIdx.y == 1) { W = Wa1l;             O = Ps; }
    else                      { W = Wa1l + 128 * 128; O = Pd; }

    __shared__ float xs[8][132];
    const int tid = threadIdx.x;
    const int n0 = blockIdx.x * 8;
    for (int q = tid; q < 8 * 32; q += 256) {
        int ni = q >> 5, j4 = (q & 31) * 4;
        *reinterpret_cast<float4*>(&xs[ni][j4]) =
            *reinterpret_cast<const float4*>(&xn[(size_t)(n0 + ni) * 128 + j4]);
    }
    __syncthreads();

    const int c = tid & 127, ng = tid >> 7;
    float a[4] = {0.f, 0.f, 0.f, 0.f};
    for (int j4 = 0; j4 < 128; j4 += 4) {
        float w0 = W[(j4 + 0) * 128 + c];
        float w1 = W[(j4 + 1) * 128 + c];
        float w2 = W[(j4 + 2) * 128 + c];
        float w3 = W[(j4 + 3) * 128 + c];
        #pragma unroll
        for (int i = 0; i < 4; ++i) {
            const float4 xv = *reinterpret_cast<const float4*>(&xs[ng * 4 + i][j4]);
            a[i] += xv.x * w0 + xv.y * w1 + xv.z * w2 + xv.w * w3;
        }
    }
    #pragma unroll
    for (int i = 0; i < 4; ++i)
        O[(size_t)(n0 + ng * 4 + i) * 128 + c] = a[i];
}

// ---------------- CSR build ----------------
__global__ __launch_bounds__(256)
void k_hist(const int* __restrict__ eidx, int* __restrict__ deg)
{
    int e = blockIdx.x * 256 + threadIdx.x;
    if (e < NE) atomicAdd(&deg[eidx[NE + e]], 1);
}

__global__ __launch_bounds__(1024)
void k_scan(const int* __restrict__ deg, int* __restrict__ off, int* __restrict__ cursor)
{
    __shared__ int part[1024];
    const int t = threadIdx.x;
    const int base = t * 6;
    int loc[6]; int s = 0;
    #pragma unroll
    for (int i = 0; i < 6; ++i) {
        int d = (base + i < NN) ? deg[base + i] : 0;
        loc[i] = s; s += d;
    }
    part[t] = s;
    __syncthreads();
    for (int o = 1; o < 1024; o <<= 1) {
        int v = (t >= o) ? part[t - o] : 0;
        __syncthreads();
        part[t] += v;
        __syncthreads();
    }
    int pre = (t > 0) ? part[t - 1] : 0;
    #pragma unroll
    for (int i = 0; i < 6; ++i) {
        if (base + i < NN) {
            int v = pre + loc[i];
            off[base + i] = v;
            cursor[base + i] = v;
        }
    }
    if (t == 1023) off[NN] = part[1023];
}

__global__ __launch_bounds__(256)
void k_fill(const int* __restrict__ eidx, int* __restrict__ cursor, int* __restrict__ elist)
{
    int e = blockIdx.x * 256 + threadIdx.x;
    if (e < NE) {
        int d = eidx[NE + e];
        int p = atomicAdd(&cursor[d], 1);
        elist[p] = e;
    }
}

// ---------------- fused edge attention: Pe GEMM + silu + logits + gate ----------------
__global__ __launch_bounds__(256)
void k_attn(const ushort* __restrict__ eb16, const int* __restrict__ eidx,
            const float* __restrict__ Ps, const float* __restrict__ Pd,
            const float* __restrict__ Wa1e, const float* __restrict__ Wa2l,
            const float* __restrict__ Wgl,
            float* __restrict__ num, float* __restrict__ sums)
{
    __shared__ float e_s[32][132];
    __shared__ float sum_s[32][132];
    __shared__ float t_s[32][132];
    __shared__ int dst_s[32];
    const int tid = threadIdx.x;
    const int e0 = blockIdx.x * 32;

    if (tid < 32) dst_s[tid] = eidx[NE + min(e0 + tid, NE - 1)];
    {
        int ei = tid >> 3, g = tid & 7;
        int eid = min(e0 + ei, NE - 1);
        int sn = eidx[eid], dn = eidx[NE + eid];
        const ushort* ep = eb16 + (size_t)eid * 128 + g * 16;
        uint4 u0 = *reinterpret_cast<const uint4*>(ep);
        uint4 u1 = *reinterpret_cast<const uint4*>(ep + 8);
        float* er = &e_s[ei][g * 16];
        uint w[8] = {u0.x, u0.y, u0.z, u0.w, u1.x, u1.y, u1.z, u1.w};
        #pragma unroll
        for (int q = 0; q < 8; ++q) {
            er[2 * q + 0] = __uint_as_float((w[q] & 0xffffu) << 16);
            er[2 * q + 1] = __uint_as_float(w[q] & 0xffff0000u);
        }
        const float4* ps4 = reinterpret_cast<const float4*>(&Ps[(size_t)sn * 128 + g * 16]);
        const float4* pd4 = reinterpret_cast<const float4*>(&Pd[(size_t)dn * 128 + g * 16]);
        float* sr = &sum_s[ei][g * 16];
        #pragma unroll
        for (int q = 0; q < 4; ++q) {
            float4 a = ps4[q], b = pd4[q];
            sr[4 * q + 0] = a.x + b.x;
            sr[4 * q + 1] = a.y + b.y;
            sr[4 * q + 2] = a.z + b.z;
            sr[4 * q + 3] = a.w + b.w;
        }
    }
    __syncthreads();

    // stage 1: t = silu(sum + e @ Wa1e); 8 edge-groups x 32 col-groups
    const int ct = tid & 31, eg = tid >> 5;
    float acc[4][4];
    #pragma unroll
    for (int i = 0; i < 4; ++i)
        #pragma unroll
        for (int m = 0; m < 4; ++m) acc[i][m] = 0.f;

    for (int j4 = 0; j4 < 128; j4 += 4) {
        float4 w0 = *reinterpret_cast<const float4*>(&Wa1e[(j4 + 0) * 128 + 4 * ct]);
        float4 w1 = *reinterpret_cast<const float4*>(&Wa1e[(j4 + 1) * 128 + 4 * ct]);
        float4 w2 = *reinterpret_cast<const float4*>(&Wa1e[(j4 + 2) * 128 + 4 * ct]);
        float4 w3 = *reinterpret_cast<const float4*>(&Wa1e[(j4 + 3) * 128 + 4 * ct]);
        #pragma unroll
        for (int i = 0; i < 4; ++i) {
            const float4 xv = *reinterpret_cast<const float4*>(&e_s[eg * 4 + i][j4]);
            acc[i][0] += xv.x * w0.x + xv.y * w1.x + xv.z * w2.x + xv.w * w3.x;
            acc[i][1] += xv.x * w0.y + xv.y * w1.y + xv.z * w2.y + xv.w * w3.y;
            acc[i][2] += xv.x * w0.z + xv.y * w1.z + xv.z * w2.z + xv.w * w3.z;
            acc[i][3] += xv.x * w0.w + xv.y * w1.w + xv.z * w2.w + xv.w * w3.w;
        }
    }
    #pragma unroll
    for (int i = 0; i < 4; ++i) {
        int row = eg * 4 + i;
        const float4 sv = *reinterpret_cast<const float4*>(&sum_s[row][4 * ct]);
        t_s[row][4 * ct + 0] = siluf(acc[i][0] + sv.x);
        t_s[row][4 * ct + 1] = siluf(acc[i][1] + sv.y);
        t_s[row][4 * ct + 2] = siluf(acc[i][2] + sv.z);
        t_s[row][4 * ct + 3] = siluf(acc[i][3] + sv.w);
    }
    __syncthreads();

    // stage 2: logits (exp) + gate; one (edge, head) per thread
    {
        int ei = tid >> 3, h = tid & 7;
        float lg = 0.f, g = 0.f;
        for (int j4 = 0; j4 < 128; j4 += 4) {
            const float4 tv = *reinterpret_cast<const float4*>(&t_s[ei][j4]);
            const float4 ev = *reinterpret_cast<const float4*>(&e_s[ei][j4]);
            lg += tv.x * Wa2l[(j4 + 0) * 8 + h] + tv.y * Wa2l[(j4 + 1) * 8 + h]
                + tv.z * Wa2l[(j4 + 2) * 8 + h] + tv.w * Wa2l[(j4 + 3) * 8 + h];
            g  += ev.x * Wgl[(j4 + 0) * 8 + h] + ev.y * Wgl[(j4 + 1) * 8 + h]
                + ev.z * Wgl[(j4 + 2) * 8 + h] + ev.w * Wgl[(j4 + 3) * 8 + h];
        }
        int eid = e0 + ei;
        if (eid < NE) {
            float ex = __expf(lg);
            num[(size_t)eid * 8 + h] = ex * sigmf(g);
            atomicAdd(&sums[(size_t)dst_s[ei] * 8 + h], ex);
        }
    }
}

// ---------------- aggregate: agg[n] = (1/(sum+eps)) * sum_e num[e]*V[src[e]] ----------------
__global__ __launch_bounds__(128)
void k_agg(const int* __restrict__ off, const int* __restrict__ elist,
           const int* __restrict__ eidx, const float* __restrict__ num,
           const float* __restrict__ sums, const float* __restrict__ V,
           float* __restrict__ agg)
{
    const int n = blockIdx.x, c = threadIdx.x;
    const int s = off[n], t = off[n + 1];
    const int h = c >> 4;
    float sinv = 1.f / (sums[(size_t)n * 8 + h] + 1e-9f);
    float acc = 0.f;
    int e_next = (s < t) ? elist[s] : 0;
    for (int i = s; i < t; ++i) {
        int e = e_next;
        if (i + 1 < t) e_next = elist[i + 1];
        int sn = eidx[e];
        float cf = num[(size_t)e * 8 + h];
        acc += cf * V[(size_t)sn * 128 + c];
    }
    agg[(size_t)n * 128 + c] = acc * sinv;
}

// ---------------- x += agg @ Wo ----------------
__global__ __launch_bounds__(128)
void k_out_proj(float* __restrict__ x, const float* __restrict__ agg,
                const float* __restrict__ Wol)
{
    __shared__ float a_s[128];
    int n = blockIdx.x, c = threadIdx.x;
    a_s[c] = agg[n * 128 + c];
    __syncthreads();
    float s = 0.f;
    for (int j4 = 0; j4 < 128; j4 += 4) {
        const float4 a4 = *reinterpret_cast<const float4*>(&a_s[j4]);
        s += a4.x * Wol[(j4 + 0) * 128 + c] + a4.y * Wol[(j4 + 1) * 128 + c]
           + a4.z * Wol[(j4 + 2) * 128 + c] + a4.w * Wol[(j4 + 3) * 128 + c];
    }
    x[n * 128 + c] += s;
}

// ---------------- FFN ----------------
__global__ __launch_bounds__(256)
void k_ffn(float* __restrict__ x, const float* __restrict__ xn,
           const float* __restrict__ Wf1l, const float* __restrict__ Wf2l)
{
    __shared__ float xn_s[8][132];
    __shared__ float h_s[8][516];
    const int tid = threadIdx.x;
    const int n0 = blockIdx.x * 8;

    for (int q = tid; q < 8 * 32; q += 256) {
        int ni = q >> 5, j4 = (q & 31) * 4;
        *reinterpret_cast<float4*>(&xn_s[ni][j4]) =
            *reinterpret_cast<const float4*>(&xn[(size_t)(n0 + ni) * 128 + j4]);
    }
    __syncthreads();

    {
        const int hc0 = tid, hc1 = tid + 256;
        float a0[8], a1[8];
        #pragma unroll
        for (int i = 0; i < 8; ++i) { a0[i] = 0.f; a1[i] = 0.f; }
        for (int j4 = 0; j4 < 128; j4 += 4) {
            float w00 = Wf1l[(j4 + 0) * 512 + hc0], w10 = Wf1l[(j4 + 0) * 512 + hc1];
            float w01 = Wf1l[(j4 + 1) * 512 + hc0], w11 = Wf1l[(j4 + 1) * 512 + hc1];
            float w02 = Wf1l[(j4 + 2) * 512 + hc0], w12 = Wf1l[(j4 + 2) * 512 + hc1];
            float w03 = Wf1l[(j4 + 3) * 512 + hc0], w13 = Wf1l[(j4 + 3) * 512 + hc1];
            #pragma unroll
            for (int i = 0; i < 8; ++i) {
                const float4 xv = *reinterpret_cast<const float4*>(&xn_s[i][j4]);
                a0[i] += xv.x * w00 + xv.y * w01 + xv.z * w02 + xv.w * w03;
                a1[i] += xv.x * w10 + xv.y * w11 + xv.z * w12 + xv.w * w13;
            }
        }
        #pragma unroll
        for (int i = 0; i < 8; ++i) { h_s[i][hc0] = siluf(a0[i]); h_s[i][hc1] = siluf(a1[i]); }
    }
    __syncthreads();

    const int c = tid & 127, ng = tid >> 7;
    float acc[4] = {0.f, 0.f, 0.f, 0.f};
    for (int j4 = 0; j4 < 512; j4 += 4) {
        float w0 = Wf2l[(j4 + 0) * 128 + c];
        float w1 = Wf2l[(j4 + 1) * 128 + c];
        float w2 = Wf2l[(j4 + 2) * 128 + c];
        float w3 = Wf2l[(j4 + 3) * 128 + c];
        #pragma unroll
        for (int i = 0; i < 4; ++i) {
            const float4 hv = *reinterpret_cast<const float4*>(&h_s[ng * 4 + i][j4]);
            acc[i] += hv.x * w0 + hv.y * w1 + hv.z * w2 + hv.w * w3;
        }
    }
    #pragma unroll
    for (int i = 0; i < 4; ++i)
        x[(size_t)(n0 + ng * 4 + i) * 128 + c] += acc[i];
}

// ---------------- finalize ----------------
__global__ __launch_bounds__(128)
void k_finalize(const float* __restrict__ x, float* __restrict__ out)
{
    int n = blockIdx.x, c = threadIdx.x;
    float v = x[n * 128 + c];
    float ss = v * v;
    #pragma unroll
    for (int o = 32; o > 0; o >>= 1) ss += __shfl_down(ss, o, 64);
    __shared__ float red[2];
    if ((c & 63) == 0) red[c >> 6] = ss;
    __syncthreads();
    float r = rsqrtf((red[0] + red[1]) * (1.0f / 1152.0f) + 1e-6f);
    size_t base = (size_t)n * 1152;
    out[base + c] = v * r;
    #pragma unroll
    for (int k = 1; k < 9; ++k) out[base + k * 128 + c] = 0.f;
}

extern "C" void kernel_launch(void* const* d_in, const int* in_sizes, int n_in,
                              void* d_out, int out_size, void* d_ws, size_t ws_size,
                              hipStream_t stream)
{
    const int*   atom_feats = (const int*)d_in[0];
    const int*   bond_feats = (const int*)d_in[1];
    const int*   edge_index = (const int*)d_in[2];
    const float* edge_dist  = (const float*)d_in[3];
    const float* atom_emb   = (const float*)d_in[4];
    const float* bond_emb   = (const float*)d_in[5];
    const float* W_rbf1     = (const float*)d_in[6];
    const float* b_rbf1     = (const float*)d_in[7];
    const float* W_rbf2     = (const float*)d_in[8];
    const float* b_rbf2     = (const float*)d_in[9];
    const float* Wa1        = (const float*)d_in[10];
    const float* Wa2        = (const float*)d_in[11];
    const float* Wv         = (const float*)d_in[12];
    const float* Wg         = (const float*)d_in[13];
    const float* Wo         = (const float*)d_in[14];
    const float* Wf1        = (const float*)d_in[15];
    const float* Wf2        = (const float*)d_in[16];
    float* out = (float*)d_out;

    float* ws   = (float*)d_ws;
    float* x    = ws;                          // 768000
    float* xn   = x   + NN * 128;              // 768000
    float* V    = xn  + NN * 128;              // 768000
    float* Ps   = V   + NN * 128;              // 768000
    float* Pd   = Ps  + NN * 128;              // 768000
    float* agg  = Pd  + NN * 128;              // 768000
    float* sums = agg + NN * 128;              // 48000
    float* num  = sums + NN * 8;               // E*8 = 1200000
    ushort* eb16 = (ushort*)(num + (size_t)NE * 8);        // E*128 bf16
    int* deg    = (int*)(eb16 + (size_t)NE * 128);         // 6000
    int* off    = deg + NN;                                // 6001
    int* cursor = off + NN + 1;                            // 6000
    int* elist  = cursor + NN;                             // 150000

    k_atom_embed<<<NN, 128, 0, stream>>>(atom_feats, atom_emb, x);
    k_edge_embed<<<NE / 16, 256, 0, stream>>>(edge_dist, bond_feats, W_rbf1, b_rbf1,
                                              W_rbf2, b_rbf2, bond_emb, eb16);
    // CSR build (dst is layer-invariant)
    hipMemsetAsync(deg, 0, NN * sizeof(int), stream);
    k_hist<<<(NE + 255) / 256, 256, 0, stream>>>(edge_index, deg);
    k_scan<<<1, 1024, 0, stream>>>(deg, off, cursor);
    k_fill<<<(NE + 255) / 256, 256, 0, stream>>>(edge_index, cursor, elist);

    for (int l = 0; l < 2; ++l) {
        const float* Wa1l = Wa1 + (size_t)l * 384 * 128;
        k_rms<<<NN, 128, 0, stream>>>(x, xn);
        k_nodegemm<<<dim3(NN / 8, 3), 256, 0, stream>>>(xn, Wv + (size_t)l * 128 * 128,
                                                        Wa1l, V, Ps, Pd);
        hipMemsetAsync(sums, 0, NN * 8 * sizeof(float), stream);
        k_attn<<<(NE + 31) / 32, 256, 0, stream>>>(eb16, edge_index, Ps, Pd,
            Wa1l + 256 * 128, Wa2 + (size_t)l * 128 * 8, Wg + (size_t)l * 128 * 8,
            num, sums);
        k_agg<<<NN, 128, 0, stream>>>(off, elist, edge_index, num, sums, V, agg);
        k_out_proj<<<NN, 128, 0, stream>>>(x, agg, Wo + (size_t)l * 128 * 128);
        k_rms<<<NN, 128, 0, stream>>>(x, xn);
        k_ffn<<<NN / 8, 256, 0, stream>>>(x, xn,
            Wf1 + (size_t)l * 128 * 512, Wf2 + (size_t)l * 512 * 128);
    }
    k_finalize<<<NN, 128, 0, stream>>>(x, out);
}

// Round 3
// 509.901 us; speedup vs baseline: 3.1614x; 1.4777x over previous
//
#include <hip/hip_runtime.h>

#define NN 6000
#define NE 150000
#define TBM 8192            // table intervals over [0, 5]; rows = TBM+1

typedef unsigned int uint;
typedef unsigned short ushort;

__device__ __forceinline__ float siluf(float x) { return x / (1.f + __expf(-x)); }
__device__ __forceinline__ float sigmf(float x) { return 1.f / (1.f + __expf(-x)); }

// ---------------- atom embedding ----------------
__global__ __launch_bounds__(128)
void k_atom_embed(const int* __restrict__ af, const float* __restrict__ aemb,
                  float* __restrict__ x)
{
    int n = blockIdx.x, c = threadIdx.x;
    float s = 0.f;
    #pragma unroll
    for (int f = 0; f < 4; ++f) {
        int idx = af[n * 4 + f];
        s += aemb[(f * 10 + idx) * 128 + c];
    }
    x[n * 128 + c] = s;
}

// ---------------- t1 table: t1[j][c] = silu(b1 + rbf(d_j)@W1), d_j = j*5/TBM ----------------
__global__ __launch_bounds__(256)
void k_t1(const float* __restrict__ W1, const float* __restrict__ b1,
          float* __restrict__ t1)
{
    __shared__ float rbf_s[16][32];
    __shared__ int   bs_s[16];
    const int tid = threadIdx.x;
    const int r0 = blockIdx.x * 16;

    for (int idx = tid; idx < 16 * 32; idx += 256) {
        int ri = idx >> 5, j = idx & 31;
        int row = min(r0 + ri, TBM);
        float d = (float)row * (5.0f / TBM);
        const float step = 5.0f / 511.0f;
        const float invw = 512.0f / 5.0f;
        int b0 = (int)(d * (511.0f / 5.0f) + 0.5f);
        int bs = min(max(b0 - 16, 0), 512 - 32);
        if (j == 0) bs_s[ri] = bs;
        float z = (d - (float)(bs + j) * step) * invw;
        rbf_s[ri][j] = __expf(-z * z);
    }
    __syncthreads();

    #pragma unroll
    for (int pass = 0; pass < 8; ++pass) {
        int idx = pass * 256 + tid;
        int ri = idx >> 7, c = idx & 127;
        int row = r0 + ri;
        if (row > TBM) continue;
        int bs = bs_s[ri];
        float t = b1[c];
        #pragma unroll
        for (int j = 0; j < 32; ++j)
            t += rbf_s[ri][j] * W1[(bs + j) * 128 + c];
        t1[(size_t)row * 128 + c] = siluf(t);
    }
}

// ---------------- fold W2 through per-layer weights ----------------
// x<16:  W2A[l] tile (8 rows)   W2A = W2 @ Wa1e   [128][128]
// x==16: W2G[l] = W2 @ Wg       [128][8]
// x==17: bA[l] = b2 @ Wa1e (128), bG[l] = b2 @ Wg (8)
__global__ __launch_bounds__(256)
void k_w2a(const float* __restrict__ W2, const float* __restrict__ b2,
           const float* __restrict__ Wa1, const float* __restrict__ Wg,
           float* __restrict__ W2A, float* __restrict__ W2G,
           float* __restrict__ bA, float* __restrict__ bG)
{
    const int l = blockIdx.y;
    const float* Wa1e = Wa1 + (size_t)l * 384 * 128 + 256 * 128;
    const float* Wgl  = Wg  + (size_t)l * 128 * 8;
    const int tid = threadIdx.x;

    if (blockIdx.x < 16) {
        __shared__ float w2_s[8][132];
        const int i0 = blockIdx.x * 8;
        for (int q = tid; q < 8 * 32; q += 256) {
            int ni = q >> 5, j4 = (q & 31) * 4;
            *reinterpret_cast<float4*>(&w2_s[ni][j4]) =
                *reinterpret_cast<const float4*>(&W2[(size_t)(i0 + ni) * 128 + j4]);
        }
        __syncthreads();
        const int j = tid & 127, ng = tid >> 7;
        float a[4] = {0.f, 0.f, 0.f, 0.f};
        for (int k4 = 0; k4 < 128; k4 += 4) {
            float w0 = Wa1e[(k4 + 0) * 128 + j];
            float w1 = Wa1e[(k4 + 1) * 128 + j];
            float w2v = Wa1e[(k4 + 2) * 128 + j];
            float w3 = Wa1e[(k4 + 3) * 128 + j];
            #pragma unroll
            for (int r = 0; r < 4; ++r) {
                const float4 xv = *reinterpret_cast<const float4*>(&w2_s[ng * 4 + r][k4]);
                a[r] += xv.x * w0 + xv.y * w1 + xv.z * w2v + xv.w * w3;
            }
        }
        #pragma unroll
        for (int r = 0; r < 4; ++r)
            W2A[(size_t)l * 16384 + (size_t)(i0 + ng * 4 + r) * 128 + j] = a[r];
    } else if (blockIdx.x == 16) {
        const int i = tid & 127, hq = tid >> 7;   // hq in {0,1} -> h = hq*4..+3
        float a[4] = {0.f, 0.f, 0.f, 0.f};
        for (int k = 0; k < 128; ++k) {
            float w = W2[(size_t)i * 128 + k];
            const float4 g4 = *reinterpret_cast<const float4*>(&Wgl[k * 8 + hq * 4]);
            a[0] += w * g4.x; a[1] += w * g4.y; a[2] += w * g4.z; a[3] += w * g4.w;
        }
        #pragma unroll
        for (int q = 0; q < 4; ++q)
            W2G[(size_t)l * 1024 + (size_t)i * 8 + hq * 4 + q] = a[q];
    } else {
        if (tid < 128) {
            float s = 0.f;
            for (int k = 0; k < 128; ++k) s += b2[k] * Wa1e[k * 128 + tid];
            bA[l * 128 + tid] = s;
        } else if (tid < 136) {
            int h = tid - 128;
            float s = 0.f;
            for (int k = 0; k < 128; ++k) s += b2[k] * Wgl[k * 8 + h];
            bG[l * 8 + h] = s;
        }
    }
}

// ---------------- bond-combo tables: BAc[l][cb][128], BGc[l][cb][8] ----------------
__global__ __launch_bounds__(128)
void k_bondtabs(const float* __restrict__ bemb, const float* __restrict__ Wa1,
                const float* __restrict__ Wg,
                float* __restrict__ BAc, float* __restrict__ BGc)
{
    const int l = blockIdx.y, cb = blockIdx.x, c = threadIdx.x;
    const float* Wa1e = Wa1 + (size_t)l * 384 * 128 + 256 * 128;
    const float* Wgl  = Wg  + (size_t)l * 128 * 8;
    const int b[3] = {cb >> 6, (cb >> 3) & 7, cb & 7};

    float s = 0.f;
    #pragma unroll
    for (int f = 0; f < 3; ++f) {
        const float* er = &bemb[(size_t)(f * 8 + b[f]) * 128];
        for (int k = 0; k < 128; ++k)
            s += er[k] * Wa1e[k * 128 + c];
    }
    BAc[(size_t)l * 512 * 128 + (size_t)cb * 128 + c] = s;

    if (c < 8) {
        float g = 0.f;
        #pragma unroll
        for (int f = 0; f < 3; ++f) {
            const float* er = &bemb[(size_t)(f * 8 + b[f]) * 128];
            for (int k = 0; k < 128; ++k)
                g += er[k] * Wgl[k * 8 + c];
        }
        BGc[(size_t)l * 512 * 8 + (size_t)cb * 8 + c] = g;
    }
}

// ---------------- TA/TG tables: TA = t1@W2A + bA, TG = t1@W2G + bG ----------------
__global__ __launch_bounds__(256)
void k_ta(const float* __restrict__ t1, const float* __restrict__ W2A,
          const float* __restrict__ W2G, const float* __restrict__ bA,
          const float* __restrict__ bG, float* __restrict__ TA, float* __restrict__ TG)
{
    __shared__ float t1_s[8][132];
    const int l = blockIdx.y, tid = threadIdx.x;
    const int r0 = blockIdx.x * 8;
    const float* W2Al = W2A + (size_t)l * 16384;
    const float* W2Gl = W2G + (size_t)l * 1024;

    for (int q = tid; q < 8 * 32; q += 256) {
        int ni = q >> 5, j4 = (q & 31) * 4;
        int row = min(r0 + ni, TBM);
        *reinterpret_cast<float4*>(&t1_s[ni][j4]) =
            *reinterpret_cast<const float4*>(&t1[(size_t)row * 128 + j4]);
    }
    __syncthreads();

    const int c = tid & 127, ng = tid >> 7;
    float a[4];
    #pragma unroll
    for (int r = 0; r < 4; ++r) a[r] = bA[l * 128 + c];
    for (int k4 = 0; k4 < 128; k4 += 4) {
        float w0 = W2Al[(k4 + 0) * 128 + c];
        float w1 = W2Al[(k4 + 1) * 128 + c];
        float w2v = W2Al[(k4 + 2) * 128 + c];
        float w3 = W2Al[(k4 + 3) * 128 + c];
        #pragma unroll
        for (int r = 0; r < 4; ++r) {
            const float4 xv = *reinterpret_cast<const float4*>(&t1_s[ng * 4 + r][k4]);
            a[r] += xv.x * w0 + xv.y * w1 + xv.z * w2v + xv.w * w3;
        }
    }
    #pragma unroll
    for (int r = 0; r < 4; ++r) {
        int row = r0 + ng * 4 + r;
        if (row <= TBM)
            TA[(size_t)l * (TBM + 1) * 128 + (size_t)row * 128 + c] = a[r];
    }

    if (tid < 64) {
        int ri = tid >> 3, h = tid & 7;
        int row = r0 + ri;
        if (row <= TBM) {
            float s = bG[l * 8 + h];
            for (int k = 0; k < 128; ++k)
                s += t1_s[ri][k] * W2Gl[k * 8 + h];
            TG[(size_t)l * (TBM + 1) * 8 + (size_t)row * 8 + h] = s;
        }
    }
}

// ---------------- rms_sh norm ----------------
__global__ __launch_bounds__(128)
void k_rms(const float* __restrict__ x, float* __restrict__ xn)
{
    int n = blockIdx.x, c = threadIdx.x;
    float v = x[n * 128 + c];
    float ss = v * v;
    #pragma unroll
    for (int o = 32; o > 0; o >>= 1) ss += __shfl_down(ss, o, 64);
    __shared__ float red[2];
    if ((c & 63) == 0) red[c >> 6] = ss;
    __syncthreads();
    float tot = red[0] + red[1];
    xn[n * 128 + c] = v * rsqrtf(tot * (1.0f / 1152.0f) + 1e-6f);
}

// ---------------- node GEMMs: V, Ps, Pd ----------------
__global__ __launch_bounds__(256)
void k_nodegemm(const float* __restrict__ xn, const float* __restrict__ Wvl,
                const float* __restrict__ Wa1l, float* __restrict__ V,
                float* __restrict__ Ps, float* __restrict__ Pd)
{
    const float* W; float* O;
    if (blockIdx.y == 0)      { W = Wvl;              O = V;  }
    else if (blockIdx.y == 1) { W = Wa1l;             O = Ps; }
    else                      { W = Wa1l + 128 * 128; O = Pd; }

    __shared__ float xs[8][132];
    const int tid = threadIdx.x;
    const int n0 = blockIdx.x * 8;
    for (int q = tid; q < 8 * 32; q += 256) {
        int ni = q >> 5, j4 = (q & 31) * 4;
        *reinterpret_cast<float4*>(&xs[ni][j4]) =
            *reinterpret_cast<const float4*>(&xn[(size_t)(n0 + ni) * 128 + j4]);
    }
    __syncthreads();

    const int c = tid & 127, ng = tid >> 7;
    float a[4] = {0.f, 0.f, 0.f, 0.f};
    for (int j4 = 0; j4 < 128; j4 += 4) {
        float w0 = W[(j4 + 0) * 128 + c];
        float w1 = W[(j4 + 1) * 128 + c];
        float w2 = W[(j4 + 2) * 128 + c];
        float w3 = W[(j4 + 3) * 128 + c];
        #pragma unroll
        for (int i = 0; i < 4; ++i) {
            const float4 xv = *reinterpret_cast<const float4*>(&xs[ng * 4 + i][j4]);
            a[i] += xv.x * w0 + xv.y * w1 + xv.z * w2 + xv.w * w3;
        }
    }
    #pragma unroll
    for (int i = 0; i < 4; ++i)
        O[(size_t)(n0 + ng * 4 + i) * 128 + c] = a[i];
}

// ---------------- CSR build ----------------
__global__ __launch_bounds__(256)
void k_hist(const int* __restrict__ eidx, int* __restrict__ deg)
{
    int e = blockIdx.x * 256 + threadIdx.x;
    if (e < NE) atomicAdd(&deg[eidx[NE + e]], 1);
}

__global__ __launch_bounds__(1024)
void k_scan(const int* __restrict__ deg, int* __restrict__ off, int* __restrict__ cursor)
{
    __shared__ int part[1024];
    const int t = threadIdx.x;
    const int base = t * 6;
    int loc[6]; int s = 0;
    #pragma unroll
    for (int i = 0; i < 6; ++i) {
        int d = (base + i < NN) ? deg[base + i] : 0;
        loc[i] = s; s += d;
    }
    part[t] = s;
    __syncthreads();
    for (int o = 1; o < 1024; o <<= 1) {
        int v = (t >= o) ? part[t - o] : 0;
        __syncthreads();
        part[t] += v;
        __syncthreads();
    }
    int pre = (t > 0) ? part[t - 1] : 0;
    #pragma unroll
    for (int i = 0; i < 6; ++i) {
        if (base + i < NN) {
            int v = pre + loc[i];
            off[base + i] = v;
            cursor[base + i] = v;
        }
    }
    if (t == 1023) off[NN] = part[1023];
}

__global__ __launch_bounds__(256)
void k_fill(const int* __restrict__ eidx, int* __restrict__ cursor, int* __restrict__ elist)
{
    int e = blockIdx.x * 256 + threadIdx.x;
    if (e < NE) {
        int d = eidx[NE + e];
        int p = atomicAdd(&cursor[d], 1);
        elist[p] = e;
    }
}

// ---------------- attention via tables ----------------
// pre = Ps[sn]+Pd[dn]+lerp(TA)+BAc[cb]; t=silu(pre); logit = t@Wa2; gate from TG/BGc
__global__ __launch_bounds__(256)
void k_attn(const int* __restrict__ eidx, const int* __restrict__ bondf,
            const float* __restrict__ dist,
            const float* __restrict__ Ps, const float* __restrict__ Pd,
            const float* __restrict__ TAl, const float* __restrict__ TGl,
            const float* __restrict__ BAcl, const float* __restrict__ BGcl,
            const float* __restrict__ Wa2l,
            float* __restrict__ num, float* __restrict__ sums)
{
    __shared__ float t_s[32][132];
    __shared__ float gate_s[32][8];
    __shared__ int dst_s[32];
    const int tid = threadIdx.x;
    const int e0 = blockIdx.x * 32;

    // phase A: per (edge, 16-channel group)
    {
        const int ei = tid >> 3, g = tid & 7;
        const int eid = min(e0 + ei, NE - 1);
        const int sn = eidx[eid], dn = eidx[NE + eid];
        float d = dist[eid];
        float u = d * ((float)TBM / 5.0f);
        int i = min((int)u, TBM - 1);
        float f = u - (float)i, f1 = 1.f - f;
        int cb = bondf[eid * 3 + 0] * 64 + bondf[eid * 3 + 1] * 8 + bondf[eid * 3 + 2];

        const float4* ps4 = reinterpret_cast<const float4*>(&Ps[(size_t)sn * 128 + g * 16]);
        const float4* pd4 = reinterpret_cast<const float4*>(&Pd[(size_t)dn * 128 + g * 16]);
        const float4* ta0 = reinterpret_cast<const float4*>(&TAl[(size_t)i * 128 + g * 16]);
        const float4* ta1 = ta0 + 32;
        const float4* ba4 = reinterpret_cast<const float4*>(&BAcl[(size_t)cb * 128 + g * 16]);
        float* tr = &t_s[ei][g * 16];
        #pragma unroll
        for (int q = 0; q < 4; ++q) {
            float4 a = ps4[q], b = pd4[q], c0 = ta0[q], c1 = ta1[q], e4 = ba4[q];
            tr[4 * q + 0] = siluf(a.x + b.x + f1 * c0.x + f * c1.x + e4.x);
            tr[4 * q + 1] = siluf(a.y + b.y + f1 * c0.y + f * c1.y + e4.y);
            tr[4 * q + 2] = siluf(a.z + b.z + f1 * c0.z + f * c1.z + e4.z);
            tr[4 * q + 3] = siluf(a.w + b.w + f1 * c0.w + f * c1.w + e4.w);
        }
        if (g == 0) {
            dst_s[ei] = dn;
            const float4* tg0 = reinterpret_cast<const float4*>(&TGl[(size_t)i * 8]);
            const float4* bg4 = reinterpret_cast<const float4*>(&BGcl[(size_t)cb * 8]);
            #pragma unroll
            for (int q = 0; q < 2; ++q) {
                float4 g0 = tg0[q], g1 = tg0[q + 2], bb = bg4[q];
                gate_s[ei][4 * q + 0] = f1 * g0.x + f * g1.x + bb.x;
                gate_s[ei][4 * q + 1] = f1 * g0.y + f * g1.y + bb.y;
                gate_s[ei][4 * q + 2] = f1 * g0.z + f * g1.z + bb.z;
                gate_s[ei][4 * q + 3] = f1 * g0.w + f * g1.w + bb.w;
            }
        }
    }
    __syncthreads();

    // phase B: per (edge, head)
    {
        const int ei = tid >> 3, h = tid & 7;
        const int eid = e0 + ei;
        float lg = 0.f;
        for (int j4 = 0; j4 < 128; j4 += 4) {
            const float4 tv = *reinterpret_cast<const float4*>(&t_s[ei][j4]);
            lg += tv.x * Wa2l[(j4 + 0) * 8 + h] + tv.y * Wa2l[(j4 + 1) * 8 + h]
                + tv.z * Wa2l[(j4 + 2) * 8 + h] + tv.w * Wa2l[(j4 + 3) * 8 + h];
        }
        if (eid < NE) {
            float ex = __expf(lg);
            num[(size_t)eid * 8 + h] = ex * sigmf(gate_s[ei][h]);
            atomicAdd(&sums[(size_t)dst_s[ei] * 8 + h], ex);
        }
    }
}

// ---------------- aggregate ----------------
__global__ __launch_bounds__(128)
void k_agg(const int* __restrict__ off, const int* __restrict__ elist,
           const int* __restrict__ eidx, const float* __restrict__ num,
           const float* __restrict__ sums, const float* __restrict__ V,
           float* __restrict__ agg)
{
    const int n = blockIdx.x, c = threadIdx.x;
    const int s = off[n], t = off[n + 1];
    const int h = c >> 4;
    float sinv = 1.f / (sums[(size_t)n * 8 + h] + 1e-9f);
    float acc = 0.f;
    int e_next = (s < t) ? elist[s] : 0;
    for (int i = s; i < t; ++i) {
        int e = e_next;
        if (i + 1 < t) e_next = elist[i + 1];
        int sn = eidx[e];
        float cf = num[(size_t)e * 8 + h];
        acc += cf * V[(size_t)sn * 128 + c];
    }
    agg[(size_t)n * 128 + c] = acc * sinv;
}

// ---------------- x += agg @ Wo ----------------
__global__ __launch_bounds__(128)
void k_out_proj(float* __restrict__ x, const float* __restrict__ agg,
                const float* __restrict__ Wol)
{
    __shared__ float a_s[128];
    int n = blockIdx.x, c = threadIdx.x;
    a_s[c] = agg[n * 128 + c];
    __syncthreads();
    float s = 0.f;
    for (int j4 = 0; j4 < 128; j4 += 4) {
        const float4 a4 = *reinterpret_cast<const float4*>(&a_s[j4]);
        s += a4.x * Wol[(j4 + 0) * 128 + c] + a4.y * Wol[(j4 + 1) * 128 + c]
           + a4.z * Wol[(j4 + 2) * 128 + c] + a4.w * Wol[(j4 + 3) * 128 + c];
    }
    x[n * 128 + c] += s;
}

// ---------------- FFN ----------------
__global__ __launch_bounds__(256)
void k_ffn(float* __restrict__ x, const float* __restrict__ xn,
           const float* __restrict__ Wf1l, const float* __restrict__ Wf2l)
{
    __shared__ float xn_s[8][132];
    __shared__ float h_s[8][516];
    const int tid = threadIdx.x;
    const int n0 = blockIdx.x * 8;

    for (int q = tid; q < 8 * 32; q += 256) {
        int ni = q >> 5, j4 = (q & 31) * 4;
        *reinterpret_cast<float4*>(&xn_s[ni][j4]) =
            *reinterpret_cast<const float4*>(&xn[(size_t)(n0 + ni) * 128 + j4]);
    }
    __syncthreads();

    {
        const int hc0 = tid, hc1 = tid + 256;
        float a0[8], a1[8];
        #pragma unroll
        for (int i = 0; i < 8; ++i) { a0[i] = 0.f; a1[i] = 0.f; }
        for (int j4 = 0; j4 < 128; j4 += 4) {
            float w00 = Wf1l[(j4 + 0) * 512 + hc0], w10 = Wf1l[(j4 + 0) * 512 + hc1];
            float w01 = Wf1l[(j4 + 1) * 512 + hc0], w11 = Wf1l[(j4 + 1) * 512 + hc1];
            float w02 = Wf1l[(j4 + 2) * 512 + hc0], w12 = Wf1l[(j4 + 2) * 512 + hc1];
            float w03 = Wf1l[(j4 + 3) * 512 + hc0], w13 = Wf1l[(j4 + 3) * 512 + hc1];
            #pragma unroll
            for (int i = 0; i < 8; ++i) {
                const float4 xv = *reinterpret_cast<const float4*>(&xn_s[i][j4]);
                a0[i] += xv.x * w00 + xv.y * w01 + xv.z * w02 + xv.w * w03;
                a1[i] += xv.x * w10 + xv.y * w11 + xv.z * w12 + xv.w * w13;
            }
        }
        #pragma unroll
        for (int i = 0; i < 8; ++i) { h_s[i][hc0] = siluf(a0[i]); h_s[i][hc1] = siluf(a1[i]); }
    }
    __syncthreads();

    const int c = tid & 127, ng = tid >> 7;
    float acc[4] = {0.f, 0.f, 0.f, 0.f};
    for (int j4 = 0; j4 < 512; j4 += 4) {
        float w0 = Wf2l[(j4 + 0) * 128 + c];
        float w1 = Wf2l[(j4 + 1) * 128 + c];
        float w2 = Wf2l[(j4 + 2) * 128 + c];
        float w3 = Wf2l[(j4 + 3) * 128 + c];
        #pragma unroll
        for (int i = 0; i < 4; ++i) {
            const float4 hv = *reinterpret_cast<const float4*>(&h_s[ng * 4 + i][j4]);
            acc[i] += hv.x * w0 + hv.y * w1 + hv.z * w2 + hv.w * w3;
        }
    }
    #pragma unroll
    for (int i = 0; i < 4; ++i)
        x[(size_t)(n0 + ng * 4 + i) * 128 + c] += acc[i];
}

// ---------------- finalize ----------------
__global__ __launch_bounds__(128)
void k_finalize(const float* __restrict__ x, float* __restrict__ out)
{
    int n = blockIdx.x, c = threadIdx.x;
    float v = x[n * 128 + c];
    float ss = v * v;
    #pragma unroll
    for (int o = 32; o > 0; o >>= 1) ss += __shfl_down(ss, o, 64);
    __shared__ float red[2];
    if ((c & 63) == 0) red[c >> 6] = ss;
    __syncthreads();
    float r = rsqrtf((red[0] + red[1]) * (1.0f / 1152.0f) + 1e-6f);
    size_t base = (size_t)n * 1152;
    out[base + c] = v * r;
    #pragma unroll
    for (int k = 1; k < 9; ++k) out[base + k * 128 + c] = 0.f;
}

extern "C" void kernel_launch(void* const* d_in, const int* in_sizes, int n_in,
                              void* d_out, int out_size, void* d_ws, size_t ws_size,
                              hipStream_t stream)
{
    const int*   atom_feats = (const int*)d_in[0];
    const int*   bond_feats = (const int*)d_in[1];
    const int*   edge_index = (const int*)d_in[2];
    const float* edge_dist  = (const float*)d_in[3];
    const float* atom_emb   = (const float*)d_in[4];
    const float* bond_emb   = (const float*)d_in[5];
    const float* W_rbf1     = (const float*)d_in[6];
    const float* b_rbf1     = (const float*)d_in[7];
    const float* W_rbf2     = (const float*)d_in[8];
    const float* b_rbf2     = (const float*)d_in[9];
    const float* Wa1        = (const float*)d_in[10];
    const float* Wa2        = (const float*)d_in[11];
    const float* Wv         = (const float*)d_in[12];
    const float* Wg         = (const float*)d_in[13];
    const float* Wo         = (const float*)d_in[14];
    const float* Wf1        = (const float*)d_in[15];
    const float* Wf2        = (const float*)d_in[16];
    float* out = (float*)d_out;

    const size_t TROWS = TBM + 1;
    float* ws   = (float*)d_ws;
    float* x    = ws;                           // N*C
    float* xn   = x    + NN * 128;
    float* V    = xn   + NN * 128;
    float* Ps   = V    + NN * 128;
    float* Pd   = Ps   + NN * 128;
    float* agg  = Pd   + NN * 128;
    float* sums = agg  + NN * 128;              // N*8
    float* num  = sums + NN * 8;                // E*8
    float* t1   = num  + (size_t)NE * 8;        // TROWS*128
    float* TA   = t1   + TROWS * 128;           // 2*TROWS*128
    float* TG   = TA   + 2 * TROWS * 128;       // 2*TROWS*8
    float* W2A  = TG   + 2 * TROWS * 8;         // 2*128*128
    float* W2G  = W2A  + 2 * 128 * 128;         // 2*128*8
    float* bA   = W2G  + 2 * 128 * 8;           // 2*128
    float* bG   = bA   + 2 * 128;               // 2*8
    float* BAc  = bG   + 2 * 8;                 // 2*512*128
    float* BGc  = BAc  + 2 * 512 * 128;         // 2*512*8
    int* deg    = (int*)(BGc + 2 * 512 * 8);
    int* off    = deg + NN;
    int* cursor = off + NN + 1;
    int* elist  = cursor + NN;

    k_atom_embed<<<NN, 128, 0, stream>>>(atom_feats, atom_emb, x);

    // tables (once per call)
    k_t1<<<(TBM + 16) / 16, 256, 0, stream>>>(W_rbf1, b_rbf1, t1);
    k_w2a<<<dim3(18, 2), 256, 0, stream>>>(W_rbf2, b_rbf2, Wa1, Wg, W2A, W2G, bA, bG);
    k_bondtabs<<<dim3(512, 2), 128, 0, stream>>>(bond_emb, Wa1, Wg, BAc, BGc);
    k_ta<<<dim3((TBM + 8) / 8, 2), 256, 0, stream>>>(t1, W2A, W2G, bA, bG, TA, TG);

    // CSR (dst is layer-invariant)
    hipMemsetAsync(deg, 0, NN * sizeof(int), stream);
    k_hist<<<(NE + 255) / 256, 256, 0, stream>>>(edge_index, deg);
    k_scan<<<1, 1024, 0, stream>>>(deg, off, cursor);
    k_fill<<<(NE + 255) / 256, 256, 0, stream>>>(edge_index, cursor, elist);

    for (int l = 0; l < 2; ++l) {
        k_rms<<<NN, 128, 0, stream>>>(x, xn);
        k_nodegemm<<<dim3(NN / 8, 3), 256, 0, stream>>>(xn, Wv + (size_t)l * 128 * 128,
                                                        Wa1 + (size_t)l * 384 * 128, V, Ps, Pd);
        hipMemsetAsync(sums, 0, NN * 8 * sizeof(float), stream);
        k_attn<<<(NE + 31) / 32, 256, 0, stream>>>(edge_index, bond_feats, edge_dist,
            Ps, Pd,
            TA + (size_t)l * TROWS * 128, TG + (size_t)l * TROWS * 8,
            BAc + (size_t)l * 512 * 128, BGc + (size_t)l * 512 * 8,
            Wa2 + (size_t)l * 128 * 8, num, sums);
        k_agg<<<NN, 128, 0, stream>>>(off, elist, edge_index, num, sums, V, agg);
        k_out_proj<<<NN, 128, 0, stream>>>(x, agg, Wo + (size_t)l * 128 * 128);
        k_rms<<<NN, 128, 0, stream>>>(x, xn);
        k_ffn<<<NN / 8, 256, 0, stream>>>(x, xn,
            Wf1 + (size_t)l * 128 * 512, Wf2 + (size_t)l * 512 * 128);
    }
    k_finalize<<<NN, 128, 0, stream>>>(x, out);
}

// Round 4
// 483.227 us; speedup vs baseline: 3.3359x; 1.0552x over previous
//
#include <hip/hip_runtime.h>

#define NN 6000
#define NE 150000
#define TBM 8192            // table intervals over [0, 5]; rows = TBM+1
#define TROWS (TBM + 1)

typedef unsigned int uint;
typedef unsigned short ushort;

__device__ __forceinline__ float siluf(float x) { return x / (1.f + __expf(-x)); }
__device__ __forceinline__ float sigmf(float x) { return 1.f / (1.f + __expf(-x)); }
__device__ __forceinline__ uint pack2bf(float lo, float hi) {
    uint ul = __float_as_uint(lo);
    ul = (ul + 0x7fffu + ((ul >> 16) & 1u)) >> 16;
    uint uh = __float_as_uint(hi);
    uh = ((uh + 0x7fffu + ((uh >> 16) & 1u)) >> 16) << 16;
    return ul | uh;
}
__device__ __forceinline__ float2 up2(uint u) {
    return make_float2(__uint_as_float(u << 16), __uint_as_float(u & 0xffff0000u));
}

// ---------------- atom embedding ----------------
__global__ __launch_bounds__(128)
void k_atom_embed(const int* __restrict__ af, const float* __restrict__ aemb,
                  float* __restrict__ x)
{
    int n = blockIdx.x, c = threadIdx.x;
    float s = 0.f;
    #pragma unroll
    for (int f = 0; f < 4; ++f) {
        int idx = af[n * 4 + f];
        s += aemb[(f * 10 + idx) * 128 + c];
    }
    x[n * 128 + c] = s;
}

// ---------------- t1 table ----------------
__global__ __launch_bounds__(256)
void k_t1(const float* __restrict__ W1, const float* __restrict__ b1,
          float* __restrict__ t1)
{
    __shared__ float rbf_s[16][32];
    __shared__ int   bs_s[16];
    const int tid = threadIdx.x;
    const int r0 = blockIdx.x * 16;

    for (int idx = tid; idx < 16 * 32; idx += 256) {
        int ri = idx >> 5, j = idx & 31;
        int row = min(r0 + ri, TBM);
        float d = (float)row * (5.0f / TBM);
        const float step = 5.0f / 511.0f;
        const float invw = 512.0f / 5.0f;
        int b0 = (int)(d * (511.0f / 5.0f) + 0.5f);
        int bs = min(max(b0 - 16, 0), 512 - 32);
        if (j == 0) bs_s[ri] = bs;
        float z = (d - (float)(bs + j) * step) * invw;
        rbf_s[ri][j] = __expf(-z * z);
    }
    __syncthreads();

    #pragma unroll
    for (int pass = 0; pass < 8; ++pass) {
        int idx = pass * 256 + tid;
        int ri = idx >> 7, c = idx & 127;
        int row = r0 + ri;
        if (row > TBM) continue;
        int bs = bs_s[ri];
        float t = b1[c];
        #pragma unroll
        for (int j = 0; j < 32; ++j)
            t += rbf_s[ri][j] * W1[(bs + j) * 128 + c];
        t1[(size_t)row * 128 + c] = siluf(t);
    }
}

// ---------------- fold W2 through per-layer weights ----------------
__global__ __launch_bounds__(256)
void k_w2a(const float* __restrict__ W2, const float* __restrict__ b2,
           const float* __restrict__ Wa1, const float* __restrict__ Wg,
           float* __restrict__ W2A, float* __restrict__ W2G,
           float* __restrict__ bA, float* __restrict__ bG)
{
    const int l = blockIdx.y;
    const float* Wa1e = Wa1 + (size_t)l * 384 * 128 + 256 * 128;
    const float* Wgl  = Wg  + (size_t)l * 128 * 8;
    const int tid = threadIdx.x;

    if (blockIdx.x < 16) {
        __shared__ float w2_s[8][132];
        const int i0 = blockIdx.x * 8;
        for (int q = tid; q < 8 * 32; q += 256) {
            int ni = q >> 5, j4 = (q & 31) * 4;
            *reinterpret_cast<float4*>(&w2_s[ni][j4]) =
                *reinterpret_cast<const float4*>(&W2[(size_t)(i0 + ni) * 128 + j4]);
        }
        __syncthreads();
        const int j = tid & 127, ng = tid >> 7;
        float a[4] = {0.f, 0.f, 0.f, 0.f};
        for (int k4 = 0; k4 < 128; k4 += 4) {
            float w0 = Wa1e[(k4 + 0) * 128 + j];
            float w1 = Wa1e[(k4 + 1) * 128 + j];
            float w2v = Wa1e[(k4 + 2) * 128 + j];
            float w3 = Wa1e[(k4 + 3) * 128 + j];
            #pragma unroll
            for (int r = 0; r < 4; ++r) {
                const float4 xv = *reinterpret_cast<const float4*>(&w2_s[ng * 4 + r][k4]);
                a[r] += xv.x * w0 + xv.y * w1 + xv.z * w2v + xv.w * w3;
            }
        }
        #pragma unroll
        for (int r = 0; r < 4; ++r)
            W2A[(size_t)l * 16384 + (size_t)(i0 + ng * 4 + r) * 128 + j] = a[r];
    } else if (blockIdx.x == 16) {
        const int i = tid & 127, hq = tid >> 7;
        float a[4] = {0.f, 0.f, 0.f, 0.f};
        for (int k = 0; k < 128; ++k) {
            float w = W2[(size_t)i * 128 + k];
            const float4 g4 = *reinterpret_cast<const float4*>(&Wgl[k * 8 + hq * 4]);
            a[0] += w * g4.x; a[1] += w * g4.y; a[2] += w * g4.z; a[3] += w * g4.w;
        }
        #pragma unroll
        for (int q = 0; q < 4; ++q)
            W2G[(size_t)l * 1024 + (size_t)i * 8 + hq * 4 + q] = a[q];
    } else {
        if (tid < 128) {
            float s = 0.f;
            for (int k = 0; k < 128; ++k) s += b2[k] * Wa1e[k * 128 + tid];
            bA[l * 128 + tid] = s;
        } else if (tid < 136) {
            int h = tid - 128;
            float s = 0.f;
            for (int k = 0; k < 128; ++k) s += b2[k] * Wgl[k * 8 + h];
            bG[l * 8 + h] = s;
        }
    }
}

// ---------------- bond-combo tables: BAcb (bf16 packed), BGc (f32) ----------------
__global__ __launch_bounds__(128)
void k_bondtabs(const float* __restrict__ bemb, const float* __restrict__ Wa1,
                const float* __restrict__ Wg,
                uint* __restrict__ BAcb, float* __restrict__ BGc)
{
    const int l = blockIdx.y, cb = blockIdx.x, c = threadIdx.x;
    const float* Wa1e = Wa1 + (size_t)l * 384 * 128 + 256 * 128;
    const float* Wgl  = Wg  + (size_t)l * 128 * 8;
    const int b[3] = {cb >> 6, (cb >> 3) & 7, cb & 7};

    float s = 0.f;
    #pragma unroll
    for (int f = 0; f < 3; ++f) {
        const float* er = &bemb[(size_t)(f * 8 + b[f]) * 128];
        for (int k = 0; k < 128; ++k)
            s += er[k] * Wa1e[k * 128 + c];
    }
    float hi = __shfl_down(s, 1, 64);
    if ((c & 1) == 0)
        BAcb[(size_t)l * 512 * 64 + (size_t)cb * 64 + (c >> 1)] = pack2bf(s, hi);

    if (c < 8) {
        float g = 0.f;
        #pragma unroll
        for (int f = 0; f < 3; ++f) {
            const float* er = &bemb[(size_t)(f * 8 + b[f]) * 128];
            for (int k = 0; k < 128; ++k)
                g += er[k] * Wgl[k * 8 + c];
        }
        BGc[(size_t)l * 512 * 8 + (size_t)cb * 8 + c] = g;
    }
}

// ---------------- TA table GEMM (bf16 packed out): TA = t1@W2A + bA ----------------
__global__ __launch_bounds__(256)
void k_ta_gemm(const float* __restrict__ t1, const float* __restrict__ W2A,
               const float* __restrict__ bA, uint* __restrict__ TAb)
{
    __shared__ float t1_s[8][132];
    const int l = blockIdx.y, tid = threadIdx.x;
    const int r0 = blockIdx.x * 8;
    const float* W2Al = W2A + (size_t)l * 16384;

    for (int q = tid; q < 8 * 32; q += 256) {
        int ni = q >> 5, j4 = (q & 31) * 4;
        int row = min(r0 + ni, TBM);
        *reinterpret_cast<float4*>(&t1_s[ni][j4]) =
            *reinterpret_cast<const float4*>(&t1[(size_t)row * 128 + j4]);
    }
    __syncthreads();

    const int c = tid & 127, ng = tid >> 7;
    float a[4];
    #pragma unroll
    for (int r = 0; r < 4; ++r) a[r] = bA[l * 128 + c];
    for (int k4 = 0; k4 < 128; k4 += 4) {
        float w0 = W2Al[(k4 + 0) * 128 + c];
        float w1 = W2Al[(k4 + 1) * 128 + c];
        float w2v = W2Al[(k4 + 2) * 128 + c];
        float w3 = W2Al[(k4 + 3) * 128 + c];
        #pragma unroll
        for (int r = 0; r < 4; ++r) {
            const float4 xv = *reinterpret_cast<const float4*>(&t1_s[ng * 4 + r][k4]);
            a[r] += xv.x * w0 + xv.y * w1 + xv.z * w2v + xv.w * w3;
        }
    }
    #pragma unroll
    for (int r = 0; r < 4; ++r) {
        float hi = __shfl_down(a[r], 1, 64);
        int row = r0 + ng * 4 + r;
        if (((c & 1) == 0) && row <= TBM)
            TAb[(size_t)l * TROWS * 64 + (size_t)row * 64 + (c >> 1)] = pack2bf(a[r], hi);
    }
}

// ---------------- TG table: TG = t1@W2G + bG (f32, tiny) ----------------
__global__ __launch_bounds__(256)
void k_tg(const float* __restrict__ t1, const float* __restrict__ W2G,
          const float* __restrict__ bG, float* __restrict__ TG)
{
    const int l = blockIdx.y, tid = threadIdx.x;
    const int row = blockIdx.x * 32 + (tid >> 3), h = tid & 7;
    if (row > TBM) return;
    const float* W2Gl = W2G + (size_t)l * 1024;
    const float* t1r = &t1[(size_t)row * 128];
    float s = bG[l * 8 + h];
    for (int k = 0; k < 128; ++k)
        s += t1r[k] * W2Gl[k * 8 + h];
    TG[(size_t)l * TROWS * 8 + (size_t)row * 8 + h] = s;
}

// ---------------- rms_sh norm ----------------
__global__ __launch_bounds__(128)
void k_rms(const float* __restrict__ x, float* __restrict__ xn)
{
    int n = blockIdx.x, c = threadIdx.x;
    float v = x[n * 128 + c];
    float ss = v * v;
    #pragma unroll
    for (int o = 32; o > 0; o >>= 1) ss += __shfl_down(ss, o, 64);
    __shared__ float red[2];
    if ((c & 63) == 0) red[c >> 6] = ss;
    __syncthreads();
    float tot = red[0] + red[1];
    xn[n * 128 + c] = v * rsqrtf(tot * (1.0f / 1152.0f) + 1e-6f);
}

// ---------------- node GEMMs -> packed bf16 V, Ps, Pd ----------------
__global__ __launch_bounds__(256)
void k_nodegemm(const float* __restrict__ xn, const float* __restrict__ Wvl,
                const float* __restrict__ Wa1l, uint* __restrict__ Vb,
                uint* __restrict__ Psb, uint* __restrict__ Pdb)
{
    const float* W; uint* O;
    if (blockIdx.y == 0)      { W = Wvl;              O = Vb;  }
    else if (blockIdx.y == 1) { W = Wa1l;             O = Psb; }
    else                      { W = Wa1l + 128 * 128; O = Pdb; }

    __shared__ float xs[8][132];
    const int tid = threadIdx.x;
    const int n0 = blockIdx.x * 8;
    for (int q = tid; q < 8 * 32; q += 256) {
        int ni = q >> 5, j4 = (q & 31) * 4;
        *reinterpret_cast<float4*>(&xs[ni][j4]) =
            *reinterpret_cast<const float4*>(&xn[(size_t)(n0 + ni) * 128 + j4]);
    }
    __syncthreads();

    const int c = tid & 127, ng = tid >> 7;
    float a[4] = {0.f, 0.f, 0.f, 0.f};
    for (int j4 = 0; j4 < 128; j4 += 4) {
        float w0 = W[(j4 + 0) * 128 + c];
        float w1 = W[(j4 + 1) * 128 + c];
        float w2 = W[(j4 + 2) * 128 + c];
        float w3 = W[(j4 + 3) * 128 + c];
        #pragma unroll
        for (int i = 0; i < 4; ++i) {
            const float4 xv = *reinterpret_cast<const float4*>(&xs[ng * 4 + i][j4]);
            a[i] += xv.x * w0 + xv.y * w1 + xv.z * w2 + xv.w * w3;
        }
    }
    #pragma unroll
    for (int i = 0; i < 4; ++i) {
        float hi = __shfl_down(a[i], 1, 64);
        if ((c & 1) == 0)
            O[(size_t)(n0 + ng * 4 + i) * 64 + (c >> 1)] = pack2bf(a[i], hi);
    }
}

// ---------------- CSR build ----------------
__global__ __launch_bounds__(256)
void k_hist(const int* __restrict__ eidx, int* __restrict__ deg)
{
    int e = blockIdx.x * 256 + threadIdx.x;
    if (e < NE) atomicAdd(&deg[eidx[NE + e]], 1);
}

__global__ __launch_bounds__(1024)
void k_scan(const int* __restrict__ deg, int* __restrict__ off, int* __restrict__ cursor)
{
    __shared__ int part[1024];
    const int t = threadIdx.x;
    const int base = t * 6;
    int loc[6]; int s = 0;
    #pragma unroll
    for (int i = 0; i < 6; ++i) {
        int d = (base + i < NN) ? deg[base + i] : 0;
        loc[i] = s; s += d;
    }
    part[t] = s;
    __syncthreads();
    for (int o = 1; o < 1024; o <<= 1) {
        int v = (t >= o) ? part[t - o] : 0;
        __syncthreads();
        part[t] += v;
        __syncthreads();
    }
    int pre = (t > 0) ? part[t - 1] : 0;
    #pragma unroll
    for (int i = 0; i < 6; ++i) {
        if (base + i < NN) {
            int v = pre + loc[i];
            off[base + i] = v;
            cursor[base + i] = v;
        }
    }
    if (t == 1023) off[NN] = part[1023];
}

__global__ __launch_bounds__(256)
void k_fill(const int* __restrict__ eidx, int* __restrict__ cursor, int* __restrict__ elist)
{
    int e = blockIdx.x * 256 + threadIdx.x;
    if (e < NE) {
        int d = eidx[NE + e];
        int p = atomicAdd(&cursor[d], 1);
        elist[p] = e;
    }
}

// ---------------- attention via bf16 tables ----------------
__global__ __launch_bounds__(256)
void k_attn(const int* __restrict__ eidx, const int* __restrict__ bondf,
            const float* __restrict__ dist,
            const uint* __restrict__ Psb, const uint* __restrict__ Pdb,
            const uint* __restrict__ TAbl, const float* __restrict__ TGl,
            const uint* __restrict__ BAcbl, const float* __restrict__ BGcl,
            const float* __restrict__ Wa2l,
            float* __restrict__ num, float* __restrict__ sums)
{
    __shared__ float t_s[32][132];
    __shared__ float gate_s[32][8];
    __shared__ int dst_s[32];
    const int tid = threadIdx.x;
    const int e0 = blockIdx.x * 32;

    // phase A: per (edge, 16-channel group)
    {
        const int ei = tid >> 3, g = tid & 7;
        const int eid = min(e0 + ei, NE - 1);
        const int sn = eidx[eid], dn = eidx[NE + eid];
        float d = dist[eid];
        float u = d * ((float)TBM / 5.0f);
        int i = min((int)u, TBM - 1);
        float f = u - (float)i, f1 = 1.f - f;
        int cb = bondf[eid * 3 + 0] * 64 + bondf[eid * 3 + 1] * 8 + bondf[eid * 3 + 2];

        uint ps[8], pd[8], t0[8], t1v[8], ba[8];
        {
            const uint4* p = reinterpret_cast<const uint4*>(&Psb[(size_t)sn * 64 + g * 8]);
            uint4 a = p[0], b = p[1];
            ps[0]=a.x; ps[1]=a.y; ps[2]=a.z; ps[3]=a.w; ps[4]=b.x; ps[5]=b.y; ps[6]=b.z; ps[7]=b.w;
            p = reinterpret_cast<const uint4*>(&Pdb[(size_t)dn * 64 + g * 8]);
            a = p[0]; b = p[1];
            pd[0]=a.x; pd[1]=a.y; pd[2]=a.z; pd[3]=a.w; pd[4]=b.x; pd[5]=b.y; pd[6]=b.z; pd[7]=b.w;
            p = reinterpret_cast<const uint4*>(&TAbl[(size_t)i * 64 + g * 8]);
            a = p[0]; b = p[1];
            t0[0]=a.x; t0[1]=a.y; t0[2]=a.z; t0[3]=a.w; t0[4]=b.x; t0[5]=b.y; t0[6]=b.z; t0[7]=b.w;
            p = reinterpret_cast<const uint4*>(&TAbl[(size_t)(i + 1) * 64 + g * 8]);
            a = p[0]; b = p[1];
            t1v[0]=a.x; t1v[1]=a.y; t1v[2]=a.z; t1v[3]=a.w; t1v[4]=b.x; t1v[5]=b.y; t1v[6]=b.z; t1v[7]=b.w;
            p = reinterpret_cast<const uint4*>(&BAcbl[(size_t)cb * 64 + g * 8]);
            a = p[0]; b = p[1];
            ba[0]=a.x; ba[1]=a.y; ba[2]=a.z; ba[3]=a.w; ba[4]=b.x; ba[5]=b.y; ba[6]=b.z; ba[7]=b.w;
        }
        float* tr = &t_s[ei][g * 16];
        #pragma unroll
        for (int q = 0; q < 8; ++q) {
            float2 vs = up2(ps[q]), vd = up2(pd[q]), v0 = up2(t0[q]), v1 = up2(t1v[q]), vb = up2(ba[q]);
            tr[2 * q + 0] = siluf(vs.x + vd.x + f1 * v0.x + f * v1.x + vb.x);
            tr[2 * q + 1] = siluf(vs.y + vd.y + f1 * v0.y + f * v1.y + vb.y);
        }
        if (g == 0) {
            dst_s[ei] = dn;
            const float4* tg0 = reinterpret_cast<const float4*>(&TGl[(size_t)i * 8]);
            const float4* bg4 = reinterpret_cast<const float4*>(&BGcl[(size_t)cb * 8]);
            #pragma unroll
            for (int q = 0; q < 2; ++q) {
                float4 g0 = tg0[q], g1 = tg0[q + 2], bb = bg4[q];
                gate_s[ei][4 * q + 0] = f1 * g0.x + f * g1.x + bb.x;
                gate_s[ei][4 * q + 1] = f1 * g0.y + f * g1.y + bb.y;
                gate_s[ei][4 * q + 2] = f1 * g0.z + f * g1.z + bb.z;
                gate_s[ei][4 * q + 3] = f1 * g0.w + f * g1.w + bb.w;
            }
        }
    }
    __syncthreads();

    // phase B: per (edge, head)
    {
        const int ei = tid >> 3, h = tid & 7;
        const int eid = e0 + ei;
        float lg = 0.f;
        for (int j4 = 0; j4 < 128; j4 += 4) {
            const float4 tv = *reinterpret_cast<const float4*>(&t_s[ei][j4]);
            lg += tv.x * Wa2l[(j4 + 0) * 8 + h] + tv.y * Wa2l[(j4 + 1) * 8 + h]
                + tv.z * Wa2l[(j4 + 2) * 8 + h] + tv.w * Wa2l[(j4 + 3) * 8 + h];
        }
        if (eid < NE) {
            float ex = __expf(lg);
            num[(size_t)eid * 8 + h] = ex * sigmf(gate_s[ei][h]);
            atomicAdd(&sums[(size_t)dst_s[ei] * 8 + h], ex);
        }
    }
}

// ---------------- fused aggregate + out_proj: x[n] += (agg[n]/sum) @ Wo ----------------
__global__ __launch_bounds__(128)
void k_aggo(const int* __restrict__ off, const int* __restrict__ elist,
            const int* __restrict__ eidx, const float* __restrict__ num,
            const float* __restrict__ sums, const uint* __restrict__ Vb,
            const float* __restrict__ Wol, float* __restrict__ x)
{
    __shared__ float a_s[128];
    const int n = blockIdx.x, c = threadIdx.x;
    const int s = off[n], t = off[n + 1];
    const int h = c >> 4;
    float sinv = 1.f / (sums[(size_t)n * 8 + h] + 1e-9f);
    float acc = 0.f;
    int e_next = (s < t) ? elist[s] : 0;
    for (int i = s; i < t; ++i) {
        int e = e_next;
        if (i + 1 < t) e_next = elist[i + 1];
        int sn = eidx[e];
        float cf = num[(size_t)e * 8 + h];
        uint u = Vb[(size_t)sn * 64 + (c >> 1)];
        float v = (c & 1) ? __uint_as_float(u & 0xffff0000u) : __uint_as_float(u << 16);
        acc += cf * v;
    }
    a_s[c] = acc * sinv;
    __syncthreads();
    float o = 0.f;
    for (int j4 = 0; j4 < 128; j4 += 4) {
        const float4 a4 = *reinterpret_cast<const float4*>(&a_s[j4]);
        o += a4.x * Wol[(j4 + 0) * 128 + c] + a4.y * Wol[(j4 + 1) * 128 + c]
           + a4.z * Wol[(j4 + 2) * 128 + c] + a4.w * Wol[(j4 + 3) * 128 + c];
    }
    x[n * 128 + c] += o;
}

// ---------------- FFN ----------------
__global__ __launch_bounds__(256)
void k_ffn(float* __restrict__ x, const float* __restrict__ xn,
           const float* __restrict__ Wf1l, const float* __restrict__ Wf2l)
{
    __shared__ float xn_s[8][132];
    __shared__ float h_s[8][516];
    const int tid = threadIdx.x;
    const int n0 = blockIdx.x * 8;

    for (int q = tid; q < 8 * 32; q += 256) {
        int ni = q >> 5, j4 = (q & 31) * 4;
        *reinterpret_cast<float4*>(&xn_s[ni][j4]) =
            *reinterpret_cast<const float4*>(&xn[(size_t)(n0 + ni) * 128 + j4]);
    }
    __syncthreads();

    {
        const int hc0 = tid, hc1 = tid + 256;
        float a0[8], a1[8];
        #pragma unroll
        for (int i = 0; i < 8; ++i) { a0[i] = 0.f; a1[i] = 0.f; }
        for (int j4 = 0; j4 < 128; j4 += 4) {
            float w00 = Wf1l[(j4 + 0) * 512 + hc0], w10 = Wf1l[(j4 + 0) * 512 + hc1];
            float w01 = Wf1l[(j4 + 1) * 512 + hc0], w11 = Wf1l[(j4 + 1) * 512 + hc1];
            float w02 = Wf1l[(j4 + 2) * 512 + hc0], w12 = Wf1l[(j4 + 2) * 512 + hc1];
            float w03 = Wf1l[(j4 + 3) * 512 + hc0], w13 = Wf1l[(j4 + 3) * 512 + hc1];
            #pragma unroll
            for (int i = 0; i < 8; ++i) {
                const float4 xv = *reinterpret_cast<const float4*>(&xn_s[i][j4]);
                a0[i] += xv.x * w00 + xv.y * w01 + xv.z * w02 + xv.w * w03;
                a1[i] += xv.x * w10 + xv.y * w11 + xv.z * w12 + xv.w * w13;
            }
        }
        #pragma unroll
        for (int i = 0; i < 8; ++i) { h_s[i][hc0] = siluf(a0[i]); h_s[i][hc1] = siluf(a1[i]); }
    }
    __syncthreads();

    const int c = tid & 127, ng = tid >> 7;
    float acc[4] = {0.f, 0.f, 0.f, 0.f};
    for (int j4 = 0; j4 < 512; j4 += 4) {
        float w0 = Wf2l[(j4 + 0) * 128 + c];
        float w1 = Wf2l[(j4 + 1) * 128 + c];
        float w2 = Wf2l[(j4 + 2) * 128 + c];
        float w3 = Wf2l[(j4 + 3) * 128 + c];
        #pragma unroll
        for (int i = 0; i < 4; ++i) {
            const float4 hv = *reinterpret_cast<const float4*>(&h_s[ng * 4 + i][j4]);
            acc[i] += hv.x * w0 + hv.y * w1 + hv.z * w2 + hv.w * w3;
        }
    }
    #pragma unroll
    for (int i = 0; i < 4; ++i)
        x[(size_t)(n0 + ng * 4 + i) * 128 + c] += acc[i];
}

// ---------------- finalize ----------------
__global__ __launch_bounds__(128)
void k_finalize(const float* __restrict__ x, float* __restrict__ out)
{
    int n = blockIdx.x, c = threadIdx.x;
    float v = x[n * 128 + c];
    float ss = v * v;
    #pragma unroll
    for (int o = 32; o > 0; o >>= 1) ss += __shfl_down(ss, o, 64);
    __shared__ float red[2];
    if ((c & 63) == 0) red[c >> 6] = ss;
    __syncthreads();
    float r = rsqrtf((red[0] + red[1]) * (1.0f / 1152.0f) + 1e-6f);
    size_t base = (size_t)n * 1152;
    out[base + c] = v * r;
    #pragma unroll
    for (int k = 1; k < 9; ++k) out[base + k * 128 + c] = 0.f;
}

extern "C" void kernel_launch(void* const* d_in, const int* in_sizes, int n_in,
                              void* d_out, int out_size, void* d_ws, size_t ws_size,
                              hipStream_t stream)
{
    const int*   atom_feats = (const int*)d_in[0];
    const int*   bond_feats = (const int*)d_in[1];
    const int*   edge_index = (const int*)d_in[2];
    const float* edge_dist  = (const float*)d_in[3];
    const float* atom_emb   = (const float*)d_in[4];
    const float* bond_emb   = (const float*)d_in[5];
    const float* W_rbf1     = (const float*)d_in[6];
    const float* b_rbf1     = (const float*)d_in[7];
    const float* W_rbf2     = (const float*)d_in[8];
    const float* b_rbf2     = (const float*)d_in[9];
    const float* Wa1        = (const float*)d_in[10];
    const float* Wa2        = (const float*)d_in[11];
    const float* Wv         = (const float*)d_in[12];
    const float* Wg         = (const float*)d_in[13];
    const float* Wo         = (const float*)d_in[14];
    const float* Wf1        = (const float*)d_in[15];
    const float* Wf2        = (const float*)d_in[16];
    float* out = (float*)d_out;

    float* ws   = (float*)d_ws;
    float* x    = ws;                           // NN*128
    float* xn   = x    + NN * 128;              // NN*128
    float* t1   = xn   + NN * 128;              // TROWS*128
    float* sums = t1   + (size_t)TROWS * 128;   // NN*8
    float* num  = sums + NN * 8;                // NE*8
    float* W2A  = num  + (size_t)NE * 8;        // 2*16384
    float* W2G  = W2A  + 2 * 16384;             // 2*1024
    float* bA   = W2G  + 2 * 1024;              // 2*128
    float* bG   = bA   + 2 * 128;               // 16
    float* TG   = bG   + 16;                    // 2*TROWS*8
    float* BGc  = TG   + 2 * (size_t)TROWS * 8; // 2*512*8
    uint* Vb    = (uint*)(BGc + 2 * 512 * 8);   // NN*64
    uint* Psb   = Vb  + NN * 64;                // NN*64
    uint* Pdb   = Psb + NN * 64;                // NN*64
    uint* TAb   = Pdb + NN * 64;                // 2*TROWS*64
    uint* BAcb  = TAb + 2 * (size_t)TROWS * 64; // 2*512*64
    int* deg    = (int*)(BAcb + 2 * 512 * 64);  // NN
    int* off    = deg + NN;                     // NN+1
    int* cursor = off + NN + 1;                 // NN
    int* elist  = cursor + NN;                  // NE

    k_atom_embed<<<NN, 128, 0, stream>>>(atom_feats, atom_emb, x);

    // tables (once per call)
    k_t1<<<(TBM + 16) / 16, 256, 0, stream>>>(W_rbf1, b_rbf1, t1);
    k_w2a<<<dim3(18, 2), 256, 0, stream>>>(W_rbf2, b_rbf2, Wa1, Wg, W2A, W2G, bA, bG);
    k_bondtabs<<<dim3(512, 2), 128, 0, stream>>>(bond_emb, Wa1, Wg, BAcb, BGc);
    k_ta_gemm<<<dim3((TBM + 8) / 8, 2), 256, 0, stream>>>(t1, W2A, bA, TAb);
    k_tg<<<dim3((TBM + 32) / 32, 2), 256, 0, stream>>>(t1, W2G, bG, TG);

    // CSR (dst is layer-invariant)
    hipMemsetAsync(deg, 0, NN * sizeof(int), stream);
    k_hist<<<(NE + 255) / 256, 256, 0, stream>>>(edge_index, deg);
    k_scan<<<1, 1024, 0, stream>>>(deg, off, cursor);
    k_fill<<<(NE + 255) / 256, 256, 0, stream>>>(edge_index, cursor, elist);

    for (int l = 0; l < 2; ++l) {
        k_rms<<<NN, 128, 0, stream>>>(x, xn);
        k_nodegemm<<<dim3(NN / 8, 3), 256, 0, stream>>>(xn, Wv + (size_t)l * 128 * 128,
                                                        Wa1 + (size_t)l * 384 * 128, Vb, Psb, Pdb);
        hipMemsetAsync(sums, 0, NN * 8 * sizeof(float), stream);
        k_attn<<<(NE + 31) / 32, 256, 0, stream>>>(edge_index, bond_feats, edge_dist,
            Psb, Pdb,
            TAb + (size_t)l * TROWS * 64, TG + (size_t)l * TROWS * 8,
            BAcb + (size_t)l * 512 * 64, BGc + (size_t)l * 512 * 8,
            Wa2 + (size_t)l * 128 * 8, num, sums);
        k_aggo<<<NN, 128, 0, stream>>>(off, elist, edge_index, num, sums, Vb,
                                       Wo + (size_t)l * 128 * 128, x);
        k_rms<<<NN, 128, 0, stream>>>(x, xn);
        k_ffn<<<NN / 8, 256, 0, stream>>>(x, xn,
            Wf1 + (size_t)l * 128 * 512, Wf2 + (size_t)l * 512 * 128);
    }
    k_finalize<<<NN, 128, 0, stream>>>(x, out);
}

// Round 5
// 323.837 us; speedup vs baseline: 4.9778x; 1.4922x over previous
//
#include <hip/hip_runtime.h>

#define NN 6000
#define NE 150000
#define TBM 2048            // table intervals over [0, 5]; rows = TBM+1
#define TROWS (TBM + 1)

typedef unsigned int uint;
typedef unsigned short ushort;
typedef __attribute__((ext_vector_type(8))) short short8v;   // 8 bf16
typedef __attribute__((ext_vector_type(4))) float float4v;

__device__ __forceinline__ float siluf(float x) { return x / (1.f + __expf(-x)); }
__device__ __forceinline__ float sigmf(float x) { return 1.f / (1.f + __expf(-x)); }
__device__ __forceinline__ uint pack2bf(float lo, float hi) {
    uint ul = __float_as_uint(lo);
    ul = (ul + 0x7fffu + ((ul >> 16) & 1u)) >> 16;
    uint uh = __float_as_uint(hi);
    uh = ((uh + 0x7fffu + ((uh >> 16) & 1u)) >> 16) << 16;
    return ul | uh;
}
__device__ __forceinline__ ushort f2bf(float f) {
    uint u = __float_as_uint(f);
    return (ushort)((u + 0x7fffu + ((u >> 16) & 1u)) >> 16);
}
__device__ __forceinline__ float2 up2(uint u) {
    return make_float2(__uint_as_float(u << 16), __uint_as_float(u & 0xffff0000u));
}

// ---------------- atom embedding ----------------
__global__ __launch_bounds__(128)
void k_atom_embed(const int* __restrict__ af, const float* __restrict__ aemb,
                  float* __restrict__ x)
{
    int n = blockIdx.x, c = threadIdx.x;
    float s = 0.f;
    #pragma unroll
    for (int f = 0; f < 4; ++f) {
        int idx = af[n * 4 + f];
        s += aemb[(f * 10 + idx) * 128 + c];
    }
    x[n * 128 + c] = s;
}

// ---------------- t1 table ----------------
__global__ __launch_bounds__(256)
void k_t1(const float* __restrict__ W1, const float* __restrict__ b1,
          float* __restrict__ t1)
{
    __shared__ float rbf_s[16][32];
    __shared__ int   bs_s[16];
    const int tid = threadIdx.x;
    const int r0 = blockIdx.x * 16;

    for (int idx = tid; idx < 16 * 32; idx += 256) {
        int ri = idx >> 5, j = idx & 31;
        int row = min(r0 + ri, TBM);
        float d = (float)row * (5.0f / TBM);
        const float step = 5.0f / 511.0f;
        const float invw = 512.0f / 5.0f;
        int b0 = (int)(d * (511.0f / 5.0f) + 0.5f);
        int bs = min(max(b0 - 16, 0), 512 - 32);
        if (j == 0) bs_s[ri] = bs;
        float z = (d - (float)(bs + j) * step) * invw;
        rbf_s[ri][j] = __expf(-z * z);
    }
    __syncthreads();

    #pragma unroll
    for (int pass = 0; pass < 8; ++pass) {
        int idx = pass * 256 + tid;
        int ri = idx >> 7, c = idx & 127;
        int row = r0 + ri;
        if (row > TBM) continue;
        int bs = bs_s[ri];
        float t = b1[c];
        #pragma unroll
        for (int j = 0; j < 32; ++j)
            t += rbf_s[ri][j] * W1[(bs + j) * 128 + c];
        t1[(size_t)row * 128 + c] = siluf(t);
    }
}

// ---------------- fold W2 through per-layer weights ----------------
__global__ __launch_bounds__(256)
void k_w2a(const float* __restrict__ W2, const float* __restrict__ b2,
           const float* __restrict__ Wa1, const float* __restrict__ Wg,
           float* __restrict__ W2A, float* __restrict__ W2G,
           float* __restrict__ bA, float* __restrict__ bG)
{
    const int l = blockIdx.y;
    const float* Wa1e = Wa1 + (size_t)l * 384 * 128 + 256 * 128;
    const float* Wgl  = Wg  + (size_t)l * 128 * 8;
    const int tid = threadIdx.x;

    if (blockIdx.x < 16) {
        __shared__ float w2_s[8][132];
        const int i0 = blockIdx.x * 8;
        for (int q = tid; q < 8 * 32; q += 256) {
            int ni = q >> 5, j4 = (q & 31) * 4;
            *reinterpret_cast<float4*>(&w2_s[ni][j4]) =
                *reinterpret_cast<const float4*>(&W2[(size_t)(i0 + ni) * 128 + j4]);
        }
        __syncthreads();
        const int j = tid & 127, ng = tid >> 7;
        float a[4] = {0.f, 0.f, 0.f, 0.f};
        #pragma unroll 4
        for (int k4 = 0; k4 < 128; k4 += 4) {
            float w0 = Wa1e[(k4 + 0) * 128 + j];
            float w1 = Wa1e[(k4 + 1) * 128 + j];
            float w2v = Wa1e[(k4 + 2) * 128 + j];
            float w3 = Wa1e[(k4 + 3) * 128 + j];
            #pragma unroll
            for (int r = 0; r < 4; ++r) {
                const float4 xv = *reinterpret_cast<const float4*>(&w2_s[ng * 4 + r][k4]);
                a[r] += xv.x * w0 + xv.y * w1 + xv.z * w2v + xv.w * w3;
            }
        }
        #pragma unroll
        for (int r = 0; r < 4; ++r)
            W2A[(size_t)l * 16384 + (size_t)(i0 + ng * 4 + r) * 128 + j] = a[r];
    } else if (blockIdx.x == 16) {
        const int i = tid & 127, hq = tid >> 7;
        float a[4] = {0.f, 0.f, 0.f, 0.f};
        for (int k = 0; k < 128; ++k) {
            float w = W2[(size_t)i * 128 + k];
            const float4 g4 = *reinterpret_cast<const float4*>(&Wgl[k * 8 + hq * 4]);
            a[0] += w * g4.x; a[1] += w * g4.y; a[2] += w * g4.z; a[3] += w * g4.w;
        }
        #pragma unroll
        for (int q = 0; q < 4; ++q)
            W2G[(size_t)l * 1024 + (size_t)i * 8 + hq * 4 + q] = a[q];
    } else {
        if (tid < 128) {
            float s = 0.f;
            for (int k = 0; k < 128; ++k) s += b2[k] * Wa1e[k * 128 + tid];
            bA[l * 128 + tid] = s;
        } else if (tid < 136) {
            int h = tid - 128;
            float s = 0.f;
            for (int k = 0; k < 128; ++k) s += b2[k] * Wgl[k * 8 + h];
            bG[l * 8 + h] = s;
        }
    }
}

// ---------------- bond-combo tables ----------------
__global__ __launch_bounds__(128)
void k_bondtabs(const float* __restrict__ bemb, const float* __restrict__ Wa1,
                const float* __restrict__ Wg,
                uint* __restrict__ BAcb, float* __restrict__ BGc)
{
    const int l = blockIdx.y, cb = blockIdx.x, c = threadIdx.x;
    const float* Wa1e = Wa1 + (size_t)l * 384 * 128 + 256 * 128;
    const float* Wgl  = Wg  + (size_t)l * 128 * 8;
    const int b[3] = {cb >> 6, (cb >> 3) & 7, cb & 7};

    float s = 0.f;
    #pragma unroll
    for (int f = 0; f < 3; ++f) {
        const float* er = &bemb[(size_t)(f * 8 + b[f]) * 128];
        for (int k = 0; k < 128; ++k)
            s += er[k] * Wa1e[k * 128 + c];
    }
    float hi = __shfl_down(s, 1, 64);
    if ((c & 1) == 0)
        BAcb[(size_t)l * 512 * 64 + (size_t)cb * 64 + (c >> 1)] = pack2bf(s, hi);

    if (c < 8) {
        float g = 0.f;
        #pragma unroll
        for (int f = 0; f < 3; ++f) {
            const float* er = &bemb[(size_t)(f * 8 + b[f]) * 128];
            for (int k = 0; k < 128; ++k)
                g += er[k] * Wgl[k * 8 + c];
        }
        BGc[(size_t)l * 512 * 8 + (size_t)cb * 8 + c] = g;
    }
}

// ---------------- TA table GEMM (bf16 packed out) ----------------
__global__ __launch_bounds__(256)
void k_ta_gemm(const float* __restrict__ t1, const float* __restrict__ W2A,
               const float* __restrict__ bA, uint* __restrict__ TAb)
{
    __shared__ float t1_s[8][132];
    const int l = blockIdx.y, tid = threadIdx.x;
    const int r0 = blockIdx.x * 8;
    const float* W2Al = W2A + (size_t)l * 16384;

    for (int q = tid; q < 8 * 32; q += 256) {
        int ni = q >> 5, j4 = (q & 31) * 4;
        int row = min(r0 + ni, TBM);
        *reinterpret_cast<float4*>(&t1_s[ni][j4]) =
            *reinterpret_cast<const float4*>(&t1[(size_t)row * 128 + j4]);
    }
    __syncthreads();

    const int c = tid & 127, ng = tid >> 7;
    float a[4];
    #pragma unroll
    for (int r = 0; r < 4; ++r) a[r] = bA[l * 128 + c];
    #pragma unroll 4
    for (int k4 = 0; k4 < 128; k4 += 4) {
        float w0 = W2Al[(k4 + 0) * 128 + c];
        float w1 = W2Al[(k4 + 1) * 128 + c];
        float w2v = W2Al[(k4 + 2) * 128 + c];
        float w3 = W2Al[(k4 + 3) * 128 + c];
        #pragma unroll
        for (int r = 0; r < 4; ++r) {
            const float4 xv = *reinterpret_cast<const float4*>(&t1_s[ng * 4 + r][k4]);
            a[r] += xv.x * w0 + xv.y * w1 + xv.z * w2v + xv.w * w3;
        }
    }
    #pragma unroll
    for (int r = 0; r < 4; ++r) {
        float hi = __shfl_down(a[r], 1, 64);
        int row = r0 + ng * 4 + r;
        if (((c & 1) == 0) && row <= TBM)
            TAb[(size_t)l * TROWS * 64 + (size_t)row * 64 + (c >> 1)] = pack2bf(a[r], hi);
    }
}

// ---------------- TG table ----------------
__global__ __launch_bounds__(256)
void k_tg(const float* __restrict__ t1, const float* __restrict__ W2G,
          const float* __restrict__ bG, float* __restrict__ TG)
{
    const int l = blockIdx.y, tid = threadIdx.x;
    const int row = blockIdx.x * 32 + (tid >> 3), h = tid & 7;
    if (row > TBM) return;
    const float* W2Gl = W2G + (size_t)l * 1024;
    const float* t1r = &t1[(size_t)row * 128];
    float s = bG[l * 8 + h];
    #pragma unroll 8
    for (int k = 0; k < 128; ++k)
        s += t1r[k] * W2Gl[k * 8 + h];
    TG[(size_t)l * TROWS * 8 + (size_t)row * 8 + h] = s;
}

// ---------------- pack FFN weights into MFMA B-fragment order (bf16) ----------------
// Wf1x block (nt,kt): nt in [0,32), kt in [0,4): lane l, j: Wf1[kt*32+(l>>4)*8+j][nt*16+(l&15)]
// Wf2x block (nt,kt): nt in [0,8),  kt in [0,16)
__global__ __launch_bounds__(64)
void k_packw(const float* __restrict__ Wf1, const float* __restrict__ Wf2,
             ushort* __restrict__ Wf1x, ushort* __restrict__ Wf2x)
{
    const int l = blockIdx.y, bx = blockIdx.x, lane = threadIdx.x;
    if (bx < 128) {
        const int nt = bx >> 2, kt = bx & 3;
        const float* src = Wf1 + (size_t)l * 65536;
        ushort* dst = Wf1x + (size_t)l * 65536 + ((size_t)bx * 64 + lane) * 8;
        #pragma unroll
        for (int j = 0; j < 8; ++j)
            dst[j] = f2bf(src[(size_t)(kt * 32 + (lane >> 4) * 8 + j) * 512 + nt * 16 + (lane & 15)]);
    } else {
        const int b2x = bx - 128;
        const int nt = b2x >> 4, kt = b2x & 15;
        const float* src = Wf2 + (size_t)l * 65536;
        ushort* dst = Wf2x + (size_t)l * 65536 + ((size_t)b2x * 64 + lane) * 8;
        #pragma unroll
        for (int j = 0; j < 8; ++j)
            dst[j] = f2bf(src[(size_t)(kt * 32 + (lane >> 4) * 8 + j) * 128 + nt * 16 + (lane & 15)]);
    }
}

// ---------------- rms_sh norm (f32 out + packed bf16 out) ----------------
__global__ __launch_bounds__(128)
void k_rms(const float* __restrict__ x, float* __restrict__ xn, uint* __restrict__ xnb)
{
    int n = blockIdx.x, c = threadIdx.x;
    float v = x[n * 128 + c];
    float ss = v * v;
    #pragma unroll
    for (int o = 32; o > 0; o >>= 1) ss += __shfl_down(ss, o, 64);
    __shared__ float red[2];
    if ((c & 63) == 0) red[c >> 6] = ss;
    __syncthreads();
    float tot = red[0] + red[1];
    float r = v * rsqrtf(tot * (1.0f / 1152.0f) + 1e-6f);
    xn[n * 128 + c] = r;
    float hi = __shfl_down(r, 1, 64);
    if ((c & 1) == 0) xnb[n * 64 + (c >> 1)] = pack2bf(r, hi);
}

// ---------------- node GEMMs -> packed bf16 V, Ps, Pd ----------------
__global__ __launch_bounds__(256)
void k_nodegemm(const float* __restrict__ xn, const float* __restrict__ Wvl,
                const float* __restrict__ Wa1l, uint* __restrict__ Vb,
                uint* __restrict__ Psb, uint* __restrict__ Pdb)
{
    const float* W; uint* O;
    if (blockIdx.y == 0)      { W = Wvl;              O = Vb;  }
    else if (blockIdx.y == 1) { W = Wa1l;             O = Psb; }
    else                      { W = Wa1l + 128 * 128; O = Pdb; }

    __shared__ float xs[8][132];
    const int tid = threadIdx.x;
    const int n0 = blockIdx.x * 8;
    for (int q = tid; q < 8 * 32; q += 256) {
        int ni = q >> 5, j4 = (q & 31) * 4;
        *reinterpret_cast<float4*>(&xs[ni][j4]) =
            *reinterpret_cast<const float4*>(&xn[(size_t)(n0 + ni) * 128 + j4]);
    }
    __syncthreads();

    const int c = tid & 127, ng = tid >> 7;
    float a[4] = {0.f, 0.f, 0.f, 0.f};
    #pragma unroll 4
    for (int j4 = 0; j4 < 128; j4 += 4) {
        float w0 = W[(j4 + 0) * 128 + c];
        float w1 = W[(j4 + 1) * 128 + c];
        float w2 = W[(j4 + 2) * 128 + c];
        float w3 = W[(j4 + 3) * 128 + c];
        #pragma unroll
        for (int i = 0; i < 4; ++i) {
            const float4 xv = *reinterpret_cast<const float4*>(&xs[ng * 4 + i][j4]);
            a[i] += xv.x * w0 + xv.y * w1 + xv.z * w2 + xv.w * w3;
        }
    }
    #pragma unroll
    for (int i = 0; i < 4; ++i) {
        float hi = __shfl_down(a[i], 1, 64);
        if ((c & 1) == 0)
            O[(size_t)(n0 + ng * 4 + i) * 64 + (c >> 1)] = pack2bf(a[i], hi);
    }
}

// ---------------- CSR build ----------------
__global__ __launch_bounds__(256)
void k_hist(const int* __restrict__ eidx, int* __restrict__ deg)
{
    int e = blockIdx.x * 256 + threadIdx.x;
    if (e < NE) atomicAdd(&deg[eidx[NE + e]], 1);
}

__global__ __launch_bounds__(1024)
void k_scan(const int* __restrict__ deg, int* __restrict__ off, int* __restrict__ cursor)
{
    __shared__ int part[1024];
    const int t = threadIdx.x;
    const int base = t * 6;
    int loc[6]; int s = 0;
    #pragma unroll
    for (int i = 0; i < 6; ++i) {
        int d = (base + i < NN) ? deg[base + i] : 0;
        loc[i] = s; s += d;
    }
    part[t] = s;
    __syncthreads();
    for (int o = 1; o < 1024; o <<= 1) {
        int v = (t >= o) ? part[t - o] : 0;
        __syncthreads();
        part[t] += v;
        __syncthreads();
    }
    int pre = (t > 0) ? part[t - 1] : 0;
    #pragma unroll
    for (int i = 0; i < 6; ++i) {
        if (base + i < NN) {
            int v = pre + loc[i];
            off[base + i] = v;
            cursor[base + i] = v;
        }
    }
    if (t == 1023) off[NN] = part[1023];
}

__global__ __launch_bounds__(256)
void k_fill(const int* __restrict__ eidx, int* __restrict__ cursor, int* __restrict__ elist)
{
    int e = blockIdx.x * 256 + threadIdx.x;
    if (e < NE) {
        int d = eidx[NE + e];
        int p = atomicAdd(&cursor[d], 1);
        elist[p] = e;
    }
}

// ---------------- attention via bf16 tables ----------------
__global__ __launch_bounds__(256)
void k_attn(const int* __restrict__ eidx, const int* __restrict__ bondf,
            const float* __restrict__ dist,
            const uint* __restrict__ Psb, const uint* __restrict__ Pdb,
            const uint* __restrict__ TAbl, const float* __restrict__ TGl,
            const uint* __restrict__ BAcbl, const float* __restrict__ BGcl,
            const float* __restrict__ Wa2l,
            float* __restrict__ num, float* __restrict__ sums)
{
    __shared__ float t_s[32][132];
    __shared__ float gate_s[32][8];
    __shared__ int dst_s[32];
    const int tid = threadIdx.x;
    const int e0 = blockIdx.x * 32;

    {
        const int ei = tid >> 3, g = tid & 7;
        const int eid = min(e0 + ei, NE - 1);
        const int sn = eidx[eid], dn = eidx[NE + eid];
        float d = dist[eid];
        float u = d * ((float)TBM / 5.0f);
        int i = min((int)u, TBM - 1);
        float f = u - (float)i, f1 = 1.f - f;
        int cb = bondf[eid * 3 + 0] * 64 + bondf[eid * 3 + 1] * 8 + bondf[eid * 3 + 2];

        uint ps[8], pd[8], t0[8], t1v[8], ba[8];
        {
            const uint4* p = reinterpret_cast<const uint4*>(&Psb[(size_t)sn * 64 + g * 8]);
            uint4 a = p[0], b = p[1];
            ps[0]=a.x; ps[1]=a.y; ps[2]=a.z; ps[3]=a.w; ps[4]=b.x; ps[5]=b.y; ps[6]=b.z; ps[7]=b.w;
            p = reinterpret_cast<const uint4*>(&Pdb[(size_t)dn * 64 + g * 8]);
            a = p[0]; b = p[1];
            pd[0]=a.x; pd[1]=a.y; pd[2]=a.z; pd[3]=a.w; pd[4]=b.x; pd[5]=b.y; pd[6]=b.z; pd[7]=b.w;
            p = reinterpret_cast<const uint4*>(&TAbl[(size_t)i * 64 + g * 8]);
            a = p[0]; b = p[1];
            t0[0]=a.x; t0[1]=a.y; t0[2]=a.z; t0[3]=a.w; t0[4]=b.x; t0[5]=b.y; t0[6]=b.z; t0[7]=b.w;
            p = reinterpret_cast<const uint4*>(&TAbl[(size_t)(i + 1) * 64 + g * 8]);
            a = p[0]; b = p[1];
            t1v[0]=a.x; t1v[1]=a.y; t1v[2]=a.z; t1v[3]=a.w; t1v[4]=b.x; t1v[5]=b.y; t1v[6]=b.z; t1v[7]=b.w;
            p = reinterpret_cast<const uint4*>(&BAcbl[(size_t)cb * 64 + g * 8]);
            a = p[0]; b = p[1];
            ba[0]=a.x; ba[1]=a.y; ba[2]=a.z; ba[3]=a.w; ba[4]=b.x; ba[5]=b.y; ba[6]=b.z; ba[7]=b.w;
        }
        float* tr = &t_s[ei][g * 16];
        #pragma unroll
        for (int q = 0; q < 8; ++q) {
            float2 vs = up2(ps[q]), vd = up2(pd[q]), v0 = up2(t0[q]), v1 = up2(t1v[q]), vb = up2(ba[q]);
            tr[2 * q + 0] = siluf(vs.x + vd.x + f1 * v0.x + f * v1.x + vb.x);
            tr[2 * q + 1] = siluf(vs.y + vd.y + f1 * v0.y + f * v1.y + vb.y);
        }
        if (g == 0) {
            dst_s[ei] = dn;
            const float4* tg0 = reinterpret_cast<const float4*>(&TGl[(size_t)i * 8]);
            const float4* bg4 = reinterpret_cast<const float4*>(&BGcl[(size_t)cb * 8]);
            #pragma unroll
            for (int q = 0; q < 2; ++q) {
                float4 g0 = tg0[q], g1 = tg0[q + 2], bb = bg4[q];
                gate_s[ei][4 * q + 0] = f1 * g0.x + f * g1.x + bb.x;
                gate_s[ei][4 * q + 1] = f1 * g0.y + f * g1.y + bb.y;
                gate_s[ei][4 * q + 2] = f1 * g0.z + f * g1.z + bb.z;
                gate_s[ei][4 * q + 3] = f1 * g0.w + f * g1.w + bb.w;
            }
        }
    }
    __syncthreads();

    {
        const int ei = tid >> 3, h = tid & 7;
        const int eid = e0 + ei;
        float lg = 0.f;
        for (int j4 = 0; j4 < 128; j4 += 4) {
            const float4 tv = *reinterpret_cast<const float4*>(&t_s[ei][j4]);
            lg += tv.x * Wa2l[(j4 + 0) * 8 + h] + tv.y * Wa2l[(j4 + 1) * 8 + h]
                + tv.z * Wa2l[(j4 + 2) * 8 + h] + tv.w * Wa2l[(j4 + 3) * 8 + h];
        }
        if (eid < NE) {
            float ex = __expf(lg);
            num[(size_t)eid * 8 + h] = ex * sigmf(gate_s[ei][h]);
            atomicAdd(&sums[(size_t)dst_s[ei] * 8 + h], ex);
        }
    }
}

// ---------------- fused aggregate + out_proj ----------------
__global__ __launch_bounds__(128)
void k_aggo(const int* __restrict__ off, const int* __restrict__ elist,
            const int* __restrict__ eidx, const float* __restrict__ num,
            const float* __restrict__ sums, const uint* __restrict__ Vb,
            const float* __restrict__ Wol, float* __restrict__ x)
{
    __shared__ float a_s[128];
    const int n = blockIdx.x, c = threadIdx.x;
    const int s = off[n], t = off[n + 1];
    const int h = c >> 4;
    float sinv = 1.f / (sums[(size_t)n * 8 + h] + 1e-9f);
    float acc = 0.f;
    int e_next = (s < t) ? elist[s] : 0;
    for (int i = s; i < t; ++i) {
        int e = e_next;
        if (i + 1 < t) e_next = elist[i + 1];
        int sn = eidx[e];
        float cf = num[(size_t)e * 8 + h];
        uint u = Vb[(size_t)sn * 64 + (c >> 1)];
        float v = (c & 1) ? __uint_as_float(u & 0xffff0000u) : __uint_as_float(u << 16);
        acc += cf * v;
    }
    a_s[c] = acc * sinv;
    __syncthreads();
    float o = 0.f;
    #pragma unroll 4
    for (int j4 = 0; j4 < 128; j4 += 4) {
        const float4 a4 = *reinterpret_cast<const float4*>(&a_s[j4]);
        o += a4.x * Wol[(j4 + 0) * 128 + c] + a4.y * Wol[(j4 + 1) * 128 + c]
           + a4.z * Wol[(j4 + 2) * 128 + c] + a4.w * Wol[(j4 + 3) * 128 + c];
    }
    x[n * 128 + c] += o;
}

// ---------------- FFN via MFMA: x += silu(xn@Wf1)@Wf2, 16 nodes/block ----------------
__global__ __launch_bounds__(256)
void k_ffn_mfma(float* __restrict__ x, const ushort* __restrict__ xnb,
                const ushort* __restrict__ Wf1xl, const ushort* __restrict__ Wf2xl)
{
    __shared__ ushort a_s[16][136];     // 272B rows: stride 68 dwords (== 4 mod 32)
    __shared__ ushort h_s[16][520];     // 1040B rows: stride 260 dwords (== 4 mod 32)
    const int tid = threadIdx.x;
    const int n0 = blockIdx.x * 16;

    {   // stage A tile (16 nodes x 128 ch, bf16): 16B per thread
        int row = tid >> 4, c8 = (tid & 15) * 8;
        *reinterpret_cast<uint4*>(&a_s[row][c8]) =
            *reinterpret_cast<const uint4*>(&xnb[((size_t)(n0 + row) * 64 + (c8 >> 1)) * 2]);
    }
    __syncthreads();

    const int l  = tid & 63;
    const int wq = tid >> 6;            // wave 0..3
    const int lr = l & 15, lk = l >> 4;

    // GEMM1: H[16][512], this wave: cols [wq*128, +128)
    float4v acc[8];
    #pragma unroll
    for (int nf = 0; nf < 8; ++nf) acc[nf] = (float4v){0.f, 0.f, 0.f, 0.f};
    #pragma unroll
    for (int ks = 0; ks < 4; ++ks) {
        short8v af = *reinterpret_cast<const short8v*>(&a_s[lr][lk * 8 + ks * 32]);
        #pragma unroll
        for (int nf = 0; nf < 8; ++nf) {
            int nt = wq * 8 + nf;
            short8v bf = *reinterpret_cast<const short8v*>(&Wf1xl[((size_t)(nt * 4 + ks) * 64 + l) * 8]);
            acc[nf] = __builtin_amdgcn_mfma_f32_16x16x32_bf16(af, bf, acc[nf], 0, 0, 0);
        }
    }
    // silu -> bf16 H in LDS (pair-pack via shfl_xor; even lanes store uint)
    #pragma unroll
    for (int nf = 0; nf < 8; ++nf) {
        #pragma unroll
        for (int r = 0; r < 4; ++r) {
            float v = siluf(acc[nf][r]);
            float vn = __shfl_xor(v, 1, 64);
            if ((l & 1) == 0) {
                int row = lk * 4 + r;
                int col = wq * 128 + nf * 16 + lr;     // even
                *reinterpret_cast<uint*>(&h_s[row][col]) = pack2bf(v, vn);
            }
        }
    }
    __syncthreads();

    // GEMM2: X[16][128] += H @ Wf2; this wave: cols [wq*32, +32)
    float4v acc2[2];
    acc2[0] = (float4v){0.f, 0.f, 0.f, 0.f};
    acc2[1] = (float4v){0.f, 0.f, 0.f, 0.f};
    #pragma unroll 4
    for (int ks = 0; ks < 16; ++ks) {
        short8v af = *reinterpret_cast<const short8v*>(&h_s[lr][lk * 8 + ks * 32]);
        #pragma unroll
        for (int nf = 0; nf < 2; ++nf) {
            int nt = wq * 2 + nf;
            short8v bf = *reinterpret_cast<const short8v*>(&Wf2xl[((size_t)(nt * 16 + ks) * 64 + l) * 8]);
            acc2[nf] = __builtin_amdgcn_mfma_f32_16x16x32_bf16(af, bf, acc2[nf], 0, 0, 0);
        }
    }
    #pragma unroll
    for (int nf = 0; nf < 2; ++nf) {
        #pragma unroll
        for (int r = 0; r < 4; ++r) {
            int row = lk * 4 + r;
            int col = wq * 32 + nf * 16 + lr;
            x[(size_t)(n0 + row) * 128 + col] += acc2[nf][r];
        }
    }
}

// ---------------- finalize ----------------
__global__ __launch_bounds__(128)
void k_finalize(const float* __restrict__ x, float* __restrict__ out)
{
    int n = blockIdx.x, c = threadIdx.x;
    float v = x[n * 128 + c];
    float ss = v * v;
    #pragma unroll
    for (int o = 32; o > 0; o >>= 1) ss += __shfl_down(ss, o, 64);
    __shared__ float red[2];
    if ((c & 63) == 0) red[c >> 6] = ss;
    __syncthreads();
    float r = rsqrtf((red[0] + red[1]) * (1.0f / 1152.0f) + 1e-6f);
    size_t base = (size_t)n * 1152;
    out[base + c] = v * r;
    #pragma unroll
    for (int k = 1; k < 9; ++k) out[base + k * 128 + c] = 0.f;
}

extern "C" void kernel_launch(void* const* d_in, const int* in_sizes, int n_in,
                              void* d_out, int out_size, void* d_ws, size_t ws_size,
                              hipStream_t stream)
{
    const int*   atom_feats = (const int*)d_in[0];
    const int*   bond_feats = (const int*)d_in[1];
    const int*   edge_index = (const int*)d_in[2];
    const float* edge_dist  = (const float*)d_in[3];
    const float* atom_emb   = (const float*)d_in[4];
    const float* bond_emb   = (const float*)d_in[5];
    const float* W_rbf1     = (const float*)d_in[6];
    const float* b_rbf1     = (const float*)d_in[7];
    const float* W_rbf2     = (const float*)d_in[8];
    const float* b_rbf2     = (const float*)d_in[9];
    const float* Wa1        = (const float*)d_in[10];
    const float* Wa2        = (const float*)d_in[11];
    const float* Wv         = (const float*)d_in[12];
    const float* Wg         = (const float*)d_in[13];
    const float* Wo         = (const float*)d_in[14];
    const float* Wf1        = (const float*)d_in[15];
    const float* Wf2        = (const float*)d_in[16];
    float* out = (float*)d_out;

    float* ws   = (float*)d_ws;
    float* x    = ws;                           // NN*128
    float* xn   = x    + NN * 128;              // NN*128
    float* t1   = xn   + NN * 128;              // TROWS*128
    float* sums = t1   + (size_t)TROWS * 128;   // NN*8
    float* num  = sums + NN * 8;                // NE*8
    float* W2A  = num  + (size_t)NE * 8;        // 2*16384
    float* W2G  = W2A  + 2 * 16384;             // 2*1024
    float* bA   = W2G  + 2 * 1024;              // 2*128
    float* bG   = bA   + 2 * 128;               // 16
    float* TG   = bG   + 16;                    // 2*TROWS*8
    float* BGc  = TG   + 2 * (size_t)TROWS * 8; // 2*512*8
    uint* Vb    = (uint*)(BGc + 2 * 512 * 8);   // NN*64
    uint* Psb   = Vb  + NN * 64;
    uint* Pdb   = Psb + NN * 64;
    uint* xnb   = Pdb + NN * 64;                // NN*64
    uint* TAb   = xnb + NN * 64;                // 2*TROWS*64
    uint* BAcb  = TAb + 2 * (size_t)TROWS * 64; // 2*512*64
    ushort* Wf1x = (ushort*)(BAcb + 2 * 512 * 64);  // 2*65536
    ushort* Wf2x = Wf1x + 2 * 65536;                // 2*65536
    int* deg    = (int*)(Wf2x + 2 * 65536);
    int* off    = deg + NN;
    int* cursor = off + NN + 1;
    int* elist  = cursor + NN;

    k_atom_embed<<<NN, 128, 0, stream>>>(atom_feats, atom_emb, x);

    // tables + packed weights (once per call)
    k_t1<<<(TBM + 16) / 16, 256, 0, stream>>>(W_rbf1, b_rbf1, t1);
    k_w2a<<<dim3(18, 2), 256, 0, stream>>>(W_rbf2, b_rbf2, Wa1, Wg, W2A, W2G, bA, bG);
    k_bondtabs<<<dim3(512, 2), 128, 0, stream>>>(bond_emb, Wa1, Wg, BAcb, BGc);
    k_ta_gemm<<<dim3((TBM + 8) / 8, 2), 256, 0, stream>>>(t1, W2A, bA, TAb);
    k_tg<<<dim3((TBM + 32) / 32, 2), 256, 0, stream>>>(t1, W2G, bG, TG);
    k_packw<<<dim3(256, 2), 64, 0, stream>>>(Wf1, Wf2, Wf1x, Wf2x);

    // CSR (dst is layer-invariant)
    hipMemsetAsync(deg, 0, NN * sizeof(int), stream);
    k_hist<<<(NE + 255) / 256, 256, 0, stream>>>(edge_index, deg);
    k_scan<<<1, 1024, 0, stream>>>(deg, off, cursor);
    k_fill<<<(NE + 255) / 256, 256, 0, stream>>>(edge_index, cursor, elist);

    for (int l = 0; l < 2; ++l) {
        k_rms<<<NN, 128, 0, stream>>>(x, xn, xnb);
        k_nodegemm<<<dim3(NN / 8, 3), 256, 0, stream>>>(xn, Wv + (size_t)l * 128 * 128,
                                                        Wa1 + (size_t)l * 384 * 128, Vb, Psb, Pdb);
        hipMemsetAsync(sums, 0, NN * 8 * sizeof(float), stream);
        k_attn<<<(NE + 31) / 32, 256, 0, stream>>>(edge_index, bond_feats, edge_dist,
            Psb, Pdb,
            TAb + (size_t)l * TROWS * 64, TG + (size_t)l * TROWS * 8,
            BAcb + (size_t)l * 512 * 64, BGc + (size_t)l * 512 * 8,
            Wa2 + (size_t)l * 128 * 8, num, sums);
        k_aggo<<<NN, 128, 0, stream>>>(off, elist, edge_index, num, sums, Vb,
                                       Wo + (size_t)l * 128 * 128, x);
        k_rms<<<NN, 128, 0, stream>>>(x, xn, xnb);
        k_ffn_mfma<<<NN / 16, 256, 0, stream>>>(x, (const ushort*)xnb,
            Wf1x + (size_t)l * 65536, Wf2x + (size_t)l * 65536);
    }
    k_finalize<<<NN, 128, 0, stream>>>(x, out);
}

// Round 6
// 245.254 us; speedup vs baseline: 6.5727x; 1.3204x over previous
//
#include <hip/hip_runtime.h>

#define NN 6000
#define NE 150000
#define TBM 2048
#define TROWS (TBM + 1)

typedef unsigned int uint;
typedef unsigned short ushort;
typedef __attribute__((ext_vector_type(8))) short short8v;
typedef __attribute__((ext_vector_type(4))) float float4v;

__device__ __forceinline__ float siluf(float x) { return x / (1.f + __expf(-x)); }
__device__ __forceinline__ float sigmf(float x) { return 1.f / (1.f + __expf(-x)); }
__device__ __forceinline__ uint pack2bf(float lo, float hi) {
    uint ul = __float_as_uint(lo);
    ul = (ul + 0x7fffu + ((ul >> 16) & 1u)) >> 16;
    uint uh = __float_as_uint(hi);
    uh = ((uh + 0x7fffu + ((uh >> 16) & 1u)) >> 16) << 16;
    return ul | uh;
}
__device__ __forceinline__ ushort f2bf(float f) {
    uint u = __float_as_uint(f);
    return (ushort)((u + 0x7fffu + ((u >> 16) & 1u)) >> 16);
}
__device__ __forceinline__ float2 up2(uint u) {
    return make_float2(__uint_as_float(u << 16), __uint_as_float(u & 0xffff0000u));
}

// ---------------- atom embedding ----------------
__global__ __launch_bounds__(128)
void k_atom_embed(const int* __restrict__ af, const float* __restrict__ aemb,
                  float* __restrict__ x)
{
    int n = blockIdx.x, c = threadIdx.x;
    float s = 0.f;
    #pragma unroll
    for (int f = 0; f < 4; ++f) {
        int idx = af[n * 4 + f];
        s += aemb[(f * 10 + idx) * 128 + c];
    }
    x[n * 128 + c] = s;
}

// ---------------- fold W2 through per-layer weights ----------------
__global__ __launch_bounds__(256)
void k_w2a(const float* __restrict__ W2, const float* __restrict__ b2,
           const float* __restrict__ Wa1, const float* __restrict__ Wg,
           float* __restrict__ W2A, float* __restrict__ W2G,
           float* __restrict__ bA, float* __restrict__ bG)
{
    const int l = blockIdx.y;
    const float* Wa1e = Wa1 + (size_t)l * 384 * 128 + 256 * 128;
    const float* Wgl  = Wg  + (size_t)l * 128 * 8;
    const int tid = threadIdx.x;

    if (blockIdx.x < 16) {
        __shared__ float w2_s[8][132];
        const int i0 = blockIdx.x * 8;
        for (int q = tid; q < 8 * 32; q += 256) {
            int ni = q >> 5, j4 = (q & 31) * 4;
            *reinterpret_cast<float4*>(&w2_s[ni][j4]) =
                *reinterpret_cast<const float4*>(&W2[(size_t)(i0 + ni) * 128 + j4]);
        }
        __syncthreads();
        const int j = tid & 127, ng = tid >> 7;
        float a[4] = {0.f, 0.f, 0.f, 0.f};
        #pragma unroll 4
        for (int k4 = 0; k4 < 128; k4 += 4) {
            float w0 = Wa1e[(k4 + 0) * 128 + j];
            float w1 = Wa1e[(k4 + 1) * 128 + j];
            float w2v = Wa1e[(k4 + 2) * 128 + j];
            float w3 = Wa1e[(k4 + 3) * 128 + j];
            #pragma unroll
            for (int r = 0; r < 4; ++r) {
                const float4 xv = *reinterpret_cast<const float4*>(&w2_s[ng * 4 + r][k4]);
                a[r] += xv.x * w0 + xv.y * w1 + xv.z * w2v + xv.w * w3;
            }
        }
        #pragma unroll
        for (int r = 0; r < 4; ++r)
            W2A[(size_t)l * 16384 + (size_t)(i0 + ng * 4 + r) * 128 + j] = a[r];
    } else if (blockIdx.x == 16) {
        const int i = tid & 127, hq = tid >> 7;
        float a[4] = {0.f, 0.f, 0.f, 0.f};
        for (int k = 0; k < 128; ++k) {
            float w = W2[(size_t)i * 128 + k];
            const float4 g4 = *reinterpret_cast<const float4*>(&Wgl[k * 8 + hq * 4]);
            a[0] += w * g4.x; a[1] += w * g4.y; a[2] += w * g4.z; a[3] += w * g4.w;
        }
        #pragma unroll
        for (int q = 0; q < 4; ++q)
            W2G[(size_t)l * 1024 + (size_t)i * 8 + hq * 4 + q] = a[q];
    } else {
        if (tid < 128) {
            float s = 0.f;
            for (int k = 0; k < 128; ++k) s += b2[k] * Wa1e[k * 128 + tid];
            bA[l * 128 + tid] = s;
        } else if (tid < 136) {
            int h = tid - 128;
            float s = 0.f;
            for (int k = 0; k < 128; ++k) s += b2[k] * Wgl[k * 8 + h];
            bG[l * 8 + h] = s;
        }
    }
}

// ---------------- bond-combo tables ----------------
__global__ __launch_bounds__(128)
void k_bondtabs(const float* __restrict__ bemb, const float* __restrict__ Wa1,
                const float* __restrict__ Wg,
                uint* __restrict__ BAcb, float* __restrict__ BGc)
{
    const int l = blockIdx.y, cb = blockIdx.x, c = threadIdx.x;
    const float* Wa1e = Wa1 + (size_t)l * 384 * 128 + 256 * 128;
    const float* Wgl  = Wg  + (size_t)l * 128 * 8;
    const int b[3] = {cb >> 6, (cb >> 3) & 7, cb & 7};

    float s = 0.f;
    #pragma unroll
    for (int f = 0; f < 3; ++f) {
        const float* er = &bemb[(size_t)(f * 8 + b[f]) * 128];
        for (int k = 0; k < 128; ++k)
            s += er[k] * Wa1e[k * 128 + c];
    }
    float hi = __shfl_down(s, 1, 64);
    if ((c & 1) == 0)
        BAcb[(size_t)l * 512 * 64 + (size_t)cb * 64 + (c >> 1)] = pack2bf(s, hi);

    if (c < 8) {
        float g = 0.f;
        #pragma unroll
        for (int f = 0; f < 3; ++f) {
            const float* er = &bemb[(size_t)(f * 8 + b[f]) * 128];
            for (int k = 0; k < 128; ++k)
                g += er[k] * Wgl[k * 8 + c];
        }
        BGc[(size_t)l * 512 * 8 + (size_t)cb * 8 + c] = g;
    }
}

// ---------------- fused t1 + TA + TG table build (8 rows/block) ----------------
__global__ __launch_bounds__(256)
void k_t1ta(const float* __restrict__ W1, const float* __restrict__ b1,
            const float* __restrict__ W2A, const float* __restrict__ W2G,
            const float* __restrict__ bA, const float* __restrict__ bG,
            uint* __restrict__ TAb, float* __restrict__ TG)
{
    __shared__ float rbf_s[8][32];
    __shared__ int   bs_s[8];
    __shared__ float t1_s[8][132];
    const int l = blockIdx.y, tid = threadIdx.x;
    const int r0 = blockIdx.x * 8;

    {   // rbf windows: 8 rows x 32 = 256 threads exactly
        int ri = tid >> 5, j = tid & 31;
        int row = min(r0 + ri, TBM);
        float d = (float)row * (5.0f / TBM);
        const float step = 5.0f / 511.0f;
        const float invw = 512.0f / 5.0f;
        int b0 = (int)(d * (511.0f / 5.0f) + 0.5f);
        int bs = min(max(b0 - 16, 0), 512 - 32);
        if (j == 0) bs_s[ri] = bs;
        float z = (d - (float)(bs + j) * step) * invw;
        rbf_s[ri][j] = __expf(-z * z);
    }
    __syncthreads();

    #pragma unroll
    for (int pass = 0; pass < 4; ++pass) {
        int idx = pass * 256 + tid;
        int ri = idx >> 7, c = idx & 127;
        int bs = bs_s[ri];
        float t = b1[c];
        #pragma unroll
        for (int j = 0; j < 32; ++j)
            t += rbf_s[ri][j] * W1[(bs + j) * 128 + c];
        t1_s[ri][c] = siluf(t);
    }
    __syncthreads();

    // TA GEMM: 8 rows x 128 cols
    const float* W2Al = W2A + (size_t)l * 16384;
    const int c = tid & 127, ng = tid >> 7;
    float a[4];
    #pragma unroll
    for (int r = 0; r < 4; ++r) a[r] = bA[l * 128 + c];
    #pragma unroll 4
    for (int k4 = 0; k4 < 128; k4 += 4) {
        float w0 = W2Al[(k4 + 0) * 128 + c];
        float w1 = W2Al[(k4 + 1) * 128 + c];
        float w2v = W2Al[(k4 + 2) * 128 + c];
        float w3 = W2Al[(k4 + 3) * 128 + c];
        #pragma unroll
        for (int r = 0; r < 4; ++r) {
            const float4 xv = *reinterpret_cast<const float4*>(&t1_s[ng * 4 + r][k4]);
            a[r] += xv.x * w0 + xv.y * w1 + xv.z * w2v + xv.w * w3;
        }
    }
    #pragma unroll
    for (int r = 0; r < 4; ++r) {
        float hi = __shfl_down(a[r], 1, 64);
        int row = r0 + ng * 4 + r;
        if (((c & 1) == 0) && row <= TBM)
            TAb[(size_t)l * TROWS * 64 + (size_t)row * 64 + (c >> 1)] = pack2bf(a[r], hi);
    }

    // TG: 8 rows x 8 heads on 64 threads
    if (tid < 64) {
        int ri = tid >> 3, h = tid & 7;
        int row = r0 + ri;
        if (row <= TBM) {
            const float* W2Gl = W2G + (size_t)l * 1024;
            float s = bG[l * 8 + h];
            #pragma unroll 8
            for (int k = 0; k < 128; ++k)
                s += t1_s[ri][k] * W2Gl[k * 8 + h];
            TG[(size_t)l * TROWS * 8 + (size_t)row * 8 + h] = s;
        }
    }
}

// ---------------- pack weights into MFMA B-fragment order (bf16) ----------------
// bx<128: Wf1 (nt 0..31, kt 0..3); bx in [128,256): Wf2 (nt 0..7, kt 0..15);
// bx in [256,352): {Wv, Wa1src, Wa1dst} each 32 blocks (nt 0..7, kt 0..3), ld=128
__global__ __launch_bounds__(64)
void k_packw(const float* __restrict__ Wf1, const float* __restrict__ Wf2,
             const float* __restrict__ Wv, const float* __restrict__ Wa1,
             ushort* __restrict__ Wf1x, ushort* __restrict__ Wf2x,
             ushort* __restrict__ Wvx, ushort* __restrict__ Wa1sx,
             ushort* __restrict__ Wa1dx)
{
    const int l = blockIdx.y, bx = blockIdx.x, lane = threadIdx.x;
    if (bx < 128) {
        const int nt = bx >> 2, kt = bx & 3;
        const float* src = Wf1 + (size_t)l * 65536;
        ushort* dst = Wf1x + (size_t)l * 65536 + ((size_t)bx * 64 + lane) * 8;
        #pragma unroll
        for (int j = 0; j < 8; ++j)
            dst[j] = f2bf(src[(size_t)(kt * 32 + (lane >> 4) * 8 + j) * 512 + nt * 16 + (lane & 15)]);
    } else if (bx < 256) {
        const int b2x = bx - 128;
        const int nt = b2x >> 4, kt = b2x & 15;
        const float* src = Wf2 + (size_t)l * 65536;
        ushort* dst = Wf2x + (size_t)l * 65536 + ((size_t)b2x * 64 + lane) * 8;
        #pragma unroll
        for (int j = 0; j < 8; ++j)
            dst[j] = f2bf(src[(size_t)(kt * 32 + (lane >> 4) * 8 + j) * 128 + nt * 16 + (lane & 15)]);
    } else {
        const int b3 = bx - 256;
        const int mat = b3 >> 5, blk = b3 & 31;
        const int nt = blk >> 2, kt = blk & 3;
        const float* src;
        ushort* dst;
        if (mat == 0)      { src = Wv  + (size_t)l * 16384;             dst = Wvx   + (size_t)l * 16384; }
        else if (mat == 1) { src = Wa1 + (size_t)l * 384 * 128;         dst = Wa1sx + (size_t)l * 16384; }
        else               { src = Wa1 + (size_t)l * 384 * 128 + 16384; dst = Wa1dx + (size_t)l * 16384; }
        dst += ((size_t)blk * 64 + lane) * 8;
        #pragma unroll
        for (int j = 0; j < 8; ++j)
            dst[j] = f2bf(src[(size_t)(kt * 32 + (lane >> 4) * 8 + j) * 128 + nt * 16 + (lane & 15)]);
    }
}

// ---------------- fused rms + 3 node GEMMs via MFMA (16 nodes/block) ----------------
__global__ __launch_bounds__(256)
void k_rmsgemm(const float* __restrict__ x,
               const ushort* __restrict__ Wvx, const ushort* __restrict__ Wa1sx,
               const ushort* __restrict__ Wa1dx,
               uint* __restrict__ Vb, uint* __restrict__ Psb, uint* __restrict__ Pdb)
{
    __shared__ ushort a_s[16][136];
    const int tid = threadIdx.x, n0 = blockIdx.x * 16;

    {   // rms: thread handles node tid>>4, 8 channels
        int ni = tid >> 4, c8 = (tid & 15) * 8;
        const float* xr = &x[(size_t)(n0 + ni) * 128 + c8];
        float4 v0 = *reinterpret_cast<const float4*>(xr);
        float4 v1 = *reinterpret_cast<const float4*>(xr + 4);
        float ss = v0.x * v0.x + v0.y * v0.y + v0.z * v0.z + v0.w * v0.w
                 + v1.x * v1.x + v1.y * v1.y + v1.z * v1.z + v1.w * v1.w;
        #pragma unroll
        for (int m = 1; m < 16; m <<= 1) ss += __shfl_xor(ss, m, 16);
        float r = rsqrtf(ss * (1.0f / 1152.0f) + 1e-6f);
        uint4 pk;
        pk.x = pack2bf(v0.x * r, v0.y * r);
        pk.y = pack2bf(v0.z * r, v0.w * r);
        pk.z = pack2bf(v1.x * r, v1.y * r);
        pk.w = pack2bf(v1.z * r, v1.w * r);
        *reinterpret_cast<uint4*>(&a_s[ni][c8]) = pk;
    }
    __syncthreads();

    const int l = tid & 63, wq = tid >> 6;
    const int lr = l & 15, lk = l >> 4;

    #pragma unroll
    for (int jb = 0; jb < 6; ++jb) {
        int job = wq * 6 + jb;            // 0..23: mat = job>>3, nt = job&7
        int mat = job >> 3, nt = job & 7;
        const ushort* W = (mat == 0) ? Wvx : (mat == 1 ? Wa1sx : Wa1dx);
        uint* O = (mat == 0) ? Vb : (mat == 1 ? Psb : Pdb);
        float4v acc = (float4v){0.f, 0.f, 0.f, 0.f};
        #pragma unroll
        for (int ks = 0; ks < 4; ++ks) {
            short8v af = *reinterpret_cast<const short8v*>(&a_s[lr][lk * 8 + ks * 32]);
            short8v bf = *reinterpret_cast<const short8v*>(&W[((size_t)(nt * 4 + ks) * 64 + l) * 8]);
            acc = __builtin_amdgcn_mfma_f32_16x16x32_bf16(af, bf, acc, 0, 0, 0);
        }
        #pragma unroll
        for (int r = 0; r < 4; ++r) {
            float v = acc[r];
            float vn = __shfl_xor(v, 1, 64);
            if ((l & 1) == 0) {
                int row = lk * 4 + r, col = nt * 16 + lr;
                O[(size_t)(n0 + row) * 64 + (col >> 1)] = pack2bf(v, vn);
            }
        }
    }
}

// ---------------- CSR build ----------------
__global__ __launch_bounds__(256)
void k_hist(const int* __restrict__ eidx, int* __restrict__ deg)
{
    int e = blockIdx.x * 256 + threadIdx.x;
    if (e < NE) atomicAdd(&deg[eidx[NE + e]], 1);
}

__global__ __launch_bounds__(1024)
void k_scan(const int* __restrict__ deg, int* __restrict__ off, int* __restrict__ cursor)
{
    __shared__ int part[1024];
    const int t = threadIdx.x;
    const int base = t * 6;
    int loc[6]; int s = 0;
    #pragma unroll
    for (int i = 0; i < 6; ++i) {
        int d = (base + i < NN) ? deg[base + i] : 0;
        loc[i] = s; s += d;
    }
    part[t] = s;
    __syncthreads();
    for (int o = 1; o < 1024; o <<= 1) {
        int v = (t >= o) ? part[t - o] : 0;
        __syncthreads();
        part[t] += v;
        __syncthreads();
    }
    int pre = (t > 0) ? part[t - 1] : 0;
    #pragma unroll
    for (int i = 0; i < 6; ++i) {
        if (base + i < NN) {
            int v = pre + loc[i];
            off[base + i] = v;
            cursor[base + i] = v;
        }
    }
    if (t == 1023) off[NN] = part[1023];
}

__global__ __launch_bounds__(256)
void k_fill(const int* __restrict__ eidx, int* __restrict__ cursor,
            int* __restrict__ srcp, int* __restrict__ pos)
{
    int e = blockIdx.x * 256 + threadIdx.x;
    if (e < NE) {
        int d = eidx[NE + e];
        int p = atomicAdd(&cursor[d], 1);
        srcp[p] = eidx[e];
        pos[e] = p;
    }
}

// ---------------- attention via bf16 tables (num written in CSR order) ----------------
__global__ __launch_bounds__(256)
void k_attn(const int* __restrict__ eidx, const int* __restrict__ bondf,
            const float* __restrict__ dist, const int* __restrict__ pos,
            const uint* __restrict__ Psb, const uint* __restrict__ Pdb,
            const uint* __restrict__ TAbl, const float* __restrict__ TGl,
            const uint* __restrict__ BAcbl, const float* __restrict__ BGcl,
            const float* __restrict__ Wa2l,
            float* __restrict__ num, float* __restrict__ sums)
{
    __shared__ float t_s[32][132];
    __shared__ float gate_s[32][8];
    __shared__ int dst_s[32];
    const int tid = threadIdx.x;
    const int e0 = blockIdx.x * 32;

    {
        const int ei = tid >> 3, g = tid & 7;
        const int eid = min(e0 + ei, NE - 1);
        const int sn = eidx[eid], dn = eidx[NE + eid];
        float d = dist[eid];
        float u = d * ((float)TBM / 5.0f);
        int i = min((int)u, TBM - 1);
        float f = u - (float)i, f1 = 1.f - f;
        int cb = bondf[eid * 3 + 0] * 64 + bondf[eid * 3 + 1] * 8 + bondf[eid * 3 + 2];

        uint ps[8], pd[8], t0[8], t1v[8], ba[8];
        {
            const uint4* p = reinterpret_cast<const uint4*>(&Psb[(size_t)sn * 64 + g * 8]);
            uint4 a = p[0], b = p[1];
            ps[0]=a.x; ps[1]=a.y; ps[2]=a.z; ps[3]=a.w; ps[4]=b.x; ps[5]=b.y; ps[6]=b.z; ps[7]=b.w;
            p = reinterpret_cast<const uint4*>(&Pdb[(size_t)dn * 64 + g * 8]);
            a = p[0]; b = p[1];
            pd[0]=a.x; pd[1]=a.y; pd[2]=a.z; pd[3]=a.w; pd[4]=b.x; pd[5]=b.y; pd[6]=b.z; pd[7]=b.w;
            p = reinterpret_cast<const uint4*>(&TAbl[(size_t)i * 64 + g * 8]);
            a = p[0]; b = p[1];
            t0[0]=a.x; t0[1]=a.y; t0[2]=a.z; t0[3]=a.w; t0[4]=b.x; t0[5]=b.y; t0[6]=b.z; t0[7]=b.w;
            p = reinterpret_cast<const uint4*>(&TAbl[(size_t)(i + 1) * 64 + g * 8]);
            a = p[0]; b = p[1];
            t1v[0]=a.x; t1v[1]=a.y; t1v[2]=a.z; t1v[3]=a.w; t1v[4]=b.x; t1v[5]=b.y; t1v[6]=b.z; t1v[7]=b.w;
            p = reinterpret_cast<const uint4*>(&BAcbl[(size_t)cb * 64 + g * 8]);
            a = p[0]; b = p[1];
            ba[0]=a.x; ba[1]=a.y; ba[2]=a.z; ba[3]=a.w; ba[4]=b.x; ba[5]=b.y; ba[6]=b.z; ba[7]=b.w;
        }
        float* tr = &t_s[ei][g * 16];
        #pragma unroll
        for (int q = 0; q < 8; ++q) {
            float2 vs = up2(ps[q]), vd = up2(pd[q]), v0 = up2(t0[q]), v1 = up2(t1v[q]), vb = up2(ba[q]);
            tr[2 * q + 0] = siluf(vs.x + vd.x + f1 * v0.x + f * v1.x + vb.x);
            tr[2 * q + 1] = siluf(vs.y + vd.y + f1 * v0.y + f * v1.y + vb.y);
        }
        if (g == 0) {
            dst_s[ei] = dn;
            const float4* tg0 = reinterpret_cast<const float4*>(&TGl[(size_t)i * 8]);
            const float4* bg4 = reinterpret_cast<const float4*>(&BGcl[(size_t)cb * 8]);
            #pragma unroll
            for (int q = 0; q < 2; ++q) {
                float4 g0 = tg0[q], g1 = tg0[q + 2], bb = bg4[q];
                gate_s[ei][4 * q + 0] = f1 * g0.x + f * g1.x + bb.x;
                gate_s[ei][4 * q + 1] = f1 * g0.y + f * g1.y + bb.y;
                gate_s[ei][4 * q + 2] = f1 * g0.z + f * g1.z + bb.z;
                gate_s[ei][4 * q + 3] = f1 * g0.w + f * g1.w + bb.w;
            }
        }
    }
    __syncthreads();

    {
        const int ei = tid >> 3, h = tid & 7;
        const int eid = e0 + ei;
        float lg = 0.f;
        for (int j4 = 0; j4 < 128; j4 += 4) {
            const float4 tv = *reinterpret_cast<const float4*>(&t_s[ei][j4]);
            lg += tv.x * Wa2l[(j4 + 0) * 8 + h] + tv.y * Wa2l[(j4 + 1) * 8 + h]
                + tv.z * Wa2l[(j4 + 2) * 8 + h] + tv.w * Wa2l[(j4 + 3) * 8 + h];
        }
        if (eid < NE) {
            float ex = __expf(lg);
            num[(size_t)pos[eid] * 8 + h] = ex * sigmf(gate_s[ei][h]);
            atomicAdd(&sums[(size_t)dst_s[ei] * 8 + h], ex);
        }
    }
}

// ---------------- fused aggregate (CSR-contiguous, unroll 4) + out_proj ----------------
__global__ __launch_bounds__(128)
void k_aggo(const int* __restrict__ off, const int* __restrict__ srcp,
            const float* __restrict__ num, const float* __restrict__ sums,
            const uint* __restrict__ Vb, const float* __restrict__ Wol,
            float* __restrict__ x)
{
    __shared__ float a_s[128];
    const int n = blockIdx.x, c = threadIdx.x;
    const int s = off[n], t = off[n + 1];
    const int h = c >> 4, cd = c >> 1, sel = c & 1;
    float sinv = 1.f / (sums[(size_t)n * 8 + h] + 1e-9f);
    float acc = 0.f;
    int p = s;
    for (; p + 4 <= t; p += 4) {
        int sn0 = srcp[p + 0], sn1 = srcp[p + 1], sn2 = srcp[p + 2], sn3 = srcp[p + 3];
        float cf0 = num[(size_t)(p + 0) * 8 + h];
        float cf1 = num[(size_t)(p + 1) * 8 + h];
        float cf2 = num[(size_t)(p + 2) * 8 + h];
        float cf3 = num[(size_t)(p + 3) * 8 + h];
        uint u0 = Vb[(size_t)sn0 * 64 + cd];
        uint u1 = Vb[(size_t)sn1 * 64 + cd];
        uint u2 = Vb[(size_t)sn2 * 64 + cd];
        uint u3 = Vb[(size_t)sn3 * 64 + cd];
        float v0 = sel ? __uint_as_float(u0 & 0xffff0000u) : __uint_as_float(u0 << 16);
        float v1 = sel ? __uint_as_float(u1 & 0xffff0000u) : __uint_as_float(u1 << 16);
        float v2 = sel ? __uint_as_float(u2 & 0xffff0000u) : __uint_as_float(u2 << 16);
        float v3 = sel ? __uint_as_float(u3 & 0xffff0000u) : __uint_as_float(u3 << 16);
        acc += cf0 * v0 + cf1 * v1 + cf2 * v2 + cf3 * v3;
    }
    for (; p < t; ++p) {
        int sn = srcp[p];
        float cf = num[(size_t)p * 8 + h];
        uint u = Vb[(size_t)sn * 64 + cd];
        float v = sel ? __uint_as_float(u & 0xffff0000u) : __uint_as_float(u << 16);
        acc += cf * v;
    }
    a_s[c] = acc * sinv;
    __syncthreads();
    float o = 0.f;
    #pragma unroll 4
    for (int j4 = 0; j4 < 128; j4 += 4) {
        const float4 a4 = *reinterpret_cast<const float4*>(&a_s[j4]);
        o += a4.x * Wol[(j4 + 0) * 128 + c] + a4.y * Wol[(j4 + 1) * 128 + c]
           + a4.z * Wol[(j4 + 2) * 128 + c] + a4.w * Wol[(j4 + 3) * 128 + c];
    }
    x[n * 128 + c] += o;
}

// ---------------- fused rms + FFN via MFMA (16 nodes/block) ----------------
__global__ __launch_bounds__(256)
void k_ffnrms(float* __restrict__ x, const ushort* __restrict__ Wf1xl,
              const ushort* __restrict__ Wf2xl)
{
    __shared__ ushort a_s[16][136];
    __shared__ ushort h_s[16][520];
    const int tid = threadIdx.x;
    const int n0 = blockIdx.x * 16;

    {   // rms prologue
        int ni = tid >> 4, c8 = (tid & 15) * 8;
        const float* xr = &x[(size_t)(n0 + ni) * 128 + c8];
        float4 v0 = *reinterpret_cast<const float4*>(xr);
        float4 v1 = *reinterpret_cast<const float4*>(xr + 4);
        float ss = v0.x * v0.x + v0.y * v0.y + v0.z * v0.z + v0.w * v0.w
                 + v1.x * v1.x + v1.y * v1.y + v1.z * v1.z + v1.w * v1.w;
        #pragma unroll
        for (int m = 1; m < 16; m <<= 1) ss += __shfl_xor(ss, m, 16);
        float r = rsqrtf(ss * (1.0f / 1152.0f) + 1e-6f);
        uint4 pk;
        pk.x = pack2bf(v0.x * r, v0.y * r);
        pk.y = pack2bf(v0.z * r, v0.w * r);
        pk.z = pack2bf(v1.x * r, v1.y * r);
        pk.w = pack2bf(v1.z * r, v1.w * r);
        *reinterpret_cast<uint4*>(&a_s[ni][c8]) = pk;
    }
    __syncthreads();

    const int l  = tid & 63;
    const int wq = tid >> 6;
    const int lr = l & 15, lk = l >> 4;

    float4v acc[8];
    #pragma unroll
    for (int nf = 0; nf < 8; ++nf) acc[nf] = (float4v){0.f, 0.f, 0.f, 0.f};
    #pragma unroll
    for (int ks = 0; ks < 4; ++ks) {
        short8v af = *reinterpret_cast<const short8v*>(&a_s[lr][lk * 8 + ks * 32]);
        #pragma unroll
        for (int nf = 0; nf < 8; ++nf) {
            int nt = wq * 8 + nf;
            short8v bf = *reinterpret_cast<const short8v*>(&Wf1xl[((size_t)(nt * 4 + ks) * 64 + l) * 8]);
            acc[nf] = __builtin_amdgcn_mfma_f32_16x16x32_bf16(af, bf, acc[nf], 0, 0, 0);
        }
    }
    #pragma unroll
    for (int nf = 0; nf < 8; ++nf) {
        #pragma unroll
        for (int r = 0; r < 4; ++r) {
            float v = siluf(acc[nf][r]);
            float vn = __shfl_xor(v, 1, 64);
            if ((l & 1) == 0) {
                int row = lk * 4 + r;
                int col = wq * 128 + nf * 16 + lr;
                *reinterpret_cast<uint*>(&h_s[row][col]) = pack2bf(v, vn);
            }
        }
    }
    __syncthreads();

    float4v acc2[2];
    acc2[0] = (float4v){0.f, 0.f, 0.f, 0.f};
    acc2[1] = (float4v){0.f, 0.f, 0.f, 0.f};
    #pragma unroll 4
    for (int ks = 0; ks < 16; ++ks) {
        short8v af = *reinterpret_cast<const short8v*>(&h_s[lr][lk * 8 + ks * 32]);
        #pragma unroll
        for (int nf = 0; nf < 2; ++nf) {
            int nt = wq * 2 + nf;
            short8v bf = *reinterpret_cast<const short8v*>(&Wf2xl[((size_t)(nt * 16 + ks) * 64 + l) * 8]);
            acc2[nf] = __builtin_amdgcn_mfma_f32_16x16x32_bf16(af, bf, acc2[nf], 0, 0, 0);
        }
    }
    #pragma unroll
    for (int nf = 0; nf < 2; ++nf) {
        #pragma unroll
        for (int r = 0; r < 4; ++r) {
            int row = lk * 4 + r;
            int col = wq * 32 + nf * 16 + lr;
            x[(size_t)(n0 + row) * 128 + col] += acc2[nf][r];
        }
    }
}

// ---------------- finalize ----------------
__global__ __launch_bounds__(128)
void k_finalize(const float* __restrict__ x, float* __restrict__ out)
{
    int n = blockIdx.x, c = threadIdx.x;
    float v = x[n * 128 + c];
    float ss = v * v;
    #pragma unroll
    for (int o = 32; o > 0; o >>= 1) ss += __shfl_down(ss, o, 64);
    __shared__ float red[2];
    if ((c & 63) == 0) red[c >> 6] = ss;
    __syncthreads();
    float r = rsqrtf((red[0] + red[1]) * (1.0f / 1152.0f) + 1e-6f);
    size_t base = (size_t)n * 1152;
    out[base + c] = v * r;
    #pragma unroll
    for (int k = 1; k < 9; ++k) out[base + k * 128 + c] = 0.f;
}

extern "C" void kernel_launch(void* const* d_in, const int* in_sizes, int n_in,
                              void* d_out, int out_size, void* d_ws, size_t ws_size,
                              hipStream_t stream)
{
    const int*   atom_feats = (const int*)d_in[0];
    const int*   bond_feats = (const int*)d_in[1];
    const int*   edge_index = (const int*)d_in[2];
    const float* edge_dist  = (const float*)d_in[3];
    const float* atom_emb   = (const float*)d_in[4];
    const float* bond_emb   = (const float*)d_in[5];
    const float* W_rbf1     = (const float*)d_in[6];
    const float* b_rbf1     = (const float*)d_in[7];
    const float* W_rbf2     = (const float*)d_in[8];
    const float* b_rbf2     = (const float*)d_in[9];
    const float* Wa1        = (const float*)d_in[10];
    const float* Wa2        = (const float*)d_in[11];
    const float* Wv         = (const float*)d_in[12];
    const float* Wg         = (const float*)d_in[13];
    const float* Wo         = (const float*)d_in[14];
    const float* Wf1        = (const float*)d_in[15];
    const float* Wf2        = (const float*)d_in[16];
    float* out = (float*)d_out;

    float* ws   = (float*)d_ws;
    float* x    = ws;                           // NN*128
    float* sums = x    + NN * 128;              // NN*8
    float* num  = sums + NN * 8;                // NE*8 (CSR order)
    float* W2A  = num  + (size_t)NE * 8;        // 2*16384
    float* W2G  = W2A  + 2 * 16384;             // 2*1024
    float* bA   = W2G  + 2 * 1024;              // 2*128
    float* bG   = bA   + 2 * 128;               // 16
    float* TG   = bG   + 16;                    // 2*TROWS*8
    float* BGc  = TG   + 2 * (size_t)TROWS * 8; // 2*512*8
    uint* Vb    = (uint*)(BGc + 2 * 512 * 8);   // NN*64
    uint* Psb   = Vb  + NN * 64;
    uint* Pdb   = Psb + NN * 64;
    uint* TAb   = Pdb + NN * 64;                // 2*TROWS*64
    uint* BAcb  = TAb + 2 * (size_t)TROWS * 64; // 2*512*64
    ushort* Wf1x  = (ushort*)(BAcb + 2 * 512 * 64);  // 2*65536
    ushort* Wf2x  = Wf1x  + 2 * 65536;               // 2*65536
    ushort* Wvx   = Wf2x  + 2 * 65536;               // 2*16384
    ushort* Wa1sx = Wvx   + 2 * 16384;               // 2*16384
    ushort* Wa1dx = Wa1sx + 2 * 16384;               // 2*16384
    int* deg    = (int*)(Wa1dx + 2 * 16384);
    int* off    = deg + NN;
    int* cursor = off + NN + 1;
    int* srcp   = cursor + NN;                  // NE
    int* pos    = srcp + NE;                    // NE

    k_atom_embed<<<NN, 128, 0, stream>>>(atom_feats, atom_emb, x);

    // tables + packed weights (once per call)
    k_w2a<<<dim3(18, 2), 256, 0, stream>>>(W_rbf2, b_rbf2, Wa1, Wg, W2A, W2G, bA, bG);
    k_bondtabs<<<dim3(512, 2), 128, 0, stream>>>(bond_emb, Wa1, Wg, BAcb, BGc);
    k_packw<<<dim3(352, 2), 64, 0, stream>>>(Wf1, Wf2, Wv, Wa1, Wf1x, Wf2x, Wvx, Wa1sx, Wa1dx);
    k_t1ta<<<dim3((TBM + 8) / 8, 2), 256, 0, stream>>>(W_rbf1, b_rbf1, W2A, W2G, bA, bG, TAb, TG);

    // CSR (dst is layer-invariant)
    hipMemsetAsync(deg, 0, NN * sizeof(int), stream);
    k_hist<<<(NE + 255) / 256, 256, 0, stream>>>(edge_index, deg);
    k_scan<<<1, 1024, 0, stream>>>(deg, off, cursor);
    k_fill<<<(NE + 255) / 256, 256, 0, stream>>>(edge_index, cursor, srcp, pos);

    for (int l = 0; l < 2; ++l) {
        k_rmsgemm<<<NN / 16, 256, 0, stream>>>(x,
            Wvx + (size_t)l * 16384, Wa1sx + (size_t)l * 16384, Wa1dx + (size_t)l * 16384,
            Vb, Psb, Pdb);
        hipMemsetAsync(sums, 0, NN * 8 * sizeof(float), stream);
        k_attn<<<(NE + 31) / 32, 256, 0, stream>>>(edge_index, bond_feats, edge_dist, pos,
            Psb, Pdb,
            TAb + (size_t)l * TROWS * 64, TG + (size_t)l * TROWS * 8,
            BAcb + (size_t)l * 512 * 64, BGc + (size_t)l * 512 * 8,
            Wa2 + (size_t)l * 128 * 8, num, sums);
        k_aggo<<<NN, 128, 0, stream>>>(off, srcp, num, sums, Vb,
                                       Wo + (size_t)l * 128 * 128, x);
        k_ffnrms<<<NN / 16, 256, 0, stream>>>(x,
            Wf1x + (size_t)l * 65536, Wf2x + (size_t)l * 65536);
    }
    k_finalize<<<NN, 128, 0, stream>>>(x, out);
}

// Round 7
// 237.805 us; speedup vs baseline: 6.7786x; 1.0313x over previous
//
#include <hip/hip_runtime.h>

#define NN 6000
#define NE 150000
#define TBM 2048
#define TROWS (TBM + 1)

typedef unsigned int uint;
typedef unsigned short ushort;
typedef __attribute__((ext_vector_type(8))) short short8v;
typedef __attribute__((ext_vector_type(4))) float float4v;

__device__ __forceinline__ float siluf(float x) { return x / (1.f + __expf(-x)); }
__device__ __forceinline__ float sigmf(float x) { return 1.f / (1.f + __expf(-x)); }
__device__ __forceinline__ uint pack2bf(float lo, float hi) {
    uint ul = __float_as_uint(lo);
    ul = (ul + 0x7fffu + ((ul >> 16) & 1u)) >> 16;
    uint uh = __float_as_uint(hi);
    uh = ((uh + 0x7fffu + ((uh >> 16) & 1u)) >> 16) << 16;
    return ul | uh;
}
__device__ __forceinline__ ushort f2bf(float f) {
    uint u = __float_as_uint(f);
    return (ushort)((u + 0x7fffu + ((u >> 16) & 1u)) >> 16);
}
__device__ __forceinline__ float2 up2(uint u) {
    return make_float2(__uint_as_float(u << 16), __uint_as_float(u & 0xffff0000u));
}

// ---------------- atom embedding (+ deg zeroing folded in) ----------------
__global__ __launch_bounds__(128)
void k_atom_embed(const int* __restrict__ af, const float* __restrict__ aemb,
                  float* __restrict__ x, int* __restrict__ deg)
{
    int n = blockIdx.x, c = threadIdx.x;
    if (c == 0) deg[n] = 0;
    float s = 0.f;
    #pragma unroll
    for (int f = 0; f < 4; ++f) {
        int idx = af[n * 4 + f];
        s += aemb[(f * 10 + idx) * 128 + c];
    }
    x[n * 128 + c] = s;
}

// ---------------- fold W2 through per-layer weights ----------------
__global__ __launch_bounds__(256)
void k_w2a(const float* __restrict__ W2, const float* __restrict__ b2,
           const float* __restrict__ Wa1, const float* __restrict__ Wg,
           float* __restrict__ W2A, float* __restrict__ W2G,
           float* __restrict__ bA, float* __restrict__ bG)
{
    const int l = blockIdx.y;
    const float* Wa1e = Wa1 + (size_t)l * 384 * 128 + 256 * 128;
    const float* Wgl  = Wg  + (size_t)l * 128 * 8;
    const int tid = threadIdx.x;

    if (blockIdx.x < 16) {
        __shared__ float w2_s[8][132];
        const int i0 = blockIdx.x * 8;
        for (int q = tid; q < 8 * 32; q += 256) {
            int ni = q >> 5, j4 = (q & 31) * 4;
            *reinterpret_cast<float4*>(&w2_s[ni][j4]) =
                *reinterpret_cast<const float4*>(&W2[(size_t)(i0 + ni) * 128 + j4]);
        }
        __syncthreads();
        const int j = tid & 127, ng = tid >> 7;
        float a[4] = {0.f, 0.f, 0.f, 0.f};
        #pragma unroll 4
        for (int k4 = 0; k4 < 128; k4 += 4) {
            float w0 = Wa1e[(k4 + 0) * 128 + j];
            float w1 = Wa1e[(k4 + 1) * 128 + j];
            float w2v = Wa1e[(k4 + 2) * 128 + j];
            float w3 = Wa1e[(k4 + 3) * 128 + j];
            #pragma unroll
            for (int r = 0; r < 4; ++r) {
                const float4 xv = *reinterpret_cast<const float4*>(&w2_s[ng * 4 + r][k4]);
                a[r] += xv.x * w0 + xv.y * w1 + xv.z * w2v + xv.w * w3;
            }
        }
        #pragma unroll
        for (int r = 0; r < 4; ++r)
            W2A[(size_t)l * 16384 + (size_t)(i0 + ng * 4 + r) * 128 + j] = a[r];
    } else if (blockIdx.x == 16) {
        const int i = tid & 127, hq = tid >> 7;
        float a[4] = {0.f, 0.f, 0.f, 0.f};
        for (int k = 0; k < 128; ++k) {
            float w = W2[(size_t)i * 128 + k];
            const float4 g4 = *reinterpret_cast<const float4*>(&Wgl[k * 8 + hq * 4]);
            a[0] += w * g4.x; a[1] += w * g4.y; a[2] += w * g4.z; a[3] += w * g4.w;
        }
        #pragma unroll
        for (int q = 0; q < 4; ++q)
            W2G[(size_t)l * 1024 + (size_t)i * 8 + hq * 4 + q] = a[q];
    } else {
        if (tid < 128) {
            float s = 0.f;
            for (int k = 0; k < 128; ++k) s += b2[k] * Wa1e[k * 128 + tid];
            bA[l * 128 + tid] = s;
        } else if (tid < 136) {
            int h = tid - 128;
            float s = 0.f;
            for (int k = 0; k < 128; ++k) s += b2[k] * Wgl[k * 8 + h];
            bG[l * 8 + h] = s;
        }
    }
}

// ---------------- bond-combo tables ----------------
__global__ __launch_bounds__(128)
void k_bondtabs(const float* __restrict__ bemb, const float* __restrict__ Wa1,
                const float* __restrict__ Wg,
                uint* __restrict__ BAcb, float* __restrict__ BGc)
{
    const int l = blockIdx.y, cb = blockIdx.x, c = threadIdx.x;
    const float* Wa1e = Wa1 + (size_t)l * 384 * 128 + 256 * 128;
    const float* Wgl  = Wg  + (size_t)l * 128 * 8;
    const int b[3] = {cb >> 6, (cb >> 3) & 7, cb & 7};

    float s = 0.f;
    #pragma unroll
    for (int f = 0; f < 3; ++f) {
        const float* er = &bemb[(size_t)(f * 8 + b[f]) * 128];
        for (int k = 0; k < 128; ++k)
            s += er[k] * Wa1e[k * 128 + c];
    }
    float hi = __shfl_down(s, 1, 64);
    if ((c & 1) == 0)
        BAcb[(size_t)l * 512 * 64 + (size_t)cb * 64 + (c >> 1)] = pack2bf(s, hi);

    if (c < 8) {
        float g = 0.f;
        #pragma unroll
        for (int f = 0; f < 3; ++f) {
            const float* er = &bemb[(size_t)(f * 8 + b[f]) * 128];
            for (int k = 0; k < 128; ++k)
                g += er[k] * Wgl[k * 8 + c];
        }
        BGc[(size_t)l * 512 * 8 + (size_t)cb * 8 + c] = g;
    }
}

// ---------------- fused t1 + TA + TG table build (8 rows/block) ----------------
__global__ __launch_bounds__(256)
void k_t1ta(const float* __restrict__ W1, const float* __restrict__ b1,
            const float* __restrict__ W2A, const float* __restrict__ W2G,
            const float* __restrict__ bA, const float* __restrict__ bG,
            uint* __restrict__ TAb, float* __restrict__ TG)
{
    __shared__ float rbf_s[8][32];
    __shared__ int   bs_s[8];
    __shared__ float t1_s[8][132];
    const int l = blockIdx.y, tid = threadIdx.x;
    const int r0 = blockIdx.x * 8;

    {
        int ri = tid >> 5, j = tid & 31;
        int row = min(r0 + ri, TBM);
        float d = (float)row * (5.0f / TBM);
        const float step = 5.0f / 511.0f;
        const float invw = 512.0f / 5.0f;
        int b0 = (int)(d * (511.0f / 5.0f) + 0.5f);
        int bs = min(max(b0 - 16, 0), 512 - 32);
        if (j == 0) bs_s[ri] = bs;
        float z = (d - (float)(bs + j) * step) * invw;
        rbf_s[ri][j] = __expf(-z * z);
    }
    __syncthreads();

    #pragma unroll
    for (int pass = 0; pass < 4; ++pass) {
        int idx = pass * 256 + tid;
        int ri = idx >> 7, c = idx & 127;
        int bs = bs_s[ri];
        float t = b1[c];
        #pragma unroll
        for (int j = 0; j < 32; ++j)
            t += rbf_s[ri][j] * W1[(bs + j) * 128 + c];
        t1_s[ri][c] = siluf(t);
    }
    __syncthreads();

    const float* W2Al = W2A + (size_t)l * 16384;
    const int c = tid & 127, ng = tid >> 7;
    float a[4];
    #pragma unroll
    for (int r = 0; r < 4; ++r) a[r] = bA[l * 128 + c];
    #pragma unroll 4
    for (int k4 = 0; k4 < 128; k4 += 4) {
        float w0 = W2Al[(k4 + 0) * 128 + c];
        float w1 = W2Al[(k4 + 1) * 128 + c];
        float w2v = W2Al[(k4 + 2) * 128 + c];
        float w3 = W2Al[(k4 + 3) * 128 + c];
        #pragma unroll
        for (int r = 0; r < 4; ++r) {
            const float4 xv = *reinterpret_cast<const float4*>(&t1_s[ng * 4 + r][k4]);
            a[r] += xv.x * w0 + xv.y * w1 + xv.z * w2v + xv.w * w3;
        }
    }
    #pragma unroll
    for (int r = 0; r < 4; ++r) {
        float hi = __shfl_down(a[r], 1, 64);
        int row = r0 + ng * 4 + r;
        if (((c & 1) == 0) && row <= TBM)
            TAb[(size_t)l * TROWS * 64 + (size_t)row * 64 + (c >> 1)] = pack2bf(a[r], hi);
    }

    if (tid < 64) {
        int ri = tid >> 3, h = tid & 7;
        int row = r0 + ri;
        if (row <= TBM) {
            const float* W2Gl = W2G + (size_t)l * 1024;
            float s = bG[l * 8 + h];
            #pragma unroll 8
            for (int k = 0; k < 128; ++k)
                s += t1_s[ri][k] * W2Gl[k * 8 + h];
            TG[(size_t)l * TROWS * 8 + (size_t)row * 8 + h] = s;
        }
    }
}

// ---------------- pack weights into MFMA B-fragment order (bf16) ----------------
__global__ __launch_bounds__(64)
void k_packw(const float* __restrict__ Wf1, const float* __restrict__ Wf2,
             const float* __restrict__ Wv, const float* __restrict__ Wa1,
             ushort* __restrict__ Wf1x, ushort* __restrict__ Wf2x,
             ushort* __restrict__ Wvx, ushort* __restrict__ Wa1sx,
             ushort* __restrict__ Wa1dx)
{
    const int l = blockIdx.y, bx = blockIdx.x, lane = threadIdx.x;
    if (bx < 128) {
        const int nt = bx >> 2, kt = bx & 3;
        const float* src = Wf1 + (size_t)l * 65536;
        ushort* dst = Wf1x + (size_t)l * 65536 + ((size_t)bx * 64 + lane) * 8;
        #pragma unroll
        for (int j = 0; j < 8; ++j)
            dst[j] = f2bf(src[(size_t)(kt * 32 + (lane >> 4) * 8 + j) * 512 + nt * 16 + (lane & 15)]);
    } else if (bx < 256) {
        const int b2x = bx - 128;
        const int nt = b2x >> 4, kt = b2x & 15;
        const float* src = Wf2 + (size_t)l * 65536;
        ushort* dst = Wf2x + (size_t)l * 65536 + ((size_t)b2x * 64 + lane) * 8;
        #pragma unroll
        for (int j = 0; j < 8; ++j)
            dst[j] = f2bf(src[(size_t)(kt * 32 + (lane >> 4) * 8 + j) * 128 + nt * 16 + (lane & 15)]);
    } else {
        const int b3 = bx - 256;
        const int mat = b3 >> 5, blk = b3 & 31;
        const int nt = blk >> 2, kt = blk & 3;
        const float* src;
        ushort* dst;
        if (mat == 0)      { src = Wv  + (size_t)l * 16384;             dst = Wvx   + (size_t)l * 16384; }
        else if (mat == 1) { src = Wa1 + (size_t)l * 384 * 128;         dst = Wa1sx + (size_t)l * 16384; }
        else               { src = Wa1 + (size_t)l * 384 * 128 + 16384; dst = Wa1dx + (size_t)l * 16384; }
        dst += ((size_t)blk * 64 + lane) * 8;
        #pragma unroll
        for (int j = 0; j < 8; ++j)
            dst[j] = f2bf(src[(size_t)(kt * 32 + (lane >> 4) * 8 + j) * 128 + nt * 16 + (lane & 15)]);
    }
}

// ---------------- fused rms + 3 node GEMMs via MFMA (16 nodes/block) ----------------
__global__ __launch_bounds__(256)
void k_rmsgemm(const float* __restrict__ x,
               const ushort* __restrict__ Wvx, const ushort* __restrict__ Wa1sx,
               const ushort* __restrict__ Wa1dx,
               uint* __restrict__ Vb, uint* __restrict__ Psb, uint* __restrict__ Pdb)
{
    __shared__ ushort a_s[16][136];
    const int tid = threadIdx.x, n0 = blockIdx.x * 16;

    {
        int ni = tid >> 4, c8 = (tid & 15) * 8;
        const float* xr = &x[(size_t)(n0 + ni) * 128 + c8];
        float4 v0 = *reinterpret_cast<const float4*>(xr);
        float4 v1 = *reinterpret_cast<const float4*>(xr + 4);
        float ss = v0.x * v0.x + v0.y * v0.y + v0.z * v0.z + v0.w * v0.w
                 + v1.x * v1.x + v1.y * v1.y + v1.z * v1.z + v1.w * v1.w;
        #pragma unroll
        for (int m = 1; m < 16; m <<= 1) ss += __shfl_xor(ss, m, 16);
        float r = rsqrtf(ss * (1.0f / 1152.0f) + 1e-6f);
        uint4 pk;
        pk.x = pack2bf(v0.x * r, v0.y * r);
        pk.y = pack2bf(v0.z * r, v0.w * r);
        pk.z = pack2bf(v1.x * r, v1.y * r);
        pk.w = pack2bf(v1.z * r, v1.w * r);
        *reinterpret_cast<uint4*>(&a_s[ni][c8]) = pk;
    }
    __syncthreads();

    const int l = tid & 63, wq = tid >> 6;
    const int lr = l & 15, lk = l >> 4;

    #pragma unroll
    for (int jb = 0; jb < 6; ++jb) {
        int job = wq * 6 + jb;
        int mat = job >> 3, nt = job & 7;
        const ushort* W = (mat == 0) ? Wvx : (mat == 1 ? Wa1sx : Wa1dx);
        uint* O = (mat == 0) ? Vb : (mat == 1 ? Psb : Pdb);
        float4v acc = (float4v){0.f, 0.f, 0.f, 0.f};
        #pragma unroll
        for (int ks = 0; ks < 4; ++ks) {
            short8v af = *reinterpret_cast<const short8v*>(&a_s[lr][lk * 8 + ks * 32]);
            short8v bf = *reinterpret_cast<const short8v*>(&W[((size_t)(nt * 4 + ks) * 64 + l) * 8]);
            acc = __builtin_amdgcn_mfma_f32_16x16x32_bf16(af, bf, acc, 0, 0, 0);
        }
        #pragma unroll
        for (int r = 0; r < 4; ++r) {
            float v = acc[r];
            float vn = __shfl_xor(v, 1, 64);
            if ((l & 1) == 0) {
                int row = lk * 4 + r, col = nt * 16 + lr;
                O[(size_t)(n0 + row) * 64 + (col >> 1)] = pack2bf(v, vn);
            }
        }
    }
}

// ---------------- CSR build ----------------
__global__ __launch_bounds__(256)
void k_hist(const int* __restrict__ eidx, int* __restrict__ deg)
{
    int e = blockIdx.x * 256 + threadIdx.x;
    if (e < NE) atomicAdd(&deg[eidx[NE + e]], 1);
}

__global__ __launch_bounds__(1024)
void k_scan(const int* __restrict__ deg, int* __restrict__ off, int* __restrict__ cursor)
{
    __shared__ int part[1024];
    const int t = threadIdx.x;
    const int base = t * 6;
    int loc[6]; int s = 0;
    #pragma unroll
    for (int i = 0; i < 6; ++i) {
        int d = (base + i < NN) ? deg[base + i] : 0;
        loc[i] = s; s += d;
    }
    part[t] = s;
    __syncthreads();
    for (int o = 1; o < 1024; o <<= 1) {
        int v = (t >= o) ? part[t - o] : 0;
        __syncthreads();
        part[t] += v;
        __syncthreads();
    }
    int pre = (t > 0) ? part[t - 1] : 0;
    #pragma unroll
    for (int i = 0; i < 6; ++i) {
        if (base + i < NN) {
            int v = pre + loc[i];
            off[base + i] = v;
            cursor[base + i] = v;
        }
    }
    if (t == 1023) off[NN] = part[1023];
}

__global__ __launch_bounds__(256)
void k_fill(const int* __restrict__ eidx, int* __restrict__ cursor,
            int* __restrict__ srcp, int* __restrict__ dstp, int* __restrict__ ep)
{
    int e = blockIdx.x * 256 + threadIdx.x;
    if (e < NE) {
        int d = eidx[NE + e];
        int p = atomicAdd(&cursor[d], 1);
        srcp[p] = eidx[e];
        dstp[p] = d;
        ep[p] = e;
    }
}

// ---------------- attention, CSR-position order, no atomics ----------------
__global__ __launch_bounds__(256)
void k_attn(const int* __restrict__ srcp, const int* __restrict__ dstp,
            const int* __restrict__ ep, const int* __restrict__ bondf,
            const float* __restrict__ dist,
            const uint* __restrict__ Psb, const uint* __restrict__ Pdb,
            const uint* __restrict__ TAbl, const float* __restrict__ TGl,
            const uint* __restrict__ BAcbl, const float* __restrict__ BGcl,
            const float* __restrict__ Wa2l,
            float* __restrict__ num, float* __restrict__ exs)
{
    __shared__ float t_s[32][132];
    __shared__ float gate_s[32][8];
    const int tid = threadIdx.x;
    const int p0 = blockIdx.x * 32;

    {
        const int ei = tid >> 3, g = tid & 7;
        const int p = min(p0 + ei, NE - 1);
        const int sn = srcp[p], dn = dstp[p], e = ep[p];
        float d = dist[e];
        float u = d * ((float)TBM / 5.0f);
        int i = min((int)u, TBM - 1);
        float f = u - (float)i, f1 = 1.f - f;
        int cb = bondf[e * 3 + 0] * 64 + bondf[e * 3 + 1] * 8 + bondf[e * 3 + 2];

        uint ps[8], pd[8], t0[8], t1v[8], ba[8];
        {
            const uint4* pp = reinterpret_cast<const uint4*>(&Psb[(size_t)sn * 64 + g * 8]);
            uint4 a = pp[0], b = pp[1];
            ps[0]=a.x; ps[1]=a.y; ps[2]=a.z; ps[3]=a.w; ps[4]=b.x; ps[5]=b.y; ps[6]=b.z; ps[7]=b.w;
            pp = reinterpret_cast<const uint4*>(&Pdb[(size_t)dn * 64 + g * 8]);
            a = pp[0]; b = pp[1];
            pd[0]=a.x; pd[1]=a.y; pd[2]=a.z; pd[3]=a.w; pd[4]=b.x; pd[5]=b.y; pd[6]=b.z; pd[7]=b.w;
            pp = reinterpret_cast<const uint4*>(&TAbl[(size_t)i * 64 + g * 8]);
            a = pp[0]; b = pp[1];
            t0[0]=a.x; t0[1]=a.y; t0[2]=a.z; t0[3]=a.w; t0[4]=b.x; t0[5]=b.y; t0[6]=b.z; t0[7]=b.w;
            pp = reinterpret_cast<const uint4*>(&TAbl[(size_t)(i + 1) * 64 + g * 8]);
            a = pp[0]; b = pp[1];
            t1v[0]=a.x; t1v[1]=a.y; t1v[2]=a.z; t1v[3]=a.w; t1v[4]=b.x; t1v[5]=b.y; t1v[6]=b.z; t1v[7]=b.w;
            pp = reinterpret_cast<const uint4*>(&BAcbl[(size_t)cb * 64 + g * 8]);
            a = pp[0]; b = pp[1];
            ba[0]=a.x; ba[1]=a.y; ba[2]=a.z; ba[3]=a.w; ba[4]=b.x; ba[5]=b.y; ba[6]=b.z; ba[7]=b.w;
        }
        float* tr = &t_s[ei][g * 16];
        #pragma unroll
        for (int q = 0; q < 8; ++q) {
            float2 vs = up2(ps[q]), vd = up2(pd[q]), v0 = up2(t0[q]), v1 = up2(t1v[q]), vb = up2(ba[q]);
            tr[2 * q + 0] = siluf(vs.x + vd.x + f1 * v0.x + f * v1.x + vb.x);
            tr[2 * q + 1] = siluf(vs.y + vd.y + f1 * v0.y + f * v1.y + vb.y);
        }
        if (g == 0) {
            const float4* tg0 = reinterpret_cast<const float4*>(&TGl[(size_t)i * 8]);
            const float4* bg4 = reinterpret_cast<const float4*>(&BGcl[(size_t)cb * 8]);
            #pragma unroll
            for (int q = 0; q < 2; ++q) {
                float4 g0 = tg0[q], g1 = tg0[q + 2], bb = bg4[q];
                gate_s[ei][4 * q + 0] = f1 * g0.x + f * g1.x + bb.x;
                gate_s[ei][4 * q + 1] = f1 * g0.y + f * g1.y + bb.y;
                gate_s[ei][4 * q + 2] = f1 * g0.z + f * g1.z + bb.z;
                gate_s[ei][4 * q + 3] = f1 * g0.w + f * g1.w + bb.w;
            }
        }
    }
    __syncthreads();

    {
        const int ei = tid >> 3, h = tid & 7;
        const int p = p0 + ei;
        float lg = 0.f;
        for (int j4 = 0; j4 < 128; j4 += 4) {
            const float4 tv = *reinterpret_cast<const float4*>(&t_s[ei][j4]);
            lg += tv.x * Wa2l[(j4 + 0) * 8 + h] + tv.y * Wa2l[(j4 + 1) * 8 + h]
                + tv.z * Wa2l[(j4 + 2) * 8 + h] + tv.w * Wa2l[(j4 + 3) * 8 + h];
        }
        if (p < NE) {
            float ex = __expf(lg);
            num[(size_t)p * 8 + h] = ex * sigmf(gate_s[ei][h]);
            exs[(size_t)p * 8 + h] = ex;
        }
    }
}

// ---------------- fused aggregate (+denominator) + out_proj ----------------
__global__ __launch_bounds__(128)
void k_aggo(const int* __restrict__ off, const int* __restrict__ srcp,
            const float* __restrict__ num, const float* __restrict__ exs,
            const uint* __restrict__ Vb, const float* __restrict__ Wol,
            float* __restrict__ x)
{
    __shared__ float a_s[128];
    const int n = blockIdx.x, c = threadIdx.x;
    const int s = off[n], t = off[n + 1];
    const int h = c >> 4, cd = c >> 1, sel = c & 1;
    float acc = 0.f, es = 0.f;
    int p = s;
    for (; p + 4 <= t; p += 4) {
        int sn0 = srcp[p + 0], sn1 = srcp[p + 1], sn2 = srcp[p + 2], sn3 = srcp[p + 3];
        float cf0 = num[(size_t)(p + 0) * 8 + h];
        float cf1 = num[(size_t)(p + 1) * 8 + h];
        float cf2 = num[(size_t)(p + 2) * 8 + h];
        float cf3 = num[(size_t)(p + 3) * 8 + h];
        es += exs[(size_t)(p + 0) * 8 + h] + exs[(size_t)(p + 1) * 8 + h]
            + exs[(size_t)(p + 2) * 8 + h] + exs[(size_t)(p + 3) * 8 + h];
        uint u0 = Vb[(size_t)sn0 * 64 + cd];
        uint u1 = Vb[(size_t)sn1 * 64 + cd];
        uint u2 = Vb[(size_t)sn2 * 64 + cd];
        uint u3 = Vb[(size_t)sn3 * 64 + cd];
        float v0 = sel ? __uint_as_float(u0 & 0xffff0000u) : __uint_as_float(u0 << 16);
        float v1 = sel ? __uint_as_float(u1 & 0xffff0000u) : __uint_as_float(u1 << 16);
        float v2 = sel ? __uint_as_float(u2 & 0xffff0000u) : __uint_as_float(u2 << 16);
        float v3 = sel ? __uint_as_float(u3 & 0xffff0000u) : __uint_as_float(u3 << 16);
        acc += cf0 * v0 + cf1 * v1 + cf2 * v2 + cf3 * v3;
    }
    for (; p < t; ++p) {
        int sn = srcp[p];
        float cf = num[(size_t)p * 8 + h];
        es += exs[(size_t)p * 8 + h];
        uint u = Vb[(size_t)sn * 64 + cd];
        float v = sel ? __uint_as_float(u & 0xffff0000u) : __uint_as_float(u << 16);
        acc += cf * v;
    }
    a_s[c] = acc / (es + 1e-9f);
    __syncthreads();
    float o = 0.f;
    #pragma unroll 4
    for (int j4 = 0; j4 < 128; j4 += 4) {
        const float4 a4 = *reinterpret_cast<const float4*>(&a_s[j4]);
        o += a4.x * Wol[(j4 + 0) * 128 + c] + a4.y * Wol[(j4 + 1) * 128 + c]
           + a4.z * Wol[(j4 + 2) * 128 + c] + a4.w * Wol[(j4 + 3) * 128 + c];
    }
    x[n * 128 + c] += o;
}

// ---------------- fused rms + FFN via MFMA (16 nodes/block); LAST also finalizes ----------------
template<int LAST>
__global__ __launch_bounds__(256)
void k_ffnrms(float* __restrict__ x, const ushort* __restrict__ Wf1xl,
              const ushort* __restrict__ Wf2xl, float* __restrict__ out)
{
    __shared__ ushort a_s[16][136];
    __shared__ ushort h_s[16][520];
    __shared__ float xf_s[16][132];
    const int tid = threadIdx.x;
    const int n0 = blockIdx.x * 16;

    {   // rms prologue (+ stash x_old for LAST)
        int ni = tid >> 4, c8 = (tid & 15) * 8;
        const float* xr = &x[(size_t)(n0 + ni) * 128 + c8];
        float4 v0 = *reinterpret_cast<const float4*>(xr);
        float4 v1 = *reinterpret_cast<const float4*>(xr + 4);
        if (LAST) {
            *reinterpret_cast<float4*>(&xf_s[ni][c8]) = v0;
            *reinterpret_cast<float4*>(&xf_s[ni][c8 + 4]) = v1;
        }
        float ss = v0.x * v0.x + v0.y * v0.y + v0.z * v0.z + v0.w * v0.w
                 + v1.x * v1.x + v1.y * v1.y + v1.z * v1.z + v1.w * v1.w;
        #pragma unroll
        for (int m = 1; m < 16; m <<= 1) ss += __shfl_xor(ss, m, 16);
        float r = rsqrtf(ss * (1.0f / 1152.0f) + 1e-6f);
        uint4 pk;
        pk.x = pack2bf(v0.x * r, v0.y * r);
        pk.y = pack2bf(v0.z * r, v0.w * r);
        pk.z = pack2bf(v1.x * r, v1.y * r);
        pk.w = pack2bf(v1.z * r, v1.w * r);
        *reinterpret_cast<uint4*>(&a_s[ni][c8]) = pk;
    }
    __syncthreads();

    const int l  = tid & 63;
    const int wq = tid >> 6;
    const int lr = l & 15, lk = l >> 4;

    float4v acc[8];
    #pragma unroll
    for (int nf = 0; nf < 8; ++nf) acc[nf] = (float4v){0.f, 0.f, 0.f, 0.f};
    #pragma unroll
    for (int ks = 0; ks < 4; ++ks) {
        short8v af = *reinterpret_cast<const short8v*>(&a_s[lr][lk * 8 + ks * 32]);
        #pragma unroll
        for (int nf = 0; nf < 8; ++nf) {
            int nt = wq * 8 + nf;
            short8v bf = *reinterpret_cast<const short8v*>(&Wf1xl[((size_t)(nt * 4 + ks) * 64 + l) * 8]);
            acc[nf] = __builtin_amdgcn_mfma_f32_16x16x32_bf16(af, bf, acc[nf], 0, 0, 0);
        }
    }
    #pragma unroll
    for (int nf = 0; nf < 8; ++nf) {
        #pragma unroll
        for (int r = 0; r < 4; ++r) {
            float v = siluf(acc[nf][r]);
            float vn = __shfl_xor(v, 1, 64);
            if ((l & 1) == 0) {
                int row = lk * 4 + r;
                int col = wq * 128 + nf * 16 + lr;
                *reinterpret_cast<uint*>(&h_s[row][col]) = pack2bf(v, vn);
            }
        }
    }
    __syncthreads();

    float4v acc2[2];
    acc2[0] = (float4v){0.f, 0.f, 0.f, 0.f};
    acc2[1] = (float4v){0.f, 0.f, 0.f, 0.f};
    #pragma unroll 4
    for (int ks = 0; ks < 16; ++ks) {
        short8v af = *reinterpret_cast<const short8v*>(&h_s[lr][lk * 8 + ks * 32]);
        #pragma unroll
        for (int nf = 0; nf < 2; ++nf) {
            int nt = wq * 2 + nf;
            short8v bf = *reinterpret_cast<const short8v*>(&Wf2xl[((size_t)(nt * 16 + ks) * 64 + l) * 8]);
            acc2[nf] = __builtin_amdgcn_mfma_f32_16x16x32_bf16(af, bf, acc2[nf], 0, 0, 0);
        }
    }
    if (!LAST) {
        #pragma unroll
        for (int nf = 0; nf < 2; ++nf) {
            #pragma unroll
            for (int r = 0; r < 4; ++r) {
                int row = lk * 4 + r;
                int col = wq * 32 + nf * 16 + lr;
                x[(size_t)(n0 + row) * 128 + col] += acc2[nf][r];
            }
        }
    } else {
        // accumulate delta into stashed x_old, then rms -> out (+ zero l>0)
        #pragma unroll
        for (int nf = 0; nf < 2; ++nf) {
            #pragma unroll
            for (int r = 0; r < 4; ++r) {
                int row = lk * 4 + r;
                int col = wq * 32 + nf * 16 + lr;
                xf_s[row][col] += acc2[nf][r];    // unique (row,col) per thread
            }
        }
        __syncthreads();
        int ni = tid >> 4, c8 = (tid & 15) * 8;
        float4 v0 = *reinterpret_cast<const float4*>(&xf_s[ni][c8]);
        float4 v1 = *reinterpret_cast<const float4*>(&xf_s[ni][c8 + 4]);
        float ss = v0.x * v0.x + v0.y * v0.y + v0.z * v0.z + v0.w * v0.w
                 + v1.x * v1.x + v1.y * v1.y + v1.z * v1.z + v1.w * v1.w;
        #pragma unroll
        for (int m = 1; m < 16; m <<= 1) ss += __shfl_xor(ss, m, 16);
        float r = rsqrtf(ss * (1.0f / 1152.0f) + 1e-6f);
        size_t base = (size_t)(n0 + ni) * 1152 + c8;
        float4 o0 = make_float4(v0.x * r, v0.y * r, v0.z * r, v0.w * r);
        float4 o1 = make_float4(v1.x * r, v1.y * r, v1.z * r, v1.w * r);
        *reinterpret_cast<float4*>(&out[base]) = o0;
        *reinterpret_cast<float4*>(&out[base + 4]) = o1;
        const float4 z4 = make_float4(0.f, 0.f, 0.f, 0.f);
        #pragma unroll
        for (int k = 1; k < 9; ++k) {
            *reinterpret_cast<float4*>(&out[base + (size_t)k * 128]) = z4;
            *reinterpret_cast<float4*>(&out[base + (size_t)k * 128 + 4]) = z4;
        }
    }
}

extern "C" void kernel_launch(void* const* d_in, const int* in_sizes, int n_in,
                              void* d_out, int out_size, void* d_ws, size_t ws_size,
                              hipStream_t stream)
{
    const int*   atom_feats = (const int*)d_in[0];
    const int*   bond_feats = (const int*)d_in[1];
    const int*   edge_index = (const int*)d_in[2];
    const float* edge_dist  = (const float*)d_in[3];
    const float* atom_emb   = (const float*)d_in[4];
    const float* bond_emb   = (const float*)d_in[5];
    const float* W_rbf1     = (const float*)d_in[6];
    const float* b_rbf1     = (const float*)d_in[7];
    const float* W_rbf2     = (const float*)d_in[8];
    const float* b_rbf2     = (const float*)d_in[9];
    const float* Wa1        = (const float*)d_in[10];
    const float* Wa2        = (const float*)d_in[11];
    const float* Wv         = (const float*)d_in[12];
    const float* Wg         = (const float*)d_in[13];
    const float* Wo         = (const float*)d_in[14];
    const float* Wf1        = (const float*)d_in[15];
    const float* Wf2        = (const float*)d_in[16];
    float* out = (float*)d_out;

    float* ws   = (float*)d_ws;
    float* x    = ws;                           // NN*128
    float* num  = x    + NN * 128;              // NE*8 (CSR order)
    float* exs  = num  + (size_t)NE * 8;        // NE*8 (CSR order)
    float* W2A  = exs  + (size_t)NE * 8;        // 2*16384
    float* W2G  = W2A  + 2 * 16384;             // 2*1024
    float* bA   = W2G  + 2 * 1024;              // 2*128
    float* bG   = bA   + 2 * 128;               // 16
    float* TG   = bG   + 16;                    // 2*TROWS*8
    float* BGc  = TG   + 2 * (size_t)TROWS * 8; // 2*512*8
    uint* Vb    = (uint*)(BGc + 2 * 512 * 8);   // NN*64
    uint* Psb   = Vb  + NN * 64;
    uint* Pdb   = Psb + NN * 64;
    uint* TAb   = Pdb + NN * 64;                // 2*TROWS*64
    uint* BAcb  = TAb + 2 * (size_t)TROWS * 64; // 2*512*64
    ushort* Wf1x  = (ushort*)(BAcb + 2 * 512 * 64);  // 2*65536
    ushort* Wf2x  = Wf1x  + 2 * 65536;               // 2*65536
    ushort* Wvx   = Wf2x  + 2 * 65536;               // 2*16384
    ushort* Wa1sx = Wvx   + 2 * 16384;               // 2*16384
    ushort* Wa1dx = Wa1sx + 2 * 16384;               // 2*16384
    int* deg    = (int*)(Wa1dx + 2 * 16384);
    int* off    = deg + NN;
    int* cursor = off + NN + 1;
    int* srcp   = cursor + NN;                  // NE
    int* dstp   = srcp + NE;                    // NE
    int* ep     = dstp + NE;                    // NE

    k_atom_embed<<<NN, 128, 0, stream>>>(atom_feats, atom_emb, x, deg);

    // tables + packed weights (once per call)
    k_w2a<<<dim3(18, 2), 256, 0, stream>>>(W_rbf2, b_rbf2, Wa1, Wg, W2A, W2G, bA, bG);
    k_bondtabs<<<dim3(512, 2), 128, 0, stream>>>(bond_emb, Wa1, Wg, BAcb, BGc);
    k_packw<<<dim3(352, 2), 64, 0, stream>>>(Wf1, Wf2, Wv, Wa1, Wf1x, Wf2x, Wvx, Wa1sx, Wa1dx);
    k_t1ta<<<dim3((TBM + 8) / 8, 2), 256, 0, stream>>>(W_rbf1, b_rbf1, W2A, W2G, bA, bG, TAb, TG);

    // CSR (dst is layer-invariant)
    k_hist<<<(NE + 255) / 256, 256, 0, stream>>>(edge_index, deg);
    k_scan<<<1, 1024, 0, stream>>>(deg, off, cursor);
    k_fill<<<(NE + 255) / 256, 256, 0, stream>>>(edge_index, cursor, srcp, dstp, ep);

    for (int l = 0; l < 2; ++l) {
        k_rmsgemm<<<NN / 16, 256, 0, stream>>>(x,
            Wvx + (size_t)l * 16384, Wa1sx + (size_t)l * 16384, Wa1dx + (size_t)l * 16384,
            Vb, Psb, Pdb);
        k_attn<<<(NE + 31) / 32, 256, 0, stream>>>(srcp, dstp, ep, bond_feats, edge_dist,
            Psb, Pdb,
            TAb + (size_t)l * TROWS * 64, TG + (size_t)l * TROWS * 8,
            BAcb + (size_t)l * 512 * 64, BGc + (size_t)l * 512 * 8,
            Wa2 + (size_t)l * 128 * 8, num, exs);
        k_aggo<<<NN, 128, 0, stream>>>(off, srcp, num, exs, Vb,
                                       Wo + (size_t)l * 128 * 128, x);
        if (l == 0)
            k_ffnrms<0><<<NN / 16, 256, 0, stream>>>(x,
                Wf1x + (size_t)l * 65536, Wf2x + (size_t)l * 65536, out);
        else
            k_ffnrms<1><<<NN / 16, 256, 0, stream>>>(x,
                Wf1x + (size_t)l * 65536, Wf2x + (size_t)l * 65536, out);
    }
}